// Round 1
// baseline (1391.346 us; speedup 1.0000x reference)
//
#include <hip/hip_runtime.h>
#include <hip/hip_bf16.h>
#include <math.h>

// ---------------------------------------------------------------------------
// Shapes (compile-time constants for this problem)
// ---------------------------------------------------------------------------
#define SEQ     2048
#define D_MODEL 1024
#define D_IN    2048
#define N_STATE 16
#define DT_RANK 64
#define XDBL_W  96          // DT_RANK + 2*N_STATE

// ---------------------------------------------------------------------------
// Generic fp32 tiled GEMM: C[M,N] = A[M,K] * B[K,N]  (row-major, arbitrary ld)
// BM=BN=128, BK=16, 256 threads, 8x8 per thread.
// act: 0 = none, 1 = softplus(acc + bias[col])
// Requires M%128==0, N%128==0, K%16==0, ld*4 and offsets 16B aligned.
// ---------------------------------------------------------------------------
__global__ __launch_bounds__(256) void gemm128(
    const float* __restrict__ A, const float* __restrict__ B,
    float* __restrict__ C, int M, int N, int K,
    int lda, int ldb, int ldc,
    const float* __restrict__ bias, int act)
{
    __shared__ float As[16][132];
    __shared__ float Bs[16][132];

    const int t   = threadIdx.x;
    const int bn0 = blockIdx.x * 128;
    const int bm0 = blockIdx.y * 128;
    const int tx  = t & 15;        // 0..15 -> col group
    const int ty  = t >> 4;        // 0..15 -> row group

    const int ar  = t >> 2;        // 0..63
    const int ak  = (t & 3) * 4;   // 0,4,8,12
    const int bk  = t >> 5;        // 0..7
    const int bn4 = (t & 31) * 4;  // 0..124

    float acc[8][8];
#pragma unroll
    for (int i = 0; i < 8; ++i)
#pragma unroll
        for (int j = 0; j < 8; ++j) acc[i][j] = 0.f;

    for (int k0 = 0; k0 < K; k0 += 16) {
        float4 a0 = *(const float4*)&A[(size_t)(bm0 + ar)      * lda + k0 + ak];
        float4 a1 = *(const float4*)&A[(size_t)(bm0 + ar + 64) * lda + k0 + ak];
        float4 b0 = *(const float4*)&B[(size_t)(k0 + bk)     * ldb + bn0 + bn4];
        float4 b1 = *(const float4*)&B[(size_t)(k0 + bk + 8) * ldb + bn0 + bn4];

        __syncthreads();   // previous iteration finished reading LDS
        As[ak + 0][ar] = a0.x; As[ak + 1][ar] = a0.y;
        As[ak + 2][ar] = a0.z; As[ak + 3][ar] = a0.w;
        As[ak + 0][ar + 64] = a1.x; As[ak + 1][ar + 64] = a1.y;
        As[ak + 2][ar + 64] = a1.z; As[ak + 3][ar + 64] = a1.w;
        *(float4*)&Bs[bk][bn4]     = b0;
        *(float4*)&Bs[bk + 8][bn4] = b1;
        __syncthreads();

#pragma unroll
        for (int kk = 0; kk < 16; ++kk) {
            float a[8], b[8];
            ((float4*)a)[0] = *(const float4*)&As[kk][ty * 8];
            ((float4*)a)[1] = *(const float4*)&As[kk][ty * 8 + 4];
            ((float4*)b)[0] = *(const float4*)&Bs[kk][tx * 8];
            ((float4*)b)[1] = *(const float4*)&Bs[kk][tx * 8 + 4];
#pragma unroll
            for (int i = 0; i < 8; ++i)
#pragma unroll
                for (int j = 0; j < 8; ++j)
                    acc[i][j] = fmaf(a[i], b[j], acc[i][j]);
        }
    }

    const int row = bm0 + ty * 8;
    const int col = bn0 + tx * 8;
#pragma unroll
    for (int i = 0; i < 8; ++i) {
        float vals[8];
#pragma unroll
        for (int j = 0; j < 8; ++j) {
            float v = acc[i][j];
            if (act == 1) {
                v += bias[col + j];
                v = (v > 20.f) ? v : log1pf(expf(v));   // stable softplus
            }
            vals[j] = v;
        }
        *(float4*)&C[(size_t)(row + i) * ldc + col]     = ((float4*)vals)[0];
        *(float4*)&C[(size_t)(row + i) * ldc + col + 4] = ((float4*)vals)[1];
    }
}

// ---------------------------------------------------------------------------
// Depthwise causal conv (K=3) + SiLU:  u[l,d] = silu(sum_k xi[l-2+k,d]*w[d,k])
// xi lives in xr[:, 0:D_IN] (row stride 4096).
// ---------------------------------------------------------------------------
__global__ __launch_bounds__(256) void conv_silu(
    const float* __restrict__ xr, const float* __restrict__ cw,
    float* __restrict__ u)
{
    const int id = blockIdx.x * 256 + threadIdx.x;  // SEQ*D_IN threads
    const int l = id >> 11;
    const int d = id & (D_IN - 1);
    const float w0 = cw[d * 3 + 0];
    const float w1 = cw[d * 3 + 1];
    const float w2 = cw[d * 3 + 2];
    const float x0  = xr[(size_t)l * 4096 + d];
    const float xm1 = (l >= 1) ? xr[(size_t)(l - 1) * 4096 + d] : 0.f;
    const float xm2 = (l >= 2) ? xr[(size_t)(l - 2) * 4096 + d] : 0.f;
    const float v = w0 * xm2 + w1 * xm1 + w2 * x0;
    const float s = 1.f / (1.f + expf(-v));
    u[(size_t)l * D_IN + d] = v * s;
}

// ---------------------------------------------------------------------------
// x_dbl = u @ W_x  (M=SEQ, N=96, K=D_IN).  4 rows per block, 128 threads.
// ---------------------------------------------------------------------------
__global__ __launch_bounds__(128) void gemm_wx(
    const float* __restrict__ u, const float* __restrict__ Wx,
    float* __restrict__ xdbl)
{
    __shared__ float su[4][D_IN];
    const int t  = threadIdx.x;
    const int l0 = blockIdx.x * 4;
#pragma unroll
    for (int q = 0; q < 16; ++q) {
        int idx = q * 128 + t;          // float4 index, 2048 total
        int r   = idx >> 9;             // 512 float4 per row
        int c4  = (idx & 511) * 4;
        *(float4*)&su[r][c4] = *(const float4*)&u[(size_t)(l0 + r) * D_IN + c4];
    }
    __syncthreads();
    if (t < XDBL_W) {
        float a0 = 0.f, a1 = 0.f, a2 = 0.f, a3 = 0.f;
#pragma unroll 8
        for (int k = 0; k < D_IN; ++k) {
            const float w = Wx[(size_t)k * XDBL_W + t];
            a0 = fmaf(su[0][k], w, a0);
            a1 = fmaf(su[1][k], w, a1);
            a2 = fmaf(su[2][k], w, a2);
            a3 = fmaf(su[3][k], w, a3);
        }
        xdbl[(size_t)(l0 + 0) * XDBL_W + t] = a0;
        xdbl[(size_t)(l0 + 1) * XDBL_W + t] = a1;
        xdbl[(size_t)(l0 + 2) * XDBL_W + t] = a2;
        xdbl[(size_t)(l0 + 3) * XDBL_W + t] = a3;
    }
}

// ---------------------------------------------------------------------------
// Column sums of delta in double (for suffix-sum gate), two deterministic
// stages.
// ---------------------------------------------------------------------------
__global__ __launch_bounds__(256) void colsum_part(
    const float* __restrict__ delta, double* __restrict__ part)
{
    const int d  = blockIdx.x * 256 + threadIdx.x;
    const int lc = blockIdx.y;
    double s = 0.0;
    for (int i = 0; i < 128; ++i)
        s += (double)delta[(size_t)(lc * 128 + i) * D_IN + d];
    part[(size_t)lc * D_IN + d] = s;
}

__global__ __launch_bounds__(256) void colsum_final(
    const double* __restrict__ part, double* __restrict__ T)
{
    const int d = blockIdx.x * 256 + threadIdx.x;
    double s = 0.0;
    for (int lc = 0; lc < 16; ++lc) s += part[(size_t)lc * D_IN + d];
    T[d] = s;
}

// ---------------------------------------------------------------------------
// Selective scan replicating the reference's cumsum/gate numerics.
//   S[l] = A_n * (T_d - P_d[l])   (P,T double)
//   E = exp(S); g = E/(E+1e-12)
//   h[l] = h[l-1]*exp(delta*A_n) + delta*u*B
//   y[l,d] = sum_n h*g*C + u*D;  yg = y * silu(res)
// Block: 64 threads = 4 d-channels x 16 states. Grid: D_IN/4 = 512.
// ---------------------------------------------------------------------------
__global__ __launch_bounds__(64) void scan_kernel(
    const float* __restrict__ delta, const float* __restrict__ u,
    const float* __restrict__ xdbl, const double* __restrict__ Ttot,
    const float* __restrict__ Alog, const float* __restrict__ Dvec,
    const float* __restrict__ xr, float* __restrict__ yg)
{
    __shared__ float sdel[128][4];
    __shared__ float sU[128][4];
    __shared__ float sres[128][4];
    __shared__ float sbc[128][32];

    const int t  = threadIdx.x;
    const int dl = t >> 4;
    const int n  = t & 15;
    const int d0 = blockIdx.x * 4;
    const int d  = d0 + dl;

    const float An = -expf(Alog[d * N_STATE + n]);
    const double Td = Ttot[d];
    const float Dd = Dvec[d];
    double P = 0.0;
    float h = 0.f;

    for (int l0 = 0; l0 < SEQ; l0 += 128) {
        // stage delta/u/res rows (128 x 4 floats each)
#pragma unroll
        for (int q = 0; q < 2; ++q) {
            int r = q * 64 + t;
            *(float4*)&sdel[r][0] = *(const float4*)&delta[(size_t)(l0 + r) * D_IN + d0];
            *(float4*)&sU[r][0]   = *(const float4*)&u[(size_t)(l0 + r) * D_IN + d0];
            *(float4*)&sres[r][0] = *(const float4*)&xr[(size_t)(l0 + r) * 4096 + D_IN + d0];
        }
        // stage B,C (cols 64..95 of xdbl): 128 rows x 32 floats
#pragma unroll
        for (int q = 0; q < 16; ++q) {
            int idx = q * 64 + t;       // float4 index
            int r   = idx >> 3;
            int c4  = (idx & 7) * 4;
            *(float4*)&sbc[r][c4] =
                *(const float4*)&xdbl[(size_t)(l0 + r) * XDBL_W + DT_RANK + c4];
        }
        __syncthreads();

        for (int i = 0; i < 128; ++i) {
            const float dv = sdel[i][dl];
            const float uv = sU[i][dl];
            P += (double)dv;
            const float sfx = (float)(Td - P);      // suffix sum of delta (>l)
            const float E   = expf(An * sfx);
            const float g   = E / (E + 1e-12f);
            const float dec = expf(An * dv);
            const float Bv  = sbc[i][n];
            const float Cv  = sbc[i][16 + n];
            h = fmaf(h, dec, dv * uv * Bv);
            float contrib = h * g * Cv;
            contrib += __shfl_xor(contrib, 1);
            contrib += __shfl_xor(contrib, 2);
            contrib += __shfl_xor(contrib, 4);
            contrib += __shfl_xor(contrib, 8);
            if (n == 0) {
                const int l = l0 + i;
                const float r  = sres[i][dl];
                const float sg = 1.f / (1.f + expf(-r));
                yg[(size_t)l * D_IN + d] = (contrib + uv * Dd) * (r * sg);
            }
        }
        __syncthreads();
    }
}

// ---------------------------------------------------------------------------
// Launch
// ---------------------------------------------------------------------------
extern "C" void kernel_launch(void* const* d_in, const int* in_sizes, int n_in,
                              void* d_out, int out_size, void* d_ws, size_t ws_size,
                              hipStream_t stream)
{
    const float* x      = (const float*)d_in[0];
    const float* W_in   = (const float*)d_in[1];
    const float* conv_w = (const float*)d_in[2];
    const float* W_x    = (const float*)d_in[3];
    const float* W_del  = (const float*)d_in[4];
    const float* b_del  = (const float*)d_in[5];
    const float* A_log  = (const float*)d_in[6];
    const float* Dv     = (const float*)d_in[7];
    const float* W_out  = (const float*)d_in[8];
    float* out = (float*)d_out;

    char* ws = (char*)d_ws;
    float*  xr    = (float*)(ws + 0);              // 2048x4096   33.55 MB
    float*  u     = (float*)(ws + 33554432);       // 2048x2048   16.78 MB
    float*  xdbl  = (float*)(ws + 50331648);       // 2048x96      0.79 MB
    float*  delta = (float*)(ws + 51118080);       // 2048x2048   16.78 MB
    double* Tpart = (double*)(ws + 67895296);      // 16x2048 dbl  0.26 MB
    double* Ttot  = (double*)(ws + 68157440);      // 2048 dbl     16 KB
    float*  yg    = (float*)(ws + 68173824);       // 2048x2048   16.78 MB

    // 1) xr = x @ W_in   (2048x4096, K=1024)
    gemm128<<<dim3(4096 / 128, 2048 / 128), 256, 0, stream>>>(
        x, W_in, xr, SEQ, 2 * D_IN, D_MODEL, D_MODEL, 2 * D_IN, 2 * D_IN,
        nullptr, 0);

    // 2) u = silu(depthwise_conv(xi))
    conv_silu<<<(SEQ * D_IN) / 256, 256, 0, stream>>>(xr, conv_w, u);

    // 3) x_dbl = u @ W_x  (2048x96, K=2048)
    gemm_wx<<<SEQ / 4, 128, 0, stream>>>(u, W_x, xdbl);

    // 4) delta = softplus(delta_lr @ W_delta + b_delta)  (2048x2048, K=64)
    gemm128<<<dim3(2048 / 128, 2048 / 128), 256, 0, stream>>>(
        xdbl, W_del, delta, SEQ, D_IN, DT_RANK, XDBL_W, D_IN, D_IN,
        b_del, 1);

    // 5) per-channel total of delta (double, deterministic two-stage)
    colsum_part<<<dim3(8, 16), 256, 0, stream>>>(delta, Tpart);
    colsum_final<<<8, 256, 0, stream>>>(Tpart, Ttot);

    // 6) selective scan + res gating
    scan_kernel<<<D_IN / 4, 64, 0, stream>>>(delta, u, xdbl, Ttot, A_log, Dv,
                                             xr, yg);

    // 7) out = yg @ W_out  (2048x1024, K=2048)
    gemm128<<<dim3(1024 / 128, 2048 / 128), 256, 0, stream>>>(
        yg, W_out, out, SEQ, D_MODEL, D_IN, D_IN, D_MODEL, D_MODEL,
        nullptr, 0);
}

// Round 3
// 746.728 us; speedup vs baseline: 1.8633x; 1.8633x over previous
//
#include <hip/hip_runtime.h>
#include <hip/hip_bf16.h>
#include <math.h>

// ---------------------------------------------------------------------------
// Shapes (compile-time constants for this problem)
// ---------------------------------------------------------------------------
#define SEQ     2048
#define D_MODEL 1024
#define D_IN    2048
#define N_STATE 16
#define DT_RANK 64
#define XDBL_W  96          // DT_RANK + 2*N_STATE
#define LC      64          // scan chunk length
#define NCH     32          // SEQ / LC
#define DT      32          // d-channels per scan block

// ---------------------------------------------------------------------------
// Generic fp32 tiled GEMM: C[M,N] = A[M,K] * B[K,N]  (row-major, arbitrary ld)
// BM=BN=128, BK=16, 256 threads, 8x8 per thread.
// act: 0 = none, 1 = softplus(acc + bias[col])
// ---------------------------------------------------------------------------
__global__ __launch_bounds__(256) void gemm128(
    const float* __restrict__ A, const float* __restrict__ B,
    float* __restrict__ C, int M, int N, int K,
    int lda, int ldb, int ldc,
    const float* __restrict__ bias, int act)
{
    __shared__ float As[16][132];
    __shared__ float Bs[16][132];

    const int t   = threadIdx.x;
    const int bn0 = blockIdx.x * 128;
    const int bm0 = blockIdx.y * 128;
    const int tx  = t & 15;
    const int ty  = t >> 4;

    const int ar  = t >> 2;
    const int ak  = (t & 3) * 4;
    const int bk  = t >> 5;
    const int bn4 = (t & 31) * 4;

    float acc[8][8];
#pragma unroll
    for (int i = 0; i < 8; ++i)
#pragma unroll
        for (int j = 0; j < 8; ++j) acc[i][j] = 0.f;

    for (int k0 = 0; k0 < K; k0 += 16) {
        float4 a0 = *(const float4*)&A[(size_t)(bm0 + ar)      * lda + k0 + ak];
        float4 a1 = *(const float4*)&A[(size_t)(bm0 + ar + 64) * lda + k0 + ak];
        float4 b0 = *(const float4*)&B[(size_t)(k0 + bk)     * ldb + bn0 + bn4];
        float4 b1 = *(const float4*)&B[(size_t)(k0 + bk + 8) * ldb + bn0 + bn4];

        __syncthreads();
        As[ak + 0][ar] = a0.x; As[ak + 1][ar] = a0.y;
        As[ak + 2][ar] = a0.z; As[ak + 3][ar] = a0.w;
        As[ak + 0][ar + 64] = a1.x; As[ak + 1][ar + 64] = a1.y;
        As[ak + 2][ar + 64] = a1.z; As[ak + 3][ar + 64] = a1.w;
        *(float4*)&Bs[bk][bn4]     = b0;
        *(float4*)&Bs[bk + 8][bn4] = b1;
        __syncthreads();

#pragma unroll
        for (int kk = 0; kk < 16; ++kk) {
            float a[8], b[8];
            ((float4*)a)[0] = *(const float4*)&As[kk][ty * 8];
            ((float4*)a)[1] = *(const float4*)&As[kk][ty * 8 + 4];
            ((float4*)b)[0] = *(const float4*)&Bs[kk][tx * 8];
            ((float4*)b)[1] = *(const float4*)&Bs[kk][tx * 8 + 4];
#pragma unroll
            for (int i = 0; i < 8; ++i)
#pragma unroll
                for (int j = 0; j < 8; ++j)
                    acc[i][j] = fmaf(a[i], b[j], acc[i][j]);
        }
    }

    const int row = bm0 + ty * 8;
    const int col = bn0 + tx * 8;
#pragma unroll
    for (int i = 0; i < 8; ++i) {
        float vals[8];
#pragma unroll
        for (int j = 0; j < 8; ++j) {
            float v = acc[i][j];
            if (act == 1) {
                v += bias[col + j];
                v = (v > 20.f) ? v : log1pf(expf(v));
            }
            vals[j] = v;
        }
        *(float4*)&C[(size_t)(row + i) * ldc + col]     = ((float4*)vals)[0];
        *(float4*)&C[(size_t)(row + i) * ldc + col + 4] = ((float4*)vals)[1];
    }
}

// ---------------------------------------------------------------------------
// Depthwise causal conv (K=3) + SiLU
// ---------------------------------------------------------------------------
__global__ __launch_bounds__(256) void conv_silu(
    const float* __restrict__ xr, const float* __restrict__ cw,
    float* __restrict__ u)
{
    const int id = blockIdx.x * 256 + threadIdx.x;
    const int l = id >> 11;
    const int d = id & (D_IN - 1);
    const float w0 = cw[d * 3 + 0];
    const float w1 = cw[d * 3 + 1];
    const float w2 = cw[d * 3 + 2];
    const float x0  = xr[(size_t)l * 4096 + d];
    const float xm1 = (l >= 1) ? xr[(size_t)(l - 1) * 4096 + d] : 0.f;
    const float xm2 = (l >= 2) ? xr[(size_t)(l - 2) * 4096 + d] : 0.f;
    const float v = w0 * xm2 + w1 * xm1 + w2 * x0;
    const float s = 1.f / (1.f + expf(-v));
    u[(size_t)l * D_IN + d] = v * s;
}

// ---------------------------------------------------------------------------
// x_dbl = u @ W_x  (M=SEQ, N=96, K=D_IN)
// ---------------------------------------------------------------------------
__global__ __launch_bounds__(128) void gemm_wx(
    const float* __restrict__ u, const float* __restrict__ Wx,
    float* __restrict__ xdbl)
{
    __shared__ float su[4][D_IN];
    const int t  = threadIdx.x;
    const int l0 = blockIdx.x * 4;
#pragma unroll
    for (int q = 0; q < 16; ++q) {
        int idx = q * 128 + t;
        int r   = idx >> 9;
        int c4  = (idx & 511) * 4;
        *(float4*)&su[r][c4] = *(const float4*)&u[(size_t)(l0 + r) * D_IN + c4];
    }
    __syncthreads();
    if (t < XDBL_W) {
        float a0 = 0.f, a1 = 0.f, a2 = 0.f, a3 = 0.f;
#pragma unroll 8
        for (int k = 0; k < D_IN; ++k) {
            const float w = Wx[(size_t)k * XDBL_W + t];
            a0 = fmaf(su[0][k], w, a0);
            a1 = fmaf(su[1][k], w, a1);
            a2 = fmaf(su[2][k], w, a2);
            a3 = fmaf(su[3][k], w, a3);
        }
        xdbl[(size_t)(l0 + 0) * XDBL_W + t] = a0;
        xdbl[(size_t)(l0 + 1) * XDBL_W + t] = a1;
        xdbl[(size_t)(l0 + 2) * XDBL_W + t] = a2;
        xdbl[(size_t)(l0 + 3) * XDBL_W + t] = a3;
    }
}

// ---------------------------------------------------------------------------
// Per-chunk column sums of delta (double), 32 chunks of 64 rows.
// ---------------------------------------------------------------------------
__global__ __launch_bounds__(256) void csum64(
    const float* __restrict__ delta, double* __restrict__ csum)
{
    const int d = blockIdx.x * 256 + threadIdx.x;
    const int c = blockIdx.y;
    double s = 0.0;
    for (int i = 0; i < LC; ++i)
        s += (double)delta[(size_t)(c * LC + i) * D_IN + d];
    csum[(size_t)c * D_IN + d] = s;
}

// Per-d prefix of chunk sums (P0[c] = sum of chunks < c) + total T[d].
__global__ __launch_bounds__(256) void chunk_prefix(
    const double* __restrict__ csum, double* __restrict__ P0,
    double* __restrict__ Td)
{
    const int d = blockIdx.x * 256 + threadIdx.x;
    double P = 0.0;
    for (int c = 0; c < NCH; ++c) {
        P0[(size_t)c * D_IN + d] = P;
        P += csum[(size_t)c * D_IN + d];
    }
    Td[d] = P;
}

// ---------------------------------------------------------------------------
// Pass A: per-chunk local scan from h=0; store final local state per (c,d,n).
// Block: 512 thr = 32 d x 16 n. Grid: (NCH, D_IN/DT).
// ---------------------------------------------------------------------------
__global__ __launch_bounds__(512) void scan_partA(
    const float* __restrict__ delta, const float* __restrict__ u,
    const float* __restrict__ xdbl, const float* __restrict__ Alog,
    float* __restrict__ hfin)
{
    __shared__ float sdel[LC][DT];
    __shared__ float sU[LC][DT];
    __shared__ float sB[LC][16];

    const int t  = threadIdx.x;
    const int c  = blockIdx.x;
    const int d0 = blockIdx.y * DT;

    {   // stage delta/u tiles: 64x32 floats = 512 float4
        int r = t >> 3, c4 = (t & 7) * 4;
        *(float4*)&sdel[r][c4] = *(const float4*)&delta[(size_t)(c * LC + r) * D_IN + d0 + c4];
        *(float4*)&sU[r][c4]   = *(const float4*)&u[(size_t)(c * LC + r) * D_IN + d0 + c4];
    }
    if (t < 256) {  // B tile: 64x16
        int r = t >> 2, c4 = (t & 3) * 4;
        *(float4*)&sB[r][c4] = *(const float4*)&xdbl[(size_t)(c * LC + r) * XDBL_W + DT_RANK + c4];
    }
    __syncthreads();

    const int n  = t & 15;
    const int dq = t >> 4;
    const int d  = d0 + dq;
    const float An = -expf(Alog[d * N_STATE + n]);

    float h = 0.f;
#pragma unroll 8
    for (int i = 0; i < LC; ++i) {
        const float dv = sdel[i][dq];
        const float uv = sU[i][dq];
        h = fmaf(h, expf(An * dv), dv * uv * sB[i][n]);
    }
    hfin[((size_t)c * D_IN + d) * N_STATE + n] = h;
}

// ---------------------------------------------------------------------------
// Pass B: serial combine across the 32 chunks (per (d,n)); hfin becomes the
// INCOMING state H0 for each chunk (in-place).
// ---------------------------------------------------------------------------
__global__ __launch_bounds__(256) void scan_combine(
    float* __restrict__ hfin, const double* __restrict__ csum,
    const float* __restrict__ Alog)
{
    const int id = blockIdx.x * 256 + threadIdx.x;   // (d,n)
    const int d = id >> 4;
    const int n = id & 15;
    const float An = -expf(Alog[d * N_STATE + n]);
    float H = 0.f;
    for (int c = 0; c < NCH; ++c) {
        const size_t idx = ((size_t)c * D_IN + d) * N_STATE + n;
        const float hf = hfin[idx];
        hfin[idx] = H;
        const float Dec = expf(An * (float)csum[(size_t)c * D_IN + d]);
        H = fmaf(H, Dec, hf);
    }
}

// ---------------------------------------------------------------------------
// Pass C: full scan with incoming state + suffix gate + n-reduce + res-SiLU.
// yg may alias delta (all global reads staged to LDS before writes).
// Plocal in DOUBLE: csum64 summed the same 64 floats serially in double, so
// at the chunk end (Td - P0[c]) - Plocal == 0 exactly; fp32 Plocal had ~3e-4
// error -> sfx < 0 -> expf(An*sfx) = +inf (|An| up to 8.9e6) -> NaN.
// fmaxf(sfx,0) guards any residual rounding path.
// ---------------------------------------------------------------------------
__global__ __launch_bounds__(512) void scan_partC(
    const float* __restrict__ delta, const float* __restrict__ u,
    const float* __restrict__ xdbl, const float* __restrict__ H0buf,
    const double* __restrict__ P0, const double* __restrict__ Td,
    const float* __restrict__ Alog, const float* __restrict__ Dvec,
    const float* __restrict__ xr, float* __restrict__ yg)
{
    __shared__ float sdel[LC][DT];
    __shared__ float sU[LC][DT];
    __shared__ float sres[LC][DT];
    __shared__ float sB[LC][16];
    __shared__ float sC[LC][16];

    const int t  = threadIdx.x;
    const int c  = blockIdx.x;
    const int d0 = blockIdx.y * DT;

    {
        int r = t >> 3, c4 = (t & 7) * 4;
        *(float4*)&sdel[r][c4] = *(const float4*)&delta[(size_t)(c * LC + r) * D_IN + d0 + c4];
        *(float4*)&sU[r][c4]   = *(const float4*)&u[(size_t)(c * LC + r) * D_IN + d0 + c4];
        *(float4*)&sres[r][c4] = *(const float4*)&xr[(size_t)(c * LC + r) * 4096 + D_IN + d0 + c4];
    }
    if (t < 256) {
        int r = t >> 2, c4 = (t & 3) * 4;
        *(float4*)&sB[r][c4] = *(const float4*)&xdbl[(size_t)(c * LC + r) * XDBL_W + DT_RANK + c4];
        *(float4*)&sC[r][c4] = *(const float4*)&xdbl[(size_t)(c * LC + r) * XDBL_W + DT_RANK + 16 + c4];
    }
    __syncthreads();

    const int n  = t & 15;
    const int dq = t >> 4;
    const int d  = d0 + dq;
    const float An = -expf(Alog[d * N_STATE + n]);
    const float Dd = Dvec[d];
    const double sfxbase = Td[d] - P0[(size_t)c * D_IN + d];

    float h = H0buf[((size_t)c * D_IN + d) * N_STATE + n];
    double Plocal = 0.0;

    for (int i = 0; i < LC; ++i) {
        const float dv = sdel[i][dq];
        const float uv = sU[i][dq];
        Plocal += (double)dv;
        const float sfx = fmaxf((float)(sfxbase - Plocal), 0.f);
        const float E   = expf(An * sfx);
        const float g   = E / (E + 1e-12f);
        h = fmaf(h, expf(An * dv), dv * uv * sB[i][n]);
        float contrib = h * g * sC[i][n];
        contrib += __shfl_xor(contrib, 1);
        contrib += __shfl_xor(contrib, 2);
        contrib += __shfl_xor(contrib, 4);
        contrib += __shfl_xor(contrib, 8);
        if (n == 0) {
            const float r  = sres[i][dq];
            const float sg = 1.f / (1.f + expf(-r));
            yg[(size_t)(c * LC + i) * D_IN + d] = (contrib + uv * Dd) * (r * sg);
        }
    }
}

// ---------------------------------------------------------------------------
// Launch
// ---------------------------------------------------------------------------
extern "C" void kernel_launch(void* const* d_in, const int* in_sizes, int n_in,
                              void* d_out, int out_size, void* d_ws, size_t ws_size,
                              hipStream_t stream)
{
    const float* x      = (const float*)d_in[0];
    const float* W_in   = (const float*)d_in[1];
    const float* conv_w = (const float*)d_in[2];
    const float* W_x    = (const float*)d_in[3];
    const float* W_del  = (const float*)d_in[4];
    const float* b_del  = (const float*)d_in[5];
    const float* A_log  = (const float*)d_in[6];
    const float* Dv     = (const float*)d_in[7];
    const float* W_out  = (const float*)d_in[8];
    float* out = (float*)d_out;

    char* ws = (char*)d_ws;
    float*  xr    = (float*)(ws + 0);              // 2048x4096   33.55 MB
    float*  u     = (float*)(ws + 33554432);       // 2048x2048   16.78 MB
    float*  xdbl  = (float*)(ws + 50331648);       // 2048x96      0.79 MB
    float*  delta = (float*)(ws + 51118080);       // 2048x2048   16.78 MB
    float*  hfin  = (float*)(ws + 67895296);       // 32x2048x16   4.19 MB
    double* csum  = (double*)(ws + 72089600);      // 32x2048 dbl  0.52 MB
    double* P0    = (double*)(ws + 72613888);      // 32x2048 dbl  0.52 MB
    double* Td    = (double*)(ws + 73138176);      // 2048 dbl     16 KB
    float*  yg    = delta;                         // alias (safe: pass C stages
                                                   // reads to LDS before writes)

    // 1) xr = x @ W_in
    gemm128<<<dim3(4096 / 128, 2048 / 128), 256, 0, stream>>>(
        x, W_in, xr, SEQ, 2 * D_IN, D_MODEL, D_MODEL, 2 * D_IN, 2 * D_IN,
        nullptr, 0);

    // 2) u = silu(depthwise_conv(xi))
    conv_silu<<<(SEQ * D_IN) / 256, 256, 0, stream>>>(xr, conv_w, u);

    // 3) x_dbl = u @ W_x
    gemm_wx<<<SEQ / 4, 128, 0, stream>>>(u, W_x, xdbl);

    // 4) delta = softplus(delta_lr @ W_delta + b_delta)
    gemm128<<<dim3(2048 / 128, 2048 / 128), 256, 0, stream>>>(
        xdbl, W_del, delta, SEQ, D_IN, DT_RANK, XDBL_W, D_IN, D_IN,
        b_del, 1);

    // 5) chunk sums + prefix (double, deterministic)
    csum64<<<dim3(D_IN / 256, NCH), 256, 0, stream>>>(delta, csum);
    chunk_prefix<<<D_IN / 256, 256, 0, stream>>>(csum, P0, Td);

    // 6) chunk-parallel selective scan
    scan_partA<<<dim3(NCH, D_IN / DT), 512, 0, stream>>>(delta, u, xdbl, A_log, hfin);
    scan_combine<<<(D_IN * N_STATE) / 256, 256, 0, stream>>>(hfin, csum, A_log);
    scan_partC<<<dim3(NCH, D_IN / DT), 512, 0, stream>>>(
        delta, u, xdbl, hfin, P0, Td, A_log, Dv, xr, yg);

    // 7) out = yg @ W_out
    gemm128<<<dim3(1024 / 128, 2048 / 128), 256, 0, stream>>>(
        yg, W_out, out, SEQ, D_MODEL, D_IN, D_IN, D_MODEL, D_MODEL,
        nullptr, 0);
}

// Round 4
// 434.684 us; speedup vs baseline: 3.2008x; 1.7179x over previous
//
#include <hip/hip_runtime.h>
#include <hip/hip_bf16.h>
#include <math.h>

// ---------------------------------------------------------------------------
// Shapes (compile-time constants for this problem)
// ---------------------------------------------------------------------------
#define SEQ     2048
#define D_MODEL 1024
#define D_IN    2048
#define N_STATE 16
#define DT_RANK 64
#define XDBL_W  96          // DT_RANK + 2*N_STATE
#define LC      64          // scan chunk length
#define NCH     32          // SEQ / LC
#define DT      32          // d-channels per scan block

typedef __attribute__((ext_vector_type(8))) short bf16x8;
typedef __attribute__((ext_vector_type(4))) float f32x4;

__device__ __forceinline__ ushort f2bf(float x) {
    unsigned u = __float_as_uint(x);
    u += 0x7FFFu + ((u >> 16) & 1u);      // RNE
    return (ushort)(u >> 16);
}
__device__ __forceinline__ float bf2f(ushort h) {
    return __uint_as_float(((unsigned)h) << 16);
}

// ---------------------------------------------------------------------------
// split fp32 -> bf16 hi/lo (elementwise). One float4 per thread.
// ---------------------------------------------------------------------------
__global__ __launch_bounds__(256) void split_bf16(
    const float* __restrict__ in, ushort* __restrict__ hi,
    ushort* __restrict__ lo)
{
    const int i = blockIdx.x * 256 + threadIdx.x;
    const float4 v = *(const float4*)&in[(size_t)i * 4];
    ushort4 h, l;
    h.x = f2bf(v.x); l.x = f2bf(v.x - bf2f(h.x));
    h.y = f2bf(v.y); l.y = f2bf(v.y - bf2f(h.y));
    h.z = f2bf(v.z); l.z = f2bf(v.z - bf2f(h.z));
    h.w = f2bf(v.w); l.w = f2bf(v.w - bf2f(h.w));
    *(ushort4*)&hi[(size_t)i * 4] = h;
    *(ushort4*)&lo[(size_t)i * 4] = l;
}

// ---------------------------------------------------------------------------
// split + transpose: in[R][C] fp32 -> hi/lo[C][R] bf16.
// ---------------------------------------------------------------------------
__global__ __launch_bounds__(256) void split_transpose(
    const float* __restrict__ in, ushort* __restrict__ hi,
    ushort* __restrict__ lo, int R, int C)
{
    __shared__ float tile[32][33];
    const int c0 = blockIdx.x * 32;
    const int r0 = blockIdx.y * 32;
    const int tc = threadIdx.x & 31;
    const int tr = threadIdx.x >> 5;
#pragma unroll
    for (int q = 0; q < 4; ++q)
        tile[tr + 8 * q][tc] = in[(size_t)(r0 + tr + 8 * q) * C + c0 + tc];
    __syncthreads();
#pragma unroll
    for (int q = 0; q < 4; ++q) {
        const float v = tile[tc][tr + 8 * q];
        const ushort h = f2bf(v);
        const ushort l = f2bf(v - bf2f(h));
        const size_t o = (size_t)(c0 + tr + 8 * q) * R + r0 + tc;
        hi[o] = h;
        lo[o] = l;
    }
}

// ---------------------------------------------------------------------------
// bf16x3-split MFMA GEMM: C[M,N] = A[M,K] * B[K,N], with A given as hi/lo
// bf16 row-major [M][K], B given TRANSPOSED as hi/lo bf16 [N][K].
// acc += Ahi*Bhi + Ahi*Blo + Alo*Bhi  (fp32 accumulate, 16x16x32 MFMA).
// Tile 128x128, K-step 64, 256 threads (4 waves, 64x64 each).
// LDS XOR-swizzled (slot ^= row&7) -> conflict-free ds_read_b128.
// Output cols < nsplit go to C0, the rest to C1 (col-nsplit).
// ---------------------------------------------------------------------------
__global__ __launch_bounds__(256) void gemm_mfma3(
    const ushort* __restrict__ Ahi, const ushort* __restrict__ Alo,
    const ushort* __restrict__ Bhi, const ushort* __restrict__ Blo,
    float* __restrict__ C0, float* __restrict__ C1, int nsplit,
    int M, int N, int K, int ldc0, int ldc1)
{
    __shared__ ushort lA[2][128][64];   // [hi/lo][row][k]   16 KB each
    __shared__ ushort lB[2][128][64];   // [hi/lo][col][k]

    const int t    = threadIdx.x;
    const int m0   = blockIdx.y * 128;
    const int n0   = blockIdx.x * 128;
    const int wave = t >> 6;
    const int lane = t & 63;
    const int mw   = (wave & 1) * 64;
    const int nw   = (wave >> 1) * 64;
    const int l15  = lane & 15;
    const int l4   = lane >> 4;
    const int sw   = l15 & 7;

    f32x4 acc[4][4];
#pragma unroll
    for (int i = 0; i < 4; ++i)
#pragma unroll
        for (int j = 0; j < 4; ++j)
            acc[i][j] = (f32x4){0.f, 0.f, 0.f, 0.f};

    for (int k0 = 0; k0 < K; k0 += 64) {
        __syncthreads();   // previous iteration done reading LDS
#define STAGE(SRC, DST, BASE)                                                  \
        _Pragma("unroll")                                                      \
        for (int q = 0; q < 4; ++q) {                                          \
            const int idx = q * 256 + t;                                       \
            const int r = idx >> 3, kc = idx & 7;                              \
            const uint4 v =                                                    \
                *(const uint4*)&SRC[(size_t)(BASE + r) * K + k0 + kc * 8];     \
            *(uint4*)&DST[r][((kc ^ (r & 7))) * 8] = v;                        \
        }
        STAGE(Ahi, lA[0], m0)
        STAGE(Alo, lA[1], m0)
        STAGE(Bhi, lB[0], n0)
        STAGE(Blo, lB[1], n0)
#undef STAGE
        __syncthreads();

#pragma unroll
        for (int ks = 0; ks < 2; ++ks) {
            const int slot = (((ks << 2) | l4) ^ sw) * 8;
            bf16x8 ah[4], al[4], bh[4], bl[4];
#pragma unroll
            for (int f = 0; f < 4; ++f) {
                const int ar = mw + f * 16 + l15;
                const int br = nw + f * 16 + l15;
                ah[f] = *(const bf16x8*)&lA[0][ar][slot];
                al[f] = *(const bf16x8*)&lA[1][ar][slot];
                bh[f] = *(const bf16x8*)&lB[0][br][slot];
                bl[f] = *(const bf16x8*)&lB[1][br][slot];
            }
#pragma unroll
            for (int i = 0; i < 4; ++i)
#pragma unroll
                for (int j = 0; j < 4; ++j) {
                    acc[i][j] = __builtin_amdgcn_mfma_f32_16x16x32_bf16(
                        ah[i], bh[j], acc[i][j], 0, 0, 0);
                    acc[i][j] = __builtin_amdgcn_mfma_f32_16x16x32_bf16(
                        ah[i], bl[j], acc[i][j], 0, 0, 0);
                    acc[i][j] = __builtin_amdgcn_mfma_f32_16x16x32_bf16(
                        al[i], bh[j], acc[i][j], 0, 0, 0);
                }
        }
    }

    // epilogue: C/D map col=lane&15, row=(lane>>4)*4+reg  [m89/m91]
#pragma unroll
    for (int i = 0; i < 4; ++i) {
        const int rowg = m0 + mw + i * 16 + l4 * 4;
#pragma unroll
        for (int j = 0; j < 4; ++j) {
            const int colg = n0 + nw + j * 16 + l15;
            float* base;
            int cc, ldc;
            if (colg < nsplit) { base = C0; cc = colg;          ldc = ldc0; }
            else               { base = C1; cc = colg - nsplit; ldc = ldc1; }
#pragma unroll
            for (int v = 0; v < 4; ++v)
                base[(size_t)(rowg + v) * ldc + cc] = acc[i][j][v];
        }
    }
}

// ---------------------------------------------------------------------------
// fp32 tiled GEMM (kept for the small delta GEMM, K=64)
// ---------------------------------------------------------------------------
__global__ __launch_bounds__(256) void gemm128(
    const float* __restrict__ A, const float* __restrict__ B,
    float* __restrict__ C, int M, int N, int K,
    int lda, int ldb, int ldc,
    const float* __restrict__ bias, int act)
{
    __shared__ float As[16][132];
    __shared__ float Bs[16][132];

    const int t   = threadIdx.x;
    const int bn0 = blockIdx.x * 128;
    const int bm0 = blockIdx.y * 128;
    const int tx  = t & 15;
    const int ty  = t >> 4;

    const int ar  = t >> 2;
    const int ak  = (t & 3) * 4;
    const int bk  = t >> 5;
    const int bn4 = (t & 31) * 4;

    float acc[8][8];
#pragma unroll
    for (int i = 0; i < 8; ++i)
#pragma unroll
        for (int j = 0; j < 8; ++j) acc[i][j] = 0.f;

    for (int k0 = 0; k0 < K; k0 += 16) {
        float4 a0 = *(const float4*)&A[(size_t)(bm0 + ar)      * lda + k0 + ak];
        float4 a1 = *(const float4*)&A[(size_t)(bm0 + ar + 64) * lda + k0 + ak];
        float4 b0 = *(const float4*)&B[(size_t)(k0 + bk)     * ldb + bn0 + bn4];
        float4 b1 = *(const float4*)&B[(size_t)(k0 + bk + 8) * ldb + bn0 + bn4];

        __syncthreads();
        As[ak + 0][ar] = a0.x; As[ak + 1][ar] = a0.y;
        As[ak + 2][ar] = a0.z; As[ak + 3][ar] = a0.w;
        As[ak + 0][ar + 64] = a1.x; As[ak + 1][ar + 64] = a1.y;
        As[ak + 2][ar + 64] = a1.z; As[ak + 3][ar + 64] = a1.w;
        *(float4*)&Bs[bk][bn4]     = b0;
        *(float4*)&Bs[bk + 8][bn4] = b1;
        __syncthreads();

#pragma unroll
        for (int kk = 0; kk < 16; ++kk) {
            float a[8], b[8];
            ((float4*)a)[0] = *(const float4*)&As[kk][ty * 8];
            ((float4*)a)[1] = *(const float4*)&As[kk][ty * 8 + 4];
            ((float4*)b)[0] = *(const float4*)&Bs[kk][tx * 8];
            ((float4*)b)[1] = *(const float4*)&Bs[kk][tx * 8 + 4];
#pragma unroll
            for (int i = 0; i < 8; ++i)
#pragma unroll
                for (int j = 0; j < 8; ++j)
                    acc[i][j] = fmaf(a[i], b[j], acc[i][j]);
        }
    }

    const int row = bm0 + ty * 8;
    const int col = bn0 + tx * 8;
#pragma unroll
    for (int i = 0; i < 8; ++i) {
        float vals[8];
#pragma unroll
        for (int j = 0; j < 8; ++j) {
            float v = acc[i][j];
            if (act == 1) {
                v += bias[col + j];
                v = (v > 20.f) ? v : log1pf(expf(v));
            }
            vals[j] = v;
        }
        *(float4*)&C[(size_t)(row + i) * ldc + col]     = ((float4*)vals)[0];
        *(float4*)&C[(size_t)(row + i) * ldc + col + 4] = ((float4*)vals)[1];
    }
}

// ---------------------------------------------------------------------------
// Depthwise causal conv (K=3) + SiLU.  xi is [SEQ][D_IN] fp32.
// ---------------------------------------------------------------------------
__global__ __launch_bounds__(256) void conv_silu(
    const float* __restrict__ xi, const float* __restrict__ cw,
    float* __restrict__ u)
{
    const int id = blockIdx.x * 256 + threadIdx.x;
    const int l = id >> 11;
    const int d = id & (D_IN - 1);
    const float w0 = cw[d * 3 + 0];
    const float w1 = cw[d * 3 + 1];
    const float w2 = cw[d * 3 + 2];
    const float x0  = xi[(size_t)l * D_IN + d];
    const float xm1 = (l >= 1) ? xi[(size_t)(l - 1) * D_IN + d] : 0.f;
    const float xm2 = (l >= 2) ? xi[(size_t)(l - 2) * D_IN + d] : 0.f;
    const float v = w0 * xm2 + w1 * xm1 + w2 * x0;
    const float s = 1.f / (1.f + expf(-v));
    u[(size_t)l * D_IN + d] = v * s;
}

// ---------------------------------------------------------------------------
// x_dbl = u @ W_x  (M=SEQ, N=96, K=D_IN)
// ---------------------------------------------------------------------------
__global__ __launch_bounds__(128) void gemm_wx(
    const float* __restrict__ u, const float* __restrict__ Wx,
    float* __restrict__ xdbl)
{
    __shared__ float su[4][D_IN];
    const int t  = threadIdx.x;
    const int l0 = blockIdx.x * 4;
#pragma unroll
    for (int q = 0; q < 16; ++q) {
        int idx = q * 128 + t;
        int r   = idx >> 9;
        int c4  = (idx & 511) * 4;
        *(float4*)&su[r][c4] = *(const float4*)&u[(size_t)(l0 + r) * D_IN + c4];
    }
    __syncthreads();
    if (t < XDBL_W) {
        float a0 = 0.f, a1 = 0.f, a2 = 0.f, a3 = 0.f;
#pragma unroll 8
        for (int k = 0; k < D_IN; ++k) {
            const float w = Wx[(size_t)k * XDBL_W + t];
            a0 = fmaf(su[0][k], w, a0);
            a1 = fmaf(su[1][k], w, a1);
            a2 = fmaf(su[2][k], w, a2);
            a3 = fmaf(su[3][k], w, a3);
        }
        xdbl[(size_t)(l0 + 0) * XDBL_W + t] = a0;
        xdbl[(size_t)(l0 + 1) * XDBL_W + t] = a1;
        xdbl[(size_t)(l0 + 2) * XDBL_W + t] = a2;
        xdbl[(size_t)(l0 + 3) * XDBL_W + t] = a3;
    }
}

// ---------------------------------------------------------------------------
// Per-chunk column sums of delta (double)
// ---------------------------------------------------------------------------
__global__ __launch_bounds__(256) void csum64(
    const float* __restrict__ delta, double* __restrict__ csum)
{
    const int d = blockIdx.x * 256 + threadIdx.x;
    const int c = blockIdx.y;
    double s = 0.0;
    for (int i = 0; i < LC; ++i)
        s += (double)delta[(size_t)(c * LC + i) * D_IN + d];
    csum[(size_t)c * D_IN + d] = s;
}

__global__ __launch_bounds__(256) void chunk_prefix(
    const double* __restrict__ csum, double* __restrict__ P0,
    double* __restrict__ Td)
{
    const int d = blockIdx.x * 256 + threadIdx.x;
    double P = 0.0;
    for (int c = 0; c < NCH; ++c) {
        P0[(size_t)c * D_IN + d] = P;
        P += csum[(size_t)c * D_IN + d];
    }
    Td[d] = P;
}

// ---------------------------------------------------------------------------
// Pass A: per-chunk local scan from h=0
// ---------------------------------------------------------------------------
__global__ __launch_bounds__(512) void scan_partA(
    const float* __restrict__ delta, const float* __restrict__ u,
    const float* __restrict__ xdbl, const float* __restrict__ Alog,
    float* __restrict__ hfin)
{
    __shared__ float sdel[LC][DT];
    __shared__ float sU[LC][DT];
    __shared__ float sB[LC][16];

    const int t  = threadIdx.x;
    const int c  = blockIdx.x;
    const int d0 = blockIdx.y * DT;

    {
        int r = t >> 3, c4 = (t & 7) * 4;
        *(float4*)&sdel[r][c4] = *(const float4*)&delta[(size_t)(c * LC + r) * D_IN + d0 + c4];
        *(float4*)&sU[r][c4]   = *(const float4*)&u[(size_t)(c * LC + r) * D_IN + d0 + c4];
    }
    if (t < 256) {
        int r = t >> 2, c4 = (t & 3) * 4;
        *(float4*)&sB[r][c4] = *(const float4*)&xdbl[(size_t)(c * LC + r) * XDBL_W + DT_RANK + c4];
    }
    __syncthreads();

    const int n  = t & 15;
    const int dq = t >> 4;
    const int d  = d0 + dq;
    const float An = -expf(Alog[d * N_STATE + n]);

    float h = 0.f;
#pragma unroll 8
    for (int i = 0; i < LC; ++i) {
        const float dv = sdel[i][dq];
        const float uv = sU[i][dq];
        h = fmaf(h, expf(An * dv), dv * uv * sB[i][n]);
    }
    hfin[((size_t)c * D_IN + d) * N_STATE + n] = h;
}

// ---------------------------------------------------------------------------
// Pass B: serial combine across chunks; hfin becomes incoming state H0.
// ---------------------------------------------------------------------------
__global__ __launch_bounds__(256) void scan_combine(
    float* __restrict__ hfin, const double* __restrict__ csum,
    const float* __restrict__ Alog)
{
    const int id = blockIdx.x * 256 + threadIdx.x;
    const int d = id >> 4;
    const int n = id & 15;
    const float An = -expf(Alog[d * N_STATE + n]);
    float H = 0.f;
    for (int c = 0; c < NCH; ++c) {
        const size_t idx = ((size_t)c * D_IN + d) * N_STATE + n;
        const float hf = hfin[idx];
        hfin[idx] = H;
        const float Dec = expf(An * (float)csum[(size_t)c * D_IN + d]);
        H = fmaf(H, Dec, hf);
    }
}

// ---------------------------------------------------------------------------
// Pass C: scan with incoming state + suffix gate + n-reduce + res-SiLU.
// Plocal in double (exact cancellation at chunk end; see round-3 note).
// ---------------------------------------------------------------------------
__global__ __launch_bounds__(512) void scan_partC(
    const float* __restrict__ delta, const float* __restrict__ u,
    const float* __restrict__ xdbl, const float* __restrict__ H0buf,
    const double* __restrict__ P0, const double* __restrict__ Td,
    const float* __restrict__ Alog, const float* __restrict__ Dvec,
    const float* __restrict__ res, float* __restrict__ yg)
{
    __shared__ float sdel[LC][DT];
    __shared__ float sU[LC][DT];
    __shared__ float sres[LC][DT];
    __shared__ float sB[LC][16];
    __shared__ float sC[LC][16];

    const int t  = threadIdx.x;
    const int c  = blockIdx.x;
    const int d0 = blockIdx.y * DT;

    {
        int r = t >> 3, c4 = (t & 7) * 4;
        *(float4*)&sdel[r][c4] = *(const float4*)&delta[(size_t)(c * LC + r) * D_IN + d0 + c4];
        *(float4*)&sU[r][c4]   = *(const float4*)&u[(size_t)(c * LC + r) * D_IN + d0 + c4];
        *(float4*)&sres[r][c4] = *(const float4*)&res[(size_t)(c * LC + r) * D_IN + d0 + c4];
    }
    if (t < 256) {
        int r = t >> 2, c4 = (t & 3) * 4;
        *(float4*)&sB[r][c4] = *(const float4*)&xdbl[(size_t)(c * LC + r) * XDBL_W + DT_RANK + c4];
        *(float4*)&sC[r][c4] = *(const float4*)&xdbl[(size_t)(c * LC + r) * XDBL_W + DT_RANK + 16 + c4];
    }
    __syncthreads();

    const int n  = t & 15;
    const int dq = t >> 4;
    const int d  = d0 + dq;
    const float An = -expf(Alog[d * N_STATE + n]);
    const float Dd = Dvec[d];
    const double sfxbase = Td[d] - P0[(size_t)c * D_IN + d];

    float h = H0buf[((size_t)c * D_IN + d) * N_STATE + n];
    double Plocal = 0.0;

    for (int i = 0; i < LC; ++i) {
        const float dv = sdel[i][dq];
        const float uv = sU[i][dq];
        Plocal += (double)dv;
        const float sfx = fmaxf((float)(sfxbase - Plocal), 0.f);
        const float E   = expf(An * sfx);
        const float g   = E / (E + 1e-12f);
        h = fmaf(h, expf(An * dv), dv * uv * sB[i][n]);
        float contrib = h * g * sC[i][n];
        contrib += __shfl_xor(contrib, 1);
        contrib += __shfl_xor(contrib, 2);
        contrib += __shfl_xor(contrib, 4);
        contrib += __shfl_xor(contrib, 8);
        if (n == 0) {
            const float r  = sres[i][dq];
            const float sg = 1.f / (1.f + expf(-r));
            yg[(size_t)(c * LC + i) * D_IN + d] = (contrib + uv * Dd) * (r * sg);
        }
    }
}

// ---------------------------------------------------------------------------
// Launch.  Workspace layout (73.2 MB, time-multiplexed aliases):
//   [ 0        ,16.78MB): xi (f32)            -> later yg_hi/yg_lo (bf16)
//   [16.78     ,33.55 ): res (f32)
//   [33.55     ,50.33 ): x_hi/x_lo (bf16)     -> u (f32) -> wo_hi/wo_lo (bf16)
//   [50.33     ,51.12 ): xdbl
//   [51.12     ,67.90 ): wi_hi/wi_lo (bf16)   -> delta/yg (f32)
//   [67.90     ,73.15 ): hfin, csum, P0, Td
// ---------------------------------------------------------------------------
extern "C" void kernel_launch(void* const* d_in, const int* in_sizes, int n_in,
                              void* d_out, int out_size, void* d_ws, size_t ws_size,
                              hipStream_t stream)
{
    const float* x      = (const float*)d_in[0];
    const float* W_in   = (const float*)d_in[1];
    const float* conv_w = (const float*)d_in[2];
    const float* W_x    = (const float*)d_in[3];
    const float* W_del  = (const float*)d_in[4];
    const float* b_del  = (const float*)d_in[5];
    const float* A_log  = (const float*)d_in[6];
    const float* Dv     = (const float*)d_in[7];
    const float* W_out  = (const float*)d_in[8];
    float* out = (float*)d_out;

    char* ws = (char*)d_ws;
    float*  xi    = (float*)(ws + 0);
    ushort* yg_hi = (ushort*)(ws + 0);
    ushort* yg_lo = (ushort*)(ws + 8388608);
    float*  res   = (float*)(ws + 16777216);
    ushort* x_hi  = (ushort*)(ws + 33554432);
    ushort* x_lo  = (ushort*)(ws + 37748736);
    float*  u     = (float*)(ws + 33554432);
    ushort* wo_hi = (ushort*)(ws + 33554432);
    ushort* wo_lo = (ushort*)(ws + 37748736);
    float*  xdbl  = (float*)(ws + 50331648);
    ushort* wi_hi = (ushort*)(ws + 51118080);
    ushort* wi_lo = (ushort*)(ws + 59506688);
    float*  delta = (float*)(ws + 51118080);
    float*  hfin  = (float*)(ws + 67895296);
    double* csum  = (double*)(ws + 72089600);
    double* P0    = (double*)(ws + 72613888);
    double* Td    = (double*)(ws + 73138176);
    float*  yg    = delta;   // pass C stages reads to LDS before writing

    // 1) W_in^T split (1024x4096 -> [4096][1024] bf16 hi/lo)
    split_transpose<<<dim3(4096 / 32, 1024 / 32), 256, 0, stream>>>(
        W_in, wi_hi, wi_lo, 1024, 4096);

    // 2) x split (2048x1024)
    split_bf16<<<(SEQ * D_MODEL / 4) / 256, 256, 0, stream>>>(x, x_hi, x_lo);

    // 3) [xi | res] = x @ W_in   (MFMA, split at col 2048)
    gemm_mfma3<<<dim3(4096 / 128, 2048 / 128), 256, 0, stream>>>(
        x_hi, x_lo, wi_hi, wi_lo, xi, res, D_IN,
        SEQ, 2 * D_IN, D_MODEL, D_IN, D_IN);

    // 4) u = silu(depthwise_conv(xi))   (overwrites x_hi/x_lo region)
    conv_silu<<<(SEQ * D_IN) / 256, 256, 0, stream>>>(xi, conv_w, u);

    // 5) x_dbl = u @ W_x
    gemm_wx<<<SEQ / 4, 128, 0, stream>>>(u, W_x, xdbl);

    // 6) delta = softplus(delta_lr @ W_delta + b_delta)  (overwrites wi_hi/lo)
    gemm128<<<dim3(2048 / 128, 2048 / 128), 256, 0, stream>>>(
        xdbl, W_del, delta, SEQ, D_IN, DT_RANK, XDBL_W, D_IN, D_IN,
        b_del, 1);

    // 7) chunk sums + prefix (double)
    csum64<<<dim3(D_IN / 256, NCH), 256, 0, stream>>>(delta, csum);
    chunk_prefix<<<D_IN / 256, 256, 0, stream>>>(csum, P0, Td);

    // 8) chunk-parallel selective scan
    scan_partA<<<dim3(NCH, D_IN / DT), 512, 0, stream>>>(delta, u, xdbl, A_log, hfin);
    scan_combine<<<(D_IN * N_STATE) / 256, 256, 0, stream>>>(hfin, csum, A_log);
    scan_partC<<<dim3(NCH, D_IN / DT), 512, 0, stream>>>(
        delta, u, xdbl, hfin, P0, Td, A_log, Dv, res, yg);

    // 9) yg split (2048x2048, into dead xi region)
    split_bf16<<<(SEQ * D_IN / 4) / 256, 256, 0, stream>>>(yg, yg_hi, yg_lo);

    // 10) W_out^T split (2048x1024 -> [1024][2048] bf16 hi/lo, dead u region)
    split_transpose<<<dim3(1024 / 32, 2048 / 32), 256, 0, stream>>>(
        W_out, wo_hi, wo_lo, 2048, 1024);

    // 11) out = yg @ W_out  (MFMA)
    gemm_mfma3<<<dim3(1024 / 128, 2048 / 128), 256, 0, stream>>>(
        yg_hi, yg_lo, wo_hi, wo_lo, out, out, D_MODEL,
        SEQ, D_MODEL, D_IN, D_MODEL, D_MODEL);
}

// Round 5
// 373.445 us; speedup vs baseline: 3.7257x; 1.1640x over previous
//
#include <hip/hip_runtime.h>
#include <hip/hip_bf16.h>
#include <math.h>

// ---------------------------------------------------------------------------
// Shapes (compile-time constants for this problem)
// ---------------------------------------------------------------------------
#define SEQ     2048
#define D_MODEL 1024
#define D_IN    2048
#define N_STATE 16
#define DT_RANK 64
#define XDBL_W  96          // DT_RANK + 2*N_STATE
#define LC      64          // scan chunk length
#define NCH     32          // SEQ / LC
#define DT      32          // d-channels per scan block

#define LOG2E   1.4426950408889634f

typedef __attribute__((ext_vector_type(8))) short bf16x8;
typedef __attribute__((ext_vector_type(4))) float f32x4;

__device__ __forceinline__ float fast_exp2(float x) { return __builtin_amdgcn_exp2f(x); }
__device__ __forceinline__ float fast_rcp(float x)  { return __builtin_amdgcn_rcpf(x); }

__device__ __forceinline__ ushort f2bf(float x) {
    unsigned u = __float_as_uint(x);
    u += 0x7FFFu + ((u >> 16) & 1u);      // RNE
    return (ushort)(u >> 16);
}
__device__ __forceinline__ float bf2f(ushort h) {
    return __uint_as_float(((unsigned)h) << 16);
}

// ---------------------------------------------------------------------------
// split fp32 -> bf16 hi/lo (elementwise). One float4 per thread.
// ---------------------------------------------------------------------------
__global__ __launch_bounds__(256) void split_bf16(
    const float* __restrict__ in, ushort* __restrict__ hi,
    ushort* __restrict__ lo)
{
    const int i = blockIdx.x * 256 + threadIdx.x;
    const float4 v = *(const float4*)&in[(size_t)i * 4];
    ushort4 h, l;
    h.x = f2bf(v.x); l.x = f2bf(v.x - bf2f(h.x));
    h.y = f2bf(v.y); l.y = f2bf(v.y - bf2f(h.y));
    h.z = f2bf(v.z); l.z = f2bf(v.z - bf2f(h.z));
    h.w = f2bf(v.w); l.w = f2bf(v.w - bf2f(h.w));
    *(ushort4*)&hi[(size_t)i * 4] = h;
    *(ushort4*)&lo[(size_t)i * 4] = l;
}

// ---------------------------------------------------------------------------
// split + transpose: in[R][C] fp32 -> hi/lo[C][R] bf16.
// ---------------------------------------------------------------------------
__global__ __launch_bounds__(256) void split_transpose(
    const float* __restrict__ in, ushort* __restrict__ hi,
    ushort* __restrict__ lo, int R, int C)
{
    __shared__ float tile[32][33];
    const int c0 = blockIdx.x * 32;
    const int r0 = blockIdx.y * 32;
    const int tc = threadIdx.x & 31;
    const int tr = threadIdx.x >> 5;
#pragma unroll
    for (int q = 0; q < 4; ++q)
        tile[tr + 8 * q][tc] = in[(size_t)(r0 + tr + 8 * q) * C + c0 + tc];
    __syncthreads();
#pragma unroll
    for (int q = 0; q < 4; ++q) {
        const float v = tile[tc][tr + 8 * q];
        const ushort h = f2bf(v);
        const ushort l = f2bf(v - bf2f(h));
        const size_t o = (size_t)(c0 + tr + 8 * q) * R + r0 + tc;
        hi[o] = h;
        lo[o] = l;
    }
}

// ---------------------------------------------------------------------------
// bf16x3-split MFMA GEMM (A row-major hi/lo, B transposed hi/lo).
// acc += Ahi*Bhi + Ahi*Blo + Alo*Bhi.  Tile 128x128, K-step 64, 4 waves.
// ---------------------------------------------------------------------------
__global__ __launch_bounds__(256) void gemm_mfma3(
    const ushort* __restrict__ Ahi, const ushort* __restrict__ Alo,
    const ushort* __restrict__ Bhi, const ushort* __restrict__ Blo,
    float* __restrict__ C0, float* __restrict__ C1, int nsplit,
    int M, int N, int K, int ldc0, int ldc1)
{
    __shared__ ushort lA[2][128][64];
    __shared__ ushort lB[2][128][64];

    const int t    = threadIdx.x;
    const int m0   = blockIdx.y * 128;
    const int n0   = blockIdx.x * 128;
    const int wave = t >> 6;
    const int lane = t & 63;
    const int mw   = (wave & 1) * 64;
    const int nw   = (wave >> 1) * 64;
    const int l15  = lane & 15;
    const int l4   = lane >> 4;
    const int sw   = l15 & 7;

    f32x4 acc[4][4];
#pragma unroll
    for (int i = 0; i < 4; ++i)
#pragma unroll
        for (int j = 0; j < 4; ++j)
            acc[i][j] = (f32x4){0.f, 0.f, 0.f, 0.f};

    for (int k0 = 0; k0 < K; k0 += 64) {
        __syncthreads();
#define STAGE(SRC, DST, BASE)                                                  \
        _Pragma("unroll")                                                      \
        for (int q = 0; q < 4; ++q) {                                          \
            const int idx = q * 256 + t;                                       \
            const int r = idx >> 3, kc = idx & 7;                              \
            const uint4 v =                                                    \
                *(const uint4*)&SRC[(size_t)(BASE + r) * K + k0 + kc * 8];     \
            *(uint4*)&DST[r][((kc ^ (r & 7))) * 8] = v;                        \
        }
        STAGE(Ahi, lA[0], m0)
        STAGE(Alo, lA[1], m0)
        STAGE(Bhi, lB[0], n0)
        STAGE(Blo, lB[1], n0)
#undef STAGE
        __syncthreads();

#pragma unroll
        for (int ks = 0; ks < 2; ++ks) {
            const int slot = (((ks << 2) | l4) ^ sw) * 8;
            bf16x8 ah[4], al[4], bh[4], bl[4];
#pragma unroll
            for (int f = 0; f < 4; ++f) {
                const int ar = mw + f * 16 + l15;
                const int br = nw + f * 16 + l15;
                ah[f] = *(const bf16x8*)&lA[0][ar][slot];
                al[f] = *(const bf16x8*)&lA[1][ar][slot];
                bh[f] = *(const bf16x8*)&lB[0][br][slot];
                bl[f] = *(const bf16x8*)&lB[1][br][slot];
            }
#pragma unroll
            for (int i = 0; i < 4; ++i)
#pragma unroll
                for (int j = 0; j < 4; ++j) {
                    acc[i][j] = __builtin_amdgcn_mfma_f32_16x16x32_bf16(
                        ah[i], bh[j], acc[i][j], 0, 0, 0);
                    acc[i][j] = __builtin_amdgcn_mfma_f32_16x16x32_bf16(
                        ah[i], bl[j], acc[i][j], 0, 0, 0);
                    acc[i][j] = __builtin_amdgcn_mfma_f32_16x16x32_bf16(
                        al[i], bh[j], acc[i][j], 0, 0, 0);
                }
        }
    }

#pragma unroll
    for (int i = 0; i < 4; ++i) {
        const int rowg = m0 + mw + i * 16 + l4 * 4;
#pragma unroll
        for (int j = 0; j < 4; ++j) {
            const int colg = n0 + nw + j * 16 + l15;
            float* base;
            int cc, ldc;
            if (colg < nsplit) { base = C0; cc = colg;          ldc = ldc0; }
            else               { base = C1; cc = colg - nsplit; ldc = ldc1; }
#pragma unroll
            for (int v = 0; v < 4; ++v)
                base[(size_t)(rowg + v) * ldc + cc] = acc[i][j][v];
        }
    }
}

// ---------------------------------------------------------------------------
// fp32 tiled GEMM (small delta GEMM, K=64)
// ---------------------------------------------------------------------------
__global__ __launch_bounds__(256) void gemm128(
    const float* __restrict__ A, const float* __restrict__ B,
    float* __restrict__ C, int M, int N, int K,
    int lda, int ldb, int ldc,
    const float* __restrict__ bias, int act)
{
    __shared__ float As[16][132];
    __shared__ float Bs[16][132];

    const int t   = threadIdx.x;
    const int bn0 = blockIdx.x * 128;
    const int bm0 = blockIdx.y * 128;
    const int tx  = t & 15;
    const int ty  = t >> 4;

    const int ar  = t >> 2;
    const int ak  = (t & 3) * 4;
    const int bk  = t >> 5;
    const int bn4 = (t & 31) * 4;

    float acc[8][8];
#pragma unroll
    for (int i = 0; i < 8; ++i)
#pragma unroll
        for (int j = 0; j < 8; ++j) acc[i][j] = 0.f;

    for (int k0 = 0; k0 < K; k0 += 16) {
        float4 a0 = *(const float4*)&A[(size_t)(bm0 + ar)      * lda + k0 + ak];
        float4 a1 = *(const float4*)&A[(size_t)(bm0 + ar + 64) * lda + k0 + ak];
        float4 b0 = *(const float4*)&B[(size_t)(k0 + bk)     * ldb + bn0 + bn4];
        float4 b1 = *(const float4*)&B[(size_t)(k0 + bk + 8) * ldb + bn0 + bn4];

        __syncthreads();
        As[ak + 0][ar] = a0.x; As[ak + 1][ar] = a0.y;
        As[ak + 2][ar] = a0.z; As[ak + 3][ar] = a0.w;
        As[ak + 0][ar + 64] = a1.x; As[ak + 1][ar + 64] = a1.y;
        As[ak + 2][ar + 64] = a1.z; As[ak + 3][ar + 64] = a1.w;
        *(float4*)&Bs[bk][bn4]     = b0;
        *(float4*)&Bs[bk + 8][bn4] = b1;
        __syncthreads();

#pragma unroll
        for (int kk = 0; kk < 16; ++kk) {
            float a[8], b[8];
            ((float4*)a)[0] = *(const float4*)&As[kk][ty * 8];
            ((float4*)a)[1] = *(const float4*)&As[kk][ty * 8 + 4];
            ((float4*)b)[0] = *(const float4*)&Bs[kk][tx * 8];
            ((float4*)b)[1] = *(const float4*)&Bs[kk][tx * 8 + 4];
#pragma unroll
            for (int i = 0; i < 8; ++i)
#pragma unroll
                for (int j = 0; j < 8; ++j)
                    acc[i][j] = fmaf(a[i], b[j], acc[i][j]);
        }
    }

    const int row = bm0 + ty * 8;
    const int col = bn0 + tx * 8;
#pragma unroll
    for (int i = 0; i < 8; ++i) {
        float vals[8];
#pragma unroll
        for (int j = 0; j < 8; ++j) {
            float v = acc[i][j];
            if (act == 1) {
                v += bias[col + j];
                v = (v > 20.f) ? v : log1pf(__expf(v));
            }
            vals[j] = v;
        }
        *(float4*)&C[(size_t)(row + i) * ldc + col]     = ((float4*)vals)[0];
        *(float4*)&C[(size_t)(row + i) * ldc + col + 4] = ((float4*)vals)[1];
    }
}

// ---------------------------------------------------------------------------
// Depthwise causal conv (K=3) + SiLU.  xi is [SEQ][D_IN] fp32.
// ---------------------------------------------------------------------------
__global__ __launch_bounds__(256) void conv_silu(
    const float* __restrict__ xi, const float* __restrict__ cw,
    float* __restrict__ u)
{
    const int id = blockIdx.x * 256 + threadIdx.x;
    const int l = id >> 11;
    const int d = id & (D_IN - 1);
    const float w0 = cw[d * 3 + 0];
    const float w1 = cw[d * 3 + 1];
    const float w2 = cw[d * 3 + 2];
    const float x0  = xi[(size_t)l * D_IN + d];
    const float xm1 = (l >= 1) ? xi[(size_t)(l - 1) * D_IN + d] : 0.f;
    const float xm2 = (l >= 2) ? xi[(size_t)(l - 2) * D_IN + d] : 0.f;
    const float v = w0 * xm2 + w1 * xm1 + w2 * x0;
    const float s = fast_rcp(1.f + fast_exp2(-LOG2E * v));
    u[(size_t)l * D_IN + d] = v * s;
}

// ---------------------------------------------------------------------------
// x_dbl = u @ W_x  (M=SEQ, N=96, K=D_IN)
// ---------------------------------------------------------------------------
__global__ __launch_bounds__(128) void gemm_wx(
    const float* __restrict__ u, const float* __restrict__ Wx,
    float* __restrict__ xdbl)
{
    __shared__ float su[4][D_IN];
    const int t  = threadIdx.x;
    const int l0 = blockIdx.x * 4;
#pragma unroll
    for (int q = 0; q < 16; ++q) {
        int idx = q * 128 + t;
        int r   = idx >> 9;
        int c4  = (idx & 511) * 4;
        *(float4*)&su[r][c4] = *(const float4*)&u[(size_t)(l0 + r) * D_IN + c4];
    }
    __syncthreads();
    if (t < XDBL_W) {
        float a0 = 0.f, a1 = 0.f, a2 = 0.f, a3 = 0.f;
#pragma unroll 8
        for (int k = 0; k < D_IN; ++k) {
            const float w = Wx[(size_t)k * XDBL_W + t];
            a0 = fmaf(su[0][k], w, a0);
            a1 = fmaf(su[1][k], w, a1);
            a2 = fmaf(su[2][k], w, a2);
            a3 = fmaf(su[3][k], w, a3);
        }
        xdbl[(size_t)(l0 + 0) * XDBL_W + t] = a0;
        xdbl[(size_t)(l0 + 1) * XDBL_W + t] = a1;
        xdbl[(size_t)(l0 + 2) * XDBL_W + t] = a2;
        xdbl[(size_t)(l0 + 3) * XDBL_W + t] = a3;
    }
}

// ---------------------------------------------------------------------------
// Per-chunk column sums of delta (double)
// ---------------------------------------------------------------------------
__global__ __launch_bounds__(256) void csum64(
    const float* __restrict__ delta, double* __restrict__ csum)
{
    const int d = blockIdx.x * 256 + threadIdx.x;
    const int c = blockIdx.y;
    double s = 0.0;
    for (int i = 0; i < LC; ++i)
        s += (double)delta[(size_t)(c * LC + i) * D_IN + d];
    csum[(size_t)c * D_IN + d] = s;
}

__global__ __launch_bounds__(256) void chunk_prefix(
    const double* __restrict__ csum, double* __restrict__ P0,
    double* __restrict__ Td)
{
    const int d = blockIdx.x * 256 + threadIdx.x;
    double P = 0.0;
    for (int c = 0; c < NCH; ++c) {
        P0[(size_t)c * D_IN + d] = P;
        P += csum[(size_t)c * D_IN + d];
    }
    Td[d] = P;
}

// ---------------------------------------------------------------------------
// sfx[l][d] = float(max(Td - P_inclusive(l), 0))  -- double bookkeeping done
// ONCE per (l,d) here instead of x16 in the scan hot loop. Clamp-at-store
// guarantees An*sfx <= 0 downstream (no +inf/NaN path).
// ---------------------------------------------------------------------------
__global__ __launch_bounds__(256) void sfx_precompute(
    const float* __restrict__ delta, const double* __restrict__ P0,
    const double* __restrict__ Td, float* __restrict__ sfx)
{
    const int d = blockIdx.x * 256 + threadIdx.x;
    const int c = blockIdx.y;
    double P = P0[(size_t)c * D_IN + d];
    const double T = Td[d];
    for (int i = 0; i < LC; ++i) {
        P += (double)delta[(size_t)(c * LC + i) * D_IN + d];
        sfx[(size_t)(c * LC + i) * D_IN + d] = (float)fmax(T - P, 0.0);
    }
}

// ---------------------------------------------------------------------------
// Pass A: per-chunk local scan from h=0 (native exp2, staged delta & delta*u)
// ---------------------------------------------------------------------------
__global__ __launch_bounds__(512) void scan_partA(
    const float* __restrict__ delta, const float* __restrict__ u,
    const float* __restrict__ xdbl, const float* __restrict__ Alog,
    float* __restrict__ hfin)
{
    __shared__ float sdel[LC][DT];
    __shared__ float sdu[LC][DT];
    __shared__ float sB[LC][16];

    const int t  = threadIdx.x;
    const int c  = blockIdx.x;
    const int d0 = blockIdx.y * DT;

    {
        int r = t >> 3, c4 = (t & 7) * 4;
        const float4 dv4 = *(const float4*)&delta[(size_t)(c * LC + r) * D_IN + d0 + c4];
        const float4 uv4 = *(const float4*)&u[(size_t)(c * LC + r) * D_IN + d0 + c4];
        *(float4*)&sdel[r][c4] = dv4;
        float4 du4;
        du4.x = dv4.x * uv4.x; du4.y = dv4.y * uv4.y;
        du4.z = dv4.z * uv4.z; du4.w = dv4.w * uv4.w;
        *(float4*)&sdu[r][c4] = du4;
    }
    if (t < 256) {
        int r = t >> 2, c4 = (t & 3) * 4;
        *(float4*)&sB[r][c4] = *(const float4*)&xdbl[(size_t)(c * LC + r) * XDBL_W + DT_RANK + c4];
    }
    __syncthreads();

    const int n  = t & 15;
    const int dq = t >> 4;
    const int d  = d0 + dq;
    const float An2 = -expf(Alog[d * N_STATE + n]) * LOG2E;

    float h = 0.f;
#pragma unroll 8
    for (int i = 0; i < LC; ++i)
        h = fmaf(h, fast_exp2(An2 * sdel[i][dq]), sdu[i][dq] * sB[i][n]);
    hfin[((size_t)c * D_IN + d) * N_STATE + n] = h;
}

// ---------------------------------------------------------------------------
// Pass B: serial combine across chunks; hfin becomes incoming state H0.
// ---------------------------------------------------------------------------
__global__ __launch_bounds__(256) void scan_combine(
    float* __restrict__ hfin, const double* __restrict__ csum,
    const float* __restrict__ Alog)
{
    const int id = blockIdx.x * 256 + threadIdx.x;
    const int d = id >> 4;
    const int n = id & 15;
    const float An2 = -expf(Alog[d * N_STATE + n]) * LOG2E;
    float H = 0.f;
    for (int c = 0; c < NCH; ++c) {
        const size_t idx = ((size_t)c * D_IN + d) * N_STATE + n;
        const float hf = hfin[idx];
        hfin[idx] = H;
        const float Dec = fast_exp2(An2 * (float)csum[(size_t)c * D_IN + d]);
        H = fmaf(H, Dec, hf);
    }
}

// ---------------------------------------------------------------------------
// Pass C: scan with incoming state + precomputed suffix gate + n-reduce +
// res-SiLU. All transcendentals native (v_exp_f32 / v_rcp_f32).
// ---------------------------------------------------------------------------
__global__ __launch_bounds__(512) void scan_partC(
    const float* __restrict__ delta, const float* __restrict__ u,
    const float* __restrict__ xdbl, const float* __restrict__ H0buf,
    const float* __restrict__ sfxbuf, const float* __restrict__ Alog,
    const float* __restrict__ Dvec, const float* __restrict__ res,
    float* __restrict__ yg)
{
    __shared__ float sdel[LC][DT];
    __shared__ float sU[LC][DT];
    __shared__ float sres[LC][DT];
    __shared__ float ssfx[LC][DT];
    __shared__ float sB[LC][16];
    __shared__ float sC[LC][16];

    const int t  = threadIdx.x;
    const int c  = blockIdx.x;
    const int d0 = blockIdx.y * DT;

    {
        int r = t >> 3, c4 = (t & 7) * 4;
        const size_t row = (size_t)(c * LC + r) * D_IN + d0 + c4;
        *(float4*)&sdel[r][c4] = *(const float4*)&delta[row];
        *(float4*)&sU[r][c4]   = *(const float4*)&u[row];
        *(float4*)&sres[r][c4] = *(const float4*)&res[row];
        *(float4*)&ssfx[r][c4] = *(const float4*)&sfxbuf[row];
    }
    if (t < 256) {
        int r = t >> 2, c4 = (t & 3) * 4;
        *(float4*)&sB[r][c4] = *(const float4*)&xdbl[(size_t)(c * LC + r) * XDBL_W + DT_RANK + c4];
        *(float4*)&sC[r][c4] = *(const float4*)&xdbl[(size_t)(c * LC + r) * XDBL_W + DT_RANK + 16 + c4];
    }
    __syncthreads();

    const int n  = t & 15;
    const int dq = t >> 4;
    const int d  = d0 + dq;
    const float An2 = -expf(Alog[d * N_STATE + n]) * LOG2E;
    const float Dd = Dvec[d];

    float h = H0buf[((size_t)c * D_IN + d) * N_STATE + n];

    for (int i = 0; i < LC; ++i) {
        const float dv = sdel[i][dq];
        const float uv = sU[i][dq];
        const float E  = fast_exp2(An2 * ssfx[i][dq]);
        const float g  = E * fast_rcp(E + 1e-12f);
        h = fmaf(h, fast_exp2(An2 * dv), dv * uv * sB[i][n]);
        float contrib = h * g * sC[i][n];
        contrib += __shfl_xor(contrib, 1);
        contrib += __shfl_xor(contrib, 2);
        contrib += __shfl_xor(contrib, 4);
        contrib += __shfl_xor(contrib, 8);
        if (n == 0) {
            const float r  = sres[i][dq];
            const float sg = fast_rcp(1.f + fast_exp2(-LOG2E * r));
            yg[(size_t)(c * LC + i) * D_IN + d] = (contrib + uv * Dd) * (r * sg);
        }
    }
}

// ---------------------------------------------------------------------------
// Launch.  Workspace (73.2 MB, time-multiplexed):
//   [ 0    ,16.78): xi (f32) -> sfx (f32, after conv) -> yg_hi/lo (bf16)
//   [16.78 ,33.55): res (f32)
//   [33.55 ,50.33): x_hi/x_lo (bf16) -> u (f32) -> wo_hi/wo_lo (bf16)
//   [50.33 ,51.12): xdbl
//   [51.12 ,67.90): wi_hi/wi_lo (bf16) -> delta/yg (f32)
//   [67.90 ,73.15): hfin, csum, P0, Td
// ---------------------------------------------------------------------------
extern "C" void kernel_launch(void* const* d_in, const int* in_sizes, int n_in,
                              void* d_out, int out_size, void* d_ws, size_t ws_size,
                              hipStream_t stream)
{
    const float* x      = (const float*)d_in[0];
    const float* W_in   = (const float*)d_in[1];
    const float* conv_w = (const float*)d_in[2];
    const float* W_x    = (const float*)d_in[3];
    const float* W_del  = (const float*)d_in[4];
    const float* b_del  = (const float*)d_in[5];
    const float* A_log  = (const float*)d_in[6];
    const float* Dv     = (const float*)d_in[7];
    const float* W_out  = (const float*)d_in[8];
    float* out = (float*)d_out;

    char* ws = (char*)d_ws;
    float*  xi    = (float*)(ws + 0);
    float*  sfx   = (float*)(ws + 0);
    ushort* yg_hi = (ushort*)(ws + 0);
    ushort* yg_lo = (ushort*)(ws + 8388608);
    float*  res   = (float*)(ws + 16777216);
    ushort* x_hi  = (ushort*)(ws + 33554432);
    ushort* x_lo  = (ushort*)(ws + 37748736);
    float*  u     = (float*)(ws + 33554432);
    ushort* wo_hi = (ushort*)(ws + 33554432);
    ushort* wo_lo = (ushort*)(ws + 37748736);
    float*  xdbl  = (float*)(ws + 50331648);
    ushort* wi_hi = (ushort*)(ws + 51118080);
    ushort* wi_lo = (ushort*)(ws + 59506688);
    float*  delta = (float*)(ws + 51118080);
    float*  hfin  = (float*)(ws + 67895296);
    double* csum  = (double*)(ws + 72089600);
    double* P0    = (double*)(ws + 72613888);
    double* Td    = (double*)(ws + 73138176);
    float*  yg    = delta;   // pass C stages reads to LDS before writing

    // 1) W_in^T split
    split_transpose<<<dim3(4096 / 32, 1024 / 32), 256, 0, stream>>>(
        W_in, wi_hi, wi_lo, 1024, 4096);

    // 2) x split
    split_bf16<<<(SEQ * D_MODEL / 4) / 256, 256, 0, stream>>>(x, x_hi, x_lo);

    // 3) [xi | res] = x @ W_in
    gemm_mfma3<<<dim3(4096 / 128, 2048 / 128), 256, 0, stream>>>(
        x_hi, x_lo, wi_hi, wi_lo, xi, res, D_IN,
        SEQ, 2 * D_IN, D_MODEL, D_IN, D_IN);

    // 4) u = silu(depthwise_conv(xi))
    conv_silu<<<(SEQ * D_IN) / 256, 256, 0, stream>>>(xi, conv_w, u);

    // 5) x_dbl = u @ W_x
    gemm_wx<<<SEQ / 4, 128, 0, stream>>>(u, W_x, xdbl);

    // 6) delta = softplus(delta_lr @ W_delta + b_delta)
    gemm128<<<dim3(2048 / 128, 2048 / 128), 256, 0, stream>>>(
        xdbl, W_del, delta, SEQ, D_IN, DT_RANK, XDBL_W, D_IN, D_IN,
        b_del, 1);

    // 7) chunk sums + prefix + per-element suffix (double, deterministic)
    csum64<<<dim3(D_IN / 256, NCH), 256, 0, stream>>>(delta, csum);
    chunk_prefix<<<D_IN / 256, 256, 0, stream>>>(csum, P0, Td);
    sfx_precompute<<<dim3(D_IN / 256, NCH), 256, 0, stream>>>(delta, P0, Td, sfx);

    // 8) chunk-parallel selective scan
    scan_partA<<<dim3(NCH, D_IN / DT), 512, 0, stream>>>(delta, u, xdbl, A_log, hfin);
    scan_combine<<<(D_IN * N_STATE) / 256, 256, 0, stream>>>(hfin, csum, A_log);
    scan_partC<<<dim3(NCH, D_IN / DT), 512, 0, stream>>>(
        delta, u, xdbl, hfin, sfx, A_log, Dv, res, yg);

    // 9) yg split (sfx is dead now; region reused)
    split_bf16<<<(SEQ * D_IN / 4) / 256, 256, 0, stream>>>(yg, yg_hi, yg_lo);

    // 10) W_out^T split
    split_transpose<<<dim3(1024 / 32, 2048 / 32), 256, 0, stream>>>(
        W_out, wo_hi, wo_lo, 2048, 1024);

    // 11) out = yg @ W_out
    gemm_mfma3<<<dim3(1024 / 128, 2048 / 128), 256, 0, stream>>>(
        yg_hi, yg_lo, wo_hi, wo_lo, out, out, D_MODEL,
        SEQ, D_MODEL, D_IN, D_MODEL, D_MODEL);
}

// Round 6
// 321.440 us; speedup vs baseline: 4.3285x; 1.1618x over previous
//
#include <hip/hip_runtime.h>
#include <hip/hip_bf16.h>
#include <math.h>

// ---------------------------------------------------------------------------
// Shapes (compile-time constants for this problem)
// ---------------------------------------------------------------------------
#define SEQ     2048
#define D_MODEL 1024
#define D_IN    2048
#define N_STATE 16
#define DT_RANK 64
#define XDBL_W  96          // DT_RANK + 2*N_STATE
#define XDBL_LD 128         // padded leading dim of x_dbl
#define LC      64          // scan chunk length
#define NCH     32          // SEQ / LC
#define DT      32          // d-channels per scan block
#define WX_KSPLIT 16
#define WX_KSEG   (D_IN / WX_KSPLIT)   // 128

#define LOG2E   1.4426950408889634f

typedef __attribute__((ext_vector_type(8))) short bf16x8;
typedef __attribute__((ext_vector_type(4))) float f32x4;

__device__ __forceinline__ float fast_exp2(float x) { return __builtin_amdgcn_exp2f(x); }
__device__ __forceinline__ float fast_rcp(float x)  { return __builtin_amdgcn_rcpf(x); }

__device__ __forceinline__ ushort f2bf(float x) {
    unsigned u = __float_as_uint(x);
    u += 0x7FFFu + ((u >> 16) & 1u);      // RNE
    return (ushort)(u >> 16);
}
__device__ __forceinline__ float bf2f(ushort h) {
    return __uint_as_float(((unsigned)h) << 16);
}

// ---------------------------------------------------------------------------
// split fp32 -> bf16 hi/lo (elementwise). One float4 per thread.
// ---------------------------------------------------------------------------
__global__ __launch_bounds__(256) void split_bf16(
    const float* __restrict__ in, ushort* __restrict__ hi,
    ushort* __restrict__ lo)
{
    const int i = blockIdx.x * 256 + threadIdx.x;
    const float4 v = *(const float4*)&in[(size_t)i * 4];
    ushort4 h, l;
    h.x = f2bf(v.x); l.x = f2bf(v.x - bf2f(h.x));
    h.y = f2bf(v.y); l.y = f2bf(v.y - bf2f(h.y));
    h.z = f2bf(v.z); l.z = f2bf(v.z - bf2f(h.z));
    h.w = f2bf(v.w); l.w = f2bf(v.w - bf2f(h.w));
    *(ushort4*)&hi[(size_t)i * 4] = h;
    *(ushort4*)&lo[(size_t)i * 4] = l;
}

// ---------------------------------------------------------------------------
// split + transpose: in[R][C] fp32 -> hi/lo[C][R] bf16.
// ---------------------------------------------------------------------------
__global__ __launch_bounds__(256) void split_transpose(
    const float* __restrict__ in, ushort* __restrict__ hi,
    ushort* __restrict__ lo, int R, int C)
{
    __shared__ float tile[32][33];
    const int c0 = blockIdx.x * 32;
    const int r0 = blockIdx.y * 32;
    const int tc = threadIdx.x & 31;
    const int tr = threadIdx.x >> 5;
#pragma unroll
    for (int q = 0; q < 4; ++q)
        tile[tr + 8 * q][tc] = in[(size_t)(r0 + tr + 8 * q) * C + c0 + tc];
    __syncthreads();
#pragma unroll
    for (int q = 0; q < 4; ++q) {
        const float v = tile[tc][tr + 8 * q];
        const ushort h = f2bf(v);
        const ushort l = f2bf(v - bf2f(h));
        const size_t o = (size_t)(c0 + tr + 8 * q) * R + r0 + tc;
        hi[o] = h;
        lo[o] = l;
    }
}

// ---------------------------------------------------------------------------
// split + transpose with zero padding on the output-row (source-col) axis:
// in[R][Csrc] fp32 -> hi/lo[Cpad][R] bf16, rows >= Csrc are zero.
// Grid covers Cpad/32 x R/32.
// ---------------------------------------------------------------------------
__global__ __launch_bounds__(256) void split_transpose_pad(
    const float* __restrict__ in, ushort* __restrict__ hi,
    ushort* __restrict__ lo, int R, int Csrc)
{
    __shared__ float tile[32][33];
    const int c0 = blockIdx.x * 32;
    const int r0 = blockIdx.y * 32;
    const int tc = threadIdx.x & 31;
    const int tr = threadIdx.x >> 5;
#pragma unroll
    for (int q = 0; q < 4; ++q) {
        const int c = c0 + tc;
        tile[tr + 8 * q][tc] =
            (c < Csrc) ? in[(size_t)(r0 + tr + 8 * q) * Csrc + c] : 0.f;
    }
    __syncthreads();
#pragma unroll
    for (int q = 0; q < 4; ++q) {
        const float v = tile[tc][tr + 8 * q];
        const ushort h = f2bf(v);
        const ushort l = f2bf(v - bf2f(h));
        const size_t o = (size_t)(c0 + tr + 8 * q) * R + r0 + tc;
        hi[o] = h;
        lo[o] = l;
    }
}

// ---------------------------------------------------------------------------
// bf16x3-split MFMA GEMM (A row-major hi/lo, B transposed hi/lo).
// acc += Ahi*Bhi + Ahi*Blo + Alo*Bhi.  Tile 128x128, K-step 64, 4 waves.
// ---------------------------------------------------------------------------
__global__ __launch_bounds__(256) void gemm_mfma3(
    const ushort* __restrict__ Ahi, const ushort* __restrict__ Alo,
    const ushort* __restrict__ Bhi, const ushort* __restrict__ Blo,
    float* __restrict__ C0, float* __restrict__ C1, int nsplit,
    int M, int N, int K, int ldc0, int ldc1)
{
    __shared__ ushort lA[2][128][64];
    __shared__ ushort lB[2][128][64];

    const int t    = threadIdx.x;
    const int m0   = blockIdx.y * 128;
    const int n0   = blockIdx.x * 128;
    const int wave = t >> 6;
    const int lane = t & 63;
    const int mw   = (wave & 1) * 64;
    const int nw   = (wave >> 1) * 64;
    const int l15  = lane & 15;
    const int l4   = lane >> 4;
    const int sw   = l15 & 7;

    f32x4 acc[4][4];
#pragma unroll
    for (int i = 0; i < 4; ++i)
#pragma unroll
        for (int j = 0; j < 4; ++j)
            acc[i][j] = (f32x4){0.f, 0.f, 0.f, 0.f};

    for (int k0 = 0; k0 < K; k0 += 64) {
        __syncthreads();
#define STAGE(SRC, DST, BASE)                                                  \
        _Pragma("unroll")                                                      \
        for (int q = 0; q < 4; ++q) {                                          \
            const int idx = q * 256 + t;                                       \
            const int r = idx >> 3, kc = idx & 7;                              \
            const uint4 v =                                                    \
                *(const uint4*)&SRC[(size_t)(BASE + r) * K + k0 + kc * 8];     \
            *(uint4*)&DST[r][((kc ^ (r & 7))) * 8] = v;                        \
        }
        STAGE(Ahi, lA[0], m0)
        STAGE(Alo, lA[1], m0)
        STAGE(Bhi, lB[0], n0)
        STAGE(Blo, lB[1], n0)
#undef STAGE
        __syncthreads();

#pragma unroll
        for (int ks = 0; ks < 2; ++ks) {
            const int slot = (((ks << 2) | l4) ^ sw) * 8;
            bf16x8 ah[4], al[4], bh[4], bl[4];
#pragma unroll
            for (int f = 0; f < 4; ++f) {
                const int ar = mw + f * 16 + l15;
                const int br = nw + f * 16 + l15;
                ah[f] = *(const bf16x8*)&lA[0][ar][slot];
                al[f] = *(const bf16x8*)&lA[1][ar][slot];
                bh[f] = *(const bf16x8*)&lB[0][br][slot];
                bl[f] = *(const bf16x8*)&lB[1][br][slot];
            }
#pragma unroll
            for (int i = 0; i < 4; ++i)
#pragma unroll
                for (int j = 0; j < 4; ++j) {
                    acc[i][j] = __builtin_amdgcn_mfma_f32_16x16x32_bf16(
                        ah[i], bh[j], acc[i][j], 0, 0, 0);
                    acc[i][j] = __builtin_amdgcn_mfma_f32_16x16x32_bf16(
                        ah[i], bl[j], acc[i][j], 0, 0, 0);
                    acc[i][j] = __builtin_amdgcn_mfma_f32_16x16x32_bf16(
                        al[i], bh[j], acc[i][j], 0, 0, 0);
                }
        }
    }

#pragma unroll
    for (int i = 0; i < 4; ++i) {
        const int rowg = m0 + mw + i * 16 + l4 * 4;
#pragma unroll
        for (int j = 0; j < 4; ++j) {
            const int colg = n0 + nw + j * 16 + l15;
            float* base;
            int cc, ldc;
            if (colg < nsplit) { base = C0; cc = colg;          ldc = ldc0; }
            else               { base = C1; cc = colg - nsplit; ldc = ldc1; }
#pragma unroll
            for (int v = 0; v < 4; ++v)
                base[(size_t)(rowg + v) * ldc + cc] = acc[i][j][v];
        }
    }
}

// ---------------------------------------------------------------------------
// split-K MFMA GEMM for x_dbl = u @ W_x (N padded 96->128).
// A = u hi/lo [SEQ][D_IN], B = W_x^T padded hi/lo [128][D_IN].
// Grid (WX_KSPLIT, SEQ/128); each block does a 128x128xWX_KSEG partial.
// part[kb][row][128] fp32; reduced later in fixed order (deterministic).
// ---------------------------------------------------------------------------
__global__ __launch_bounds__(256) void gemm_wx_mfma(
    const ushort* __restrict__ Ahi, const ushort* __restrict__ Alo,
    const ushort* __restrict__ Bhi, const ushort* __restrict__ Blo,
    float* __restrict__ part)
{
    __shared__ ushort lA[2][128][64];
    __shared__ ushort lB[2][128][64];

    const int t    = threadIdx.x;
    const int kb   = blockIdx.x;
    const int m0   = blockIdx.y * 128;
    const int wave = t >> 6;
    const int lane = t & 63;
    const int mw   = (wave & 1) * 64;
    const int nw   = (wave >> 1) * 64;
    const int l15  = lane & 15;
    const int l4   = lane >> 4;
    const int sw   = l15 & 7;
    const int kbase = kb * WX_KSEG;

    f32x4 acc[4][4];
#pragma unroll
    for (int i = 0; i < 4; ++i)
#pragma unroll
        for (int j = 0; j < 4; ++j)
            acc[i][j] = (f32x4){0.f, 0.f, 0.f, 0.f};

    for (int k0 = 0; k0 < WX_KSEG; k0 += 64) {
        __syncthreads();
#define STAGE(SRC, DST, BASE)                                                  \
        _Pragma("unroll")                                                      \
        for (int q = 0; q < 4; ++q) {                                          \
            const int idx = q * 256 + t;                                       \
            const int r = idx >> 3, kc = idx & 7;                              \
            const uint4 v = *(const uint4*)                                    \
                &SRC[(size_t)(BASE + r) * D_IN + kbase + k0 + kc * 8];         \
            *(uint4*)&DST[r][((kc ^ (r & 7))) * 8] = v;                        \
        }
        STAGE(Ahi, lA[0], m0)
        STAGE(Alo, lA[1], m0)
        STAGE(Bhi, lB[0], 0)
        STAGE(Blo, lB[1], 0)
#undef STAGE
        __syncthreads();

#pragma unroll
        for (int ks = 0; ks < 2; ++ks) {
            const int slot = (((ks << 2) | l4) ^ sw) * 8;
            bf16x8 ah[4], al[4], bh[4], bl[4];
#pragma unroll
            for (int f = 0; f < 4; ++f) {
                const int ar = mw + f * 16 + l15;
                const int br = nw + f * 16 + l15;
                ah[f] = *(const bf16x8*)&lA[0][ar][slot];
                al[f] = *(const bf16x8*)&lA[1][ar][slot];
                bh[f] = *(const bf16x8*)&lB[0][br][slot];
                bl[f] = *(const bf16x8*)&lB[1][br][slot];
            }
#pragma unroll
            for (int i = 0; i < 4; ++i)
#pragma unroll
                for (int j = 0; j < 4; ++j) {
                    acc[i][j] = __builtin_amdgcn_mfma_f32_16x16x32_bf16(
                        ah[i], bh[j], acc[i][j], 0, 0, 0);
                    acc[i][j] = __builtin_amdgcn_mfma_f32_16x16x32_bf16(
                        ah[i], bl[j], acc[i][j], 0, 0, 0);
                    acc[i][j] = __builtin_amdgcn_mfma_f32_16x16x32_bf16(
                        al[i], bh[j], acc[i][j], 0, 0, 0);
                }
        }
    }

#pragma unroll
    for (int i = 0; i < 4; ++i) {
        const int rowg = m0 + mw + i * 16 + l4 * 4;
#pragma unroll
        for (int j = 0; j < 4; ++j) {
            const int colg = nw + j * 16 + l15;
#pragma unroll
            for (int v = 0; v < 4; ++v)
                part[((size_t)kb * SEQ + rowg + v) * XDBL_LD + colg] =
                    acc[i][j][v];
        }
    }
}

// Fixed-order reduction of the WX_KSPLIT partials -> xdbl [SEQ][XDBL_LD].
__global__ __launch_bounds__(256) void wx_reduce(
    const float* __restrict__ part, float* __restrict__ xdbl)
{
    const size_t i = (size_t)(blockIdx.x * 256 + threadIdx.x) * 4;
    float4 s = *(const float4*)&part[i];
#pragma unroll
    for (int kb = 1; kb < WX_KSPLIT; ++kb) {
        const float4 v = *(const float4*)&part[(size_t)kb * SEQ * XDBL_LD + i];
        s.x += v.x; s.y += v.y; s.z += v.z; s.w += v.w;
    }
    *(float4*)&xdbl[i] = s;
}

// ---------------------------------------------------------------------------
// fp32 tiled GEMM (small delta GEMM, K=64)
// ---------------------------------------------------------------------------
__global__ __launch_bounds__(256) void gemm128(
    const float* __restrict__ A, const float* __restrict__ B,
    float* __restrict__ C, int M, int N, int K,
    int lda, int ldb, int ldc,
    const float* __restrict__ bias, int act)
{
    __shared__ float As[16][132];
    __shared__ float Bs[16][132];

    const int t   = threadIdx.x;
    const int bn0 = blockIdx.x * 128;
    const int bm0 = blockIdx.y * 128;
    const int tx  = t & 15;
    const int ty  = t >> 4;

    const int ar  = t >> 2;
    const int ak  = (t & 3) * 4;
    const int bk  = t >> 5;
    const int bn4 = (t & 31) * 4;

    float acc[8][8];
#pragma unroll
    for (int i = 0; i < 8; ++i)
#pragma unroll
        for (int j = 0; j < 8; ++j) acc[i][j] = 0.f;

    for (int k0 = 0; k0 < K; k0 += 16) {
        float4 a0 = *(const float4*)&A[(size_t)(bm0 + ar)      * lda + k0 + ak];
        float4 a1 = *(const float4*)&A[(size_t)(bm0 + ar + 64) * lda + k0 + ak];
        float4 b0 = *(const float4*)&B[(size_t)(k0 + bk)     * ldb + bn0 + bn4];
        float4 b1 = *(const float4*)&B[(size_t)(k0 + bk + 8) * ldb + bn0 + bn4];

        __syncthreads();
        As[ak + 0][ar] = a0.x; As[ak + 1][ar] = a0.y;
        As[ak + 2][ar] = a0.z; As[ak + 3][ar] = a0.w;
        As[ak + 0][ar + 64] = a1.x; As[ak + 1][ar + 64] = a1.y;
        As[ak + 2][ar + 64] = a1.z; As[ak + 3][ar + 64] = a1.w;
        *(float4*)&Bs[bk][bn4]     = b0;
        *(float4*)&Bs[bk + 8][bn4] = b1;
        __syncthreads();

#pragma unroll
        for (int kk = 0; kk < 16; ++kk) {
            float a[8], b[8];
            ((float4*)a)[0] = *(const float4*)&As[kk][ty * 8];
            ((float4*)a)[1] = *(const float4*)&As[kk][ty * 8 + 4];
            ((float4*)b)[0] = *(const float4*)&Bs[kk][tx * 8];
            ((float4*)b)[1] = *(const float4*)&Bs[kk][tx * 8 + 4];
#pragma unroll
            for (int i = 0; i < 8; ++i)
#pragma unroll
                for (int j = 0; j < 8; ++j)
                    acc[i][j] = fmaf(a[i], b[j], acc[i][j]);
        }
    }

    const int row = bm0 + ty * 8;
    const int col = bn0 + tx * 8;
#pragma unroll
    for (int i = 0; i < 8; ++i) {
        float vals[8];
#pragma unroll
        for (int j = 0; j < 8; ++j) {
            float v = acc[i][j];
            if (act == 1) {
                v += bias[col + j];
                v = (v > 20.f) ? v : log1pf(__expf(v));
            }
            vals[j] = v;
        }
        *(float4*)&C[(size_t)(row + i) * ldc + col]     = ((float4*)vals)[0];
        *(float4*)&C[(size_t)(row + i) * ldc + col + 4] = ((float4*)vals)[1];
    }
}

// ---------------------------------------------------------------------------
// Depthwise causal conv (K=3) + SiLU.  xi is [SEQ][D_IN] fp32.
// ---------------------------------------------------------------------------
__global__ __launch_bounds__(256) void conv_silu(
    const float* __restrict__ xi, const float* __restrict__ cw,
    float* __restrict__ u)
{
    const int id = blockIdx.x * 256 + threadIdx.x;
    const int l = id >> 11;
    const int d = id & (D_IN - 1);
    const float w0 = cw[d * 3 + 0];
    const float w1 = cw[d * 3 + 1];
    const float w2 = cw[d * 3 + 2];
    const float x0  = xi[(size_t)l * D_IN + d];
    const float xm1 = (l >= 1) ? xi[(size_t)(l - 1) * D_IN + d] : 0.f;
    const float xm2 = (l >= 2) ? xi[(size_t)(l - 2) * D_IN + d] : 0.f;
    const float v = w0 * xm2 + w1 * xm1 + w2 * x0;
    const float s = fast_rcp(1.f + fast_exp2(-LOG2E * v));
    u[(size_t)l * D_IN + d] = v * s;
}

// ---------------------------------------------------------------------------
// Per-chunk column sums of delta (double)
// ---------------------------------------------------------------------------
__global__ __launch_bounds__(256) void csum64(
    const float* __restrict__ delta, double* __restrict__ csum)
{
    const int d = blockIdx.x * 256 + threadIdx.x;
    const int c = blockIdx.y;
    double s = 0.0;
    for (int i = 0; i < LC; ++i)
        s += (double)delta[(size_t)(c * LC + i) * D_IN + d];
    csum[(size_t)c * D_IN + d] = s;
}

__global__ __launch_bounds__(256) void chunk_prefix(
    const double* __restrict__ csum, double* __restrict__ P0,
    double* __restrict__ Td)
{
    const int d = blockIdx.x * 256 + threadIdx.x;
    double P = 0.0;
    for (int c = 0; c < NCH; ++c) {
        P0[(size_t)c * D_IN + d] = P;
        P += csum[(size_t)c * D_IN + d];
    }
    Td[d] = P;
}

// ---------------------------------------------------------------------------
// sfx[l][d] = float(max(Td - P_inclusive(l), 0)); double bookkeeping once
// per (l,d). Clamp-at-store guarantees An*sfx <= 0 downstream.
// ---------------------------------------------------------------------------
__global__ __launch_bounds__(256) void sfx_precompute(
    const float* __restrict__ delta, const double* __restrict__ P0,
    const double* __restrict__ Td, float* __restrict__ sfx)
{
    const int d = blockIdx.x * 256 + threadIdx.x;
    const int c = blockIdx.y;
    double P = P0[(size_t)c * D_IN + d];
    const double T = Td[d];
    for (int i = 0; i < LC; ++i) {
        P += (double)delta[(size_t)(c * LC + i) * D_IN + d];
        sfx[(size_t)(c * LC + i) * D_IN + d] = (float)fmax(T - P, 0.0);
    }
}

// ---------------------------------------------------------------------------
// Pass A: per-chunk local scan from h=0 (native exp2)
// ---------------------------------------------------------------------------
__global__ __launch_bounds__(512) void scan_partA(
    const float* __restrict__ delta, const float* __restrict__ u,
    const float* __restrict__ xdbl, const float* __restrict__ Alog,
    float* __restrict__ hfin)
{
    __shared__ float sdel[LC][DT];
    __shared__ float sdu[LC][DT];
    __shared__ float sB[LC][16];

    const int t  = threadIdx.x;
    const int c  = blockIdx.x;
    const int d0 = blockIdx.y * DT;

    {
        int r = t >> 3, c4 = (t & 7) * 4;
        const float4 dv4 = *(const float4*)&delta[(size_t)(c * LC + r) * D_IN + d0 + c4];
        const float4 uv4 = *(const float4*)&u[(size_t)(c * LC + r) * D_IN + d0 + c4];
        *(float4*)&sdel[r][c4] = dv4;
        float4 du4;
        du4.x = dv4.x * uv4.x; du4.y = dv4.y * uv4.y;
        du4.z = dv4.z * uv4.z; du4.w = dv4.w * uv4.w;
        *(float4*)&sdu[r][c4] = du4;
    }
    if (t < 256) {
        int r = t >> 2, c4 = (t & 3) * 4;
        *(float4*)&sB[r][c4] = *(const float4*)&xdbl[(size_t)(c * LC + r) * XDBL_LD + DT_RANK + c4];
    }
    __syncthreads();

    const int n  = t & 15;
    const int dq = t >> 4;
    const int d  = d0 + dq;
    const float An2 = -expf(Alog[d * N_STATE + n]) * LOG2E;

    float h = 0.f;
#pragma unroll 8
    for (int i = 0; i < LC; ++i)
        h = fmaf(h, fast_exp2(An2 * sdel[i][dq]), sdu[i][dq] * sB[i][n]);
    hfin[((size_t)c * D_IN + d) * N_STATE + n] = h;
}

// ---------------------------------------------------------------------------
// Pass B: serial combine across chunks; hfin becomes incoming state H0.
// ---------------------------------------------------------------------------
__global__ __launch_bounds__(256) void scan_combine(
    float* __restrict__ hfin, const double* __restrict__ csum,
    const float* __restrict__ Alog)
{
    const int id = blockIdx.x * 256 + threadIdx.x;
    const int d = id >> 4;
    const int n = id & 15;
    const float An2 = -expf(Alog[d * N_STATE + n]) * LOG2E;
    float H = 0.f;
    for (int c = 0; c < NCH; ++c) {
        const size_t idx = ((size_t)c * D_IN + d) * N_STATE + n;
        const float hf = hfin[idx];
        hfin[idx] = H;
        const float Dec = fast_exp2(An2 * (float)csum[(size_t)c * D_IN + d]);
        H = fmaf(H, Dec, hf);
    }
}

// ---------------------------------------------------------------------------
// Pass C: scan with incoming state + precomputed suffix gate + n-reduce +
// res-SiLU. All transcendentals native.
// ---------------------------------------------------------------------------
__global__ __launch_bounds__(512) void scan_partC(
    const float* __restrict__ delta, const float* __restrict__ u,
    const float* __restrict__ xdbl, const float* __restrict__ H0buf,
    const float* __restrict__ sfxbuf, const float* __restrict__ Alog,
    const float* __restrict__ Dvec, const float* __restrict__ res,
    float* __restrict__ yg)
{
    __shared__ float sdel[LC][DT];
    __shared__ float sU[LC][DT];
    __shared__ float sres[LC][DT];
    __shared__ float ssfx[LC][DT];
    __shared__ float sB[LC][16];
    __shared__ float sC[LC][16];

    const int t  = threadIdx.x;
    const int c  = blockIdx.x;
    const int d0 = blockIdx.y * DT;

    {
        int r = t >> 3, c4 = (t & 7) * 4;
        const size_t row = (size_t)(c * LC + r) * D_IN + d0 + c4;
        *(float4*)&sdel[r][c4] = *(const float4*)&delta[row];
        *(float4*)&sU[r][c4]   = *(const float4*)&u[row];
        *(float4*)&sres[r][c4] = *(const float4*)&res[row];
        *(float4*)&ssfx[r][c4] = *(const float4*)&sfxbuf[row];
    }
    if (t < 256) {
        int r = t >> 2, c4 = (t & 3) * 4;
        *(float4*)&sB[r][c4] = *(const float4*)&xdbl[(size_t)(c * LC + r) * XDBL_LD + DT_RANK + c4];
        *(float4*)&sC[r][c4] = *(const float4*)&xdbl[(size_t)(c * LC + r) * XDBL_LD + DT_RANK + 16 + c4];
    }
    __syncthreads();

    const int n  = t & 15;
    const int dq = t >> 4;
    const int d  = d0 + dq;
    const float An2 = -expf(Alog[d * N_STATE + n]) * LOG2E;
    const float Dd = Dvec[d];

    float h = H0buf[((size_t)c * D_IN + d) * N_STATE + n];

    for (int i = 0; i < LC; ++i) {
        const float dv = sdel[i][dq];
        const float uv = sU[i][dq];
        const float E  = fast_exp2(An2 * ssfx[i][dq]);
        const float g  = E * fast_rcp(E + 1e-12f);
        h = fmaf(h, fast_exp2(An2 * dv), dv * uv * sB[i][n]);
        float contrib = h * g * sC[i][n];
        contrib += __shfl_xor(contrib, 1);
        contrib += __shfl_xor(contrib, 2);
        contrib += __shfl_xor(contrib, 4);
        contrib += __shfl_xor(contrib, 8);
        if (n == 0) {
            const float r  = sres[i][dq];
            const float sg = fast_rcp(1.f + fast_exp2(-LOG2E * r));
            yg[(size_t)(c * LC + i) * D_IN + d] = (contrib + uv * Dd) * (r * sg);
        }
    }
}

// ---------------------------------------------------------------------------
// Launch.  Workspace (74.5 MB peak, time-multiplexed; ws proven >= 84.9 MB):
//   [ 0       ,16.78M): xi -> u_hi/u_lo (bf16) -> sfx -> yg_hi/yg_lo
//   [16.78    ,33.55 ): res
//   [33.55    ,50.33 ): x_hi/x_lo -> u (f32) -> wo_hi/wo_lo
//   [50.33    ,51.38 ): xdbl [2048][128] f32
//   [51.38    ,68.16 ): wi_hi/wi_lo -> wx partials [16][2048][128] -> delta/yg
//   [68.16    ,73.42 ): hfin, csum, P0, Td
//   [73.42    ,74.47 ): wx_hi/wx_lo (padded [128][2048] bf16)
// ---------------------------------------------------------------------------
extern "C" void kernel_launch(void* const* d_in, const int* in_sizes, int n_in,
                              void* d_out, int out_size, void* d_ws, size_t ws_size,
                              hipStream_t stream)
{
    const float* x      = (const float*)d_in[0];
    const float* W_in   = (const float*)d_in[1];
    const float* conv_w = (const float*)d_in[2];
    const float* W_x    = (const float*)d_in[3];
    const float* W_del  = (const float*)d_in[4];
    const float* b_del  = (const float*)d_in[5];
    const float* A_log  = (const float*)d_in[6];
    const float* Dv     = (const float*)d_in[7];
    const float* W_out  = (const float*)d_in[8];
    float* out = (float*)d_out;

    char* ws = (char*)d_ws;
    float*  xi    = (float*)(ws + 0);
    ushort* u_hi  = (ushort*)(ws + 0);
    ushort* u_lo  = (ushort*)(ws + 8388608);
    float*  sfx   = (float*)(ws + 0);
    ushort* yg_hi = (ushort*)(ws + 0);
    ushort* yg_lo = (ushort*)(ws + 8388608);
    float*  res   = (float*)(ws + 16777216);
    ushort* x_hi  = (ushort*)(ws + 33554432);
    ushort* x_lo  = (ushort*)(ws + 37748736);
    float*  u     = (float*)(ws + 33554432);
    ushort* wo_hi = (ushort*)(ws + 33554432);
    ushort* wo_lo = (ushort*)(ws + 37748736);
    float*  xdbl  = (float*)(ws + 50331648);   // [2048][128] -> ends 51380224
    ushort* wi_hi = (ushort*)(ws + 51380224);
    ushort* wi_lo = (ushort*)(ws + 59768832);
    float*  wxp   = (float*)(ws + 51380224);   // [16][2048][128] partials
    float*  delta = (float*)(ws + 51380224);   // after reduce (partials dead)
    float*  hfin  = (float*)(ws + 68157440);   // 4.19 MB -> 72351744
    double* csum  = (double*)(ws + 72351744);  // 0.52 MB -> 72876032
    double* P0    = (double*)(ws + 72876032);  // 0.52 MB -> 73400320
    double* Td    = (double*)(ws + 73400320);  // 16 KB   -> 73416704
    ushort* wx_hi = (ushort*)(ws + 73416704);  // 0.52 MB -> 73940992
    ushort* wx_lo = (ushort*)(ws + 73940992);  // 0.52 MB -> 74465280
    float*  yg    = delta;   // pass C stages reads to LDS before writing

    // 1) W_in^T split
    split_transpose<<<dim3(4096 / 32, 1024 / 32), 256, 0, stream>>>(
        W_in, wi_hi, wi_lo, 1024, 4096);

    // 2) x split
    split_bf16<<<(SEQ * D_MODEL / 4) / 256, 256, 0, stream>>>(x, x_hi, x_lo);

    // 3) [xi | res] = x @ W_in
    gemm_mfma3<<<dim3(4096 / 128, 2048 / 128), 256, 0, stream>>>(
        x_hi, x_lo, wi_hi, wi_lo, xi, res, D_IN,
        SEQ, 2 * D_IN, D_MODEL, D_IN, D_IN);

    // 4) u = silu(depthwise_conv(xi))
    conv_silu<<<(SEQ * D_IN) / 256, 256, 0, stream>>>(xi, conv_w, u);

    // 5) u split (xi dead), W_x^T padded split
    split_bf16<<<(SEQ * D_IN / 4) / 256, 256, 0, stream>>>(u, u_hi, u_lo);
    split_transpose_pad<<<dim3(XDBL_LD / 32, D_IN / 32), 256, 0, stream>>>(
        W_x, wx_hi, wx_lo, D_IN, XDBL_W);

    // 6) x_dbl = u @ W_x  (split-K MFMA into partials, fixed-order reduce)
    gemm_wx_mfma<<<dim3(WX_KSPLIT, SEQ / 128), 256, 0, stream>>>(
        u_hi, u_lo, wx_hi, wx_lo, wxp);
    wx_reduce<<<(SEQ * XDBL_LD / 4) / 256, 256, 0, stream>>>(wxp, xdbl);

    // 7) delta = softplus(delta_lr @ W_delta + b_delta)  (overwrites partials)
    gemm128<<<dim3(2048 / 128, 2048 / 128), 256, 0, stream>>>(
        xdbl, W_del, delta, SEQ, D_IN, DT_RANK, XDBL_LD, D_IN, D_IN,
        b_del, 1);

    // 8) chunk sums + prefix + per-element suffix (double, deterministic)
    csum64<<<dim3(D_IN / 256, NCH), 256, 0, stream>>>(delta, csum);
    chunk_prefix<<<D_IN / 256, 256, 0, stream>>>(csum, P0, Td);
    sfx_precompute<<<dim3(D_IN / 256, NCH), 256, 0, stream>>>(delta, P0, Td, sfx);

    // 9) chunk-parallel selective scan
    scan_partA<<<dim3(NCH, D_IN / DT), 512, 0, stream>>>(delta, u, xdbl, A_log, hfin);
    scan_combine<<<(D_IN * N_STATE) / 256, 256, 0, stream>>>(hfin, csum, A_log);
    scan_partC<<<dim3(NCH, D_IN / DT), 512, 0, stream>>>(
        delta, u, xdbl, hfin, sfx, A_log, Dv, res, yg);

    // 10) yg split (sfx dead; region reused)
    split_bf16<<<(SEQ * D_IN / 4) / 256, 256, 0, stream>>>(yg, yg_hi, yg_lo);

    // 11) W_out^T split (u dead; region reused)
    split_transpose<<<dim3(1024 / 32, 2048 / 32), 256, 0, stream>>>(
        W_out, wo_hi, wo_lo, 2048, 1024);

    // 12) out = yg @ W_out
    gemm_mfma3<<<dim3(1024 / 128, 2048 / 128), 256, 0, stream>>>(
        yg_hi, yg_lo, wo_hi, wo_lo, out, out, D_MODEL,
        SEQ, D_MODEL, D_IN, D_MODEL, D_MODEL);
}

// Round 8
// 302.681 us; speedup vs baseline: 4.5967x; 1.0620x over previous
//
#include <hip/hip_runtime.h>
#include <hip/hip_bf16.h>
#include <math.h>

// ---------------------------------------------------------------------------
// Shapes (compile-time constants for this problem)
// ---------------------------------------------------------------------------
#define SEQ     2048
#define D_MODEL 1024
#define D_IN    2048
#define N_STATE 16
#define DT_RANK 64
#define XDBL_W  96          // DT_RANK + 2*N_STATE
#define XDBL_LD 128         // padded leading dim of x_dbl
#define LC      64          // scan chunk length
#define NCH     32          // SEQ / LC
#define DT      32          // d-channels per scan block
#define WX_KSPLIT 16
#define WX_KSEG   (D_IN / WX_KSPLIT)   // 128

#define LOG2E   1.4426950408889634f

typedef __attribute__((ext_vector_type(8))) short bf16x8;
typedef __attribute__((ext_vector_type(4))) float f32x4;

__device__ __forceinline__ float fast_exp2(float x) { return __builtin_amdgcn_exp2f(x); }
__device__ __forceinline__ float fast_rcp(float x)  { return __builtin_amdgcn_rcpf(x); }

// v_add_f32 with DPP-moved operand: 16-lane butterfly without the DS pipe.
// CTRL must be a compile-time constant (hardware imm field).
template <int CTRL>
__device__ __forceinline__ float dpp_add(float x) {
    int y = __builtin_amdgcn_update_dpp(0, __float_as_int(x), CTRL, 0xF, 0xF, true);
    return x + __int_as_float(y);
}

__device__ __forceinline__ ushort f2bf(float x) {
    unsigned u = __float_as_uint(x);
    u += 0x7FFFu + ((u >> 16) & 1u);      // RNE
    return (ushort)(u >> 16);
}
__device__ __forceinline__ float bf2f(ushort h) {
    return __uint_as_float(((unsigned)h) << 16);
}

// ---------------------------------------------------------------------------
// split fp32 -> bf16 hi/lo (elementwise). One float4 per thread.
// ---------------------------------------------------------------------------
__global__ __launch_bounds__(256) void split_bf16(
    const float* __restrict__ in, ushort* __restrict__ hi,
    ushort* __restrict__ lo)
{
    const int i = blockIdx.x * 256 + threadIdx.x;
    const float4 v = *(const float4*)&in[(size_t)i * 4];
    ushort4 h, l;
    h.x = f2bf(v.x); l.x = f2bf(v.x - bf2f(h.x));
    h.y = f2bf(v.y); l.y = f2bf(v.y - bf2f(h.y));
    h.z = f2bf(v.z); l.z = f2bf(v.z - bf2f(h.z));
    h.w = f2bf(v.w); l.w = f2bf(v.w - bf2f(h.w));
    *(ushort4*)&hi[(size_t)i * 4] = h;
    *(ushort4*)&lo[(size_t)i * 4] = l;
}

// ---------------------------------------------------------------------------
// split + transpose: in[R][C] fp32 -> hi/lo[C][R] bf16.
// ---------------------------------------------------------------------------
__global__ __launch_bounds__(256) void split_transpose(
    const float* __restrict__ in, ushort* __restrict__ hi,
    ushort* __restrict__ lo, int R, int C)
{
    __shared__ float tile[32][33];
    const int c0 = blockIdx.x * 32;
    const int r0 = blockIdx.y * 32;
    const int tc = threadIdx.x & 31;
    const int tr = threadIdx.x >> 5;
#pragma unroll
    for (int q = 0; q < 4; ++q)
        tile[tr + 8 * q][tc] = in[(size_t)(r0 + tr + 8 * q) * C + c0 + tc];
    __syncthreads();
#pragma unroll
    for (int q = 0; q < 4; ++q) {
        const float v = tile[tc][tr + 8 * q];
        const ushort h = f2bf(v);
        const ushort l = f2bf(v - bf2f(h));
        const size_t o = (size_t)(c0 + tr + 8 * q) * R + r0 + tc;
        hi[o] = h;
        lo[o] = l;
    }
}

// ---------------------------------------------------------------------------
// split + transpose with zero padding on the output-row axis.
// ---------------------------------------------------------------------------
__global__ __launch_bounds__(256) void split_transpose_pad(
    const float* __restrict__ in, ushort* __restrict__ hi,
    ushort* __restrict__ lo, int R, int Csrc)
{
    __shared__ float tile[32][33];
    const int c0 = blockIdx.x * 32;
    const int r0 = blockIdx.y * 32;
    const int tc = threadIdx.x & 31;
    const int tr = threadIdx.x >> 5;
#pragma unroll
    for (int q = 0; q < 4; ++q) {
        const int c = c0 + tc;
        tile[tr + 8 * q][tc] =
            (c < Csrc) ? in[(size_t)(r0 + tr + 8 * q) * Csrc + c] : 0.f;
    }
    __syncthreads();
#pragma unroll
    for (int q = 0; q < 4; ++q) {
        const float v = tile[tc][tr + 8 * q];
        const ushort h = f2bf(v);
        const ushort l = f2bf(v - bf2f(h));
        const size_t o = (size_t)(c0 + tr + 8 * q) * R + r0 + tc;
        hi[o] = h;
        lo[o] = l;
    }
}

// ---------------------------------------------------------------------------
// bf16x3-split MFMA GEMM (A row-major hi/lo, B transposed hi/lo).
// ---------------------------------------------------------------------------
__global__ __launch_bounds__(256) void gemm_mfma3(
    const ushort* __restrict__ Ahi, const ushort* __restrict__ Alo,
    const ushort* __restrict__ Bhi, const ushort* __restrict__ Blo,
    float* __restrict__ C0, float* __restrict__ C1, int nsplit,
    int M, int N, int K, int ldc0, int ldc1)
{
    __shared__ ushort lA[2][128][64];
    __shared__ ushort lB[2][128][64];

    const int t    = threadIdx.x;
    const int m0   = blockIdx.y * 128;
    const int n0   = blockIdx.x * 128;
    const int wave = t >> 6;
    const int lane = t & 63;
    const int mw   = (wave & 1) * 64;
    const int nw   = (wave >> 1) * 64;
    const int l15  = lane & 15;
    const int l4   = lane >> 4;
    const int sw   = l15 & 7;

    f32x4 acc[4][4];
#pragma unroll
    for (int i = 0; i < 4; ++i)
#pragma unroll
        for (int j = 0; j < 4; ++j)
            acc[i][j] = (f32x4){0.f, 0.f, 0.f, 0.f};

    for (int k0 = 0; k0 < K; k0 += 64) {
        __syncthreads();
#define STAGE(SRC, DST, BASE)                                                  \
        _Pragma("unroll")                                                      \
        for (int q = 0; q < 4; ++q) {                                          \
            const int idx = q * 256 + t;                                       \
            const int r = idx >> 3, kc = idx & 7;                              \
            const uint4 v =                                                    \
                *(const uint4*)&SRC[(size_t)(BASE + r) * K + k0 + kc * 8];     \
            *(uint4*)&DST[r][((kc ^ (r & 7))) * 8] = v;                        \
        }
        STAGE(Ahi, lA[0], m0)
        STAGE(Alo, lA[1], m0)
        STAGE(Bhi, lB[0], n0)
        STAGE(Blo, lB[1], n0)
#undef STAGE
        __syncthreads();

#pragma unroll
        for (int ks = 0; ks < 2; ++ks) {
            const int slot = (((ks << 2) | l4) ^ sw) * 8;
            bf16x8 ah[4], al[4], bh[4], bl[4];
#pragma unroll
            for (int f = 0; f < 4; ++f) {
                const int ar = mw + f * 16 + l15;
                const int br = nw + f * 16 + l15;
                ah[f] = *(const bf16x8*)&lA[0][ar][slot];
                al[f] = *(const bf16x8*)&lA[1][ar][slot];
                bh[f] = *(const bf16x8*)&lB[0][br][slot];
                bl[f] = *(const bf16x8*)&lB[1][br][slot];
            }
#pragma unroll
            for (int i = 0; i < 4; ++i)
#pragma unroll
                for (int j = 0; j < 4; ++j) {
                    acc[i][j] = __builtin_amdgcn_mfma_f32_16x16x32_bf16(
                        ah[i], bh[j], acc[i][j], 0, 0, 0);
                    acc[i][j] = __builtin_amdgcn_mfma_f32_16x16x32_bf16(
                        ah[i], bl[j], acc[i][j], 0, 0, 0);
                    acc[i][j] = __builtin_amdgcn_mfma_f32_16x16x32_bf16(
                        al[i], bh[j], acc[i][j], 0, 0, 0);
                }
        }
    }

#pragma unroll
    for (int i = 0; i < 4; ++i) {
        const int rowg = m0 + mw + i * 16 + l4 * 4;
#pragma unroll
        for (int j = 0; j < 4; ++j) {
            const int colg = n0 + nw + j * 16 + l15;
            float* base;
            int cc, ldc;
            if (colg < nsplit) { base = C0; cc = colg;          ldc = ldc0; }
            else               { base = C1; cc = colg - nsplit; ldc = ldc1; }
#pragma unroll
            for (int v = 0; v < 4; ++v)
                base[(size_t)(rowg + v) * ldc + cc] = acc[i][j][v];
        }
    }
}

// ---------------------------------------------------------------------------
// split-K MFMA GEMM for x_dbl = u @ W_x (N padded 96->128).
// ---------------------------------------------------------------------------
__global__ __launch_bounds__(256) void gemm_wx_mfma(
    const ushort* __restrict__ Ahi, const ushort* __restrict__ Alo,
    const ushort* __restrict__ Bhi, const ushort* __restrict__ Blo,
    float* __restrict__ part)
{
    __shared__ ushort lA[2][128][64];
    __shared__ ushort lB[2][128][64];

    const int t    = threadIdx.x;
    const int kb   = blockIdx.x;
    const int m0   = blockIdx.y * 128;
    const int wave = t >> 6;
    const int lane = t & 63;
    const int mw   = (wave & 1) * 64;
    const int nw   = (wave >> 1) * 64;
    const int l15  = lane & 15;
    const int l4   = lane >> 4;
    const int sw   = l15 & 7;
    const int kbase = kb * WX_KSEG;

    f32x4 acc[4][4];
#pragma unroll
    for (int i = 0; i < 4; ++i)
#pragma unroll
        for (int j = 0; j < 4; ++j)
            acc[i][j] = (f32x4){0.f, 0.f, 0.f, 0.f};

    for (int k0 = 0; k0 < WX_KSEG; k0 += 64) {
        __syncthreads();
#define STAGE(SRC, DST, BASE)                                                  \
        _Pragma("unroll")                                                      \
        for (int q = 0; q < 4; ++q) {                                          \
            const int idx = q * 256 + t;                                       \
            const int r = idx >> 3, kc = idx & 7;                              \
            const uint4 v = *(const uint4*)                                    \
                &SRC[(size_t)(BASE + r) * D_IN + kbase + k0 + kc * 8];         \
            *(uint4*)&DST[r][((kc ^ (r & 7))) * 8] = v;                        \
        }
        STAGE(Ahi, lA[0], m0)
        STAGE(Alo, lA[1], m0)
        STAGE(Bhi, lB[0], 0)
        STAGE(Blo, lB[1], 0)
#undef STAGE
        __syncthreads();

#pragma unroll
        for (int ks = 0; ks < 2; ++ks) {
            const int slot = (((ks << 2) | l4) ^ sw) * 8;
            bf16x8 ah[4], al[4], bh[4], bl[4];
#pragma unroll
            for (int f = 0; f < 4; ++f) {
                const int ar = mw + f * 16 + l15;
                const int br = nw + f * 16 + l15;
                ah[f] = *(const bf16x8*)&lA[0][ar][slot];
                al[f] = *(const bf16x8*)&lA[1][ar][slot];
                bh[f] = *(const bf16x8*)&lB[0][br][slot];
                bl[f] = *(const bf16x8*)&lB[1][br][slot];
            }
#pragma unroll
            for (int i = 0; i < 4; ++i)
#pragma unroll
                for (int j = 0; j < 4; ++j) {
                    acc[i][j] = __builtin_amdgcn_mfma_f32_16x16x32_bf16(
                        ah[i], bh[j], acc[i][j], 0, 0, 0);
                    acc[i][j] = __builtin_amdgcn_mfma_f32_16x16x32_bf16(
                        ah[i], bl[j], acc[i][j], 0, 0, 0);
                    acc[i][j] = __builtin_amdgcn_mfma_f32_16x16x32_bf16(
                        al[i], bh[j], acc[i][j], 0, 0, 0);
                }
        }
    }

#pragma unroll
    for (int i = 0; i < 4; ++i) {
        const int rowg = m0 + mw + i * 16 + l4 * 4;
#pragma unroll
        for (int j = 0; j < 4; ++j) {
            const int colg = nw + j * 16 + l15;
#pragma unroll
            for (int v = 0; v < 4; ++v)
                part[((size_t)kb * SEQ + rowg + v) * XDBL_LD + colg] =
                    acc[i][j][v];
        }
    }
}

// Fixed-order reduction of the WX_KSPLIT partials -> xdbl [SEQ][XDBL_LD].
__global__ __launch_bounds__(256) void wx_reduce(
    const float* __restrict__ part, float* __restrict__ xdbl)
{
    const size_t i = (size_t)(blockIdx.x * 256 + threadIdx.x) * 4;
    float4 s = *(const float4*)&part[i];
#pragma unroll
    for (int kb = 1; kb < WX_KSPLIT; ++kb) {
        const float4 v = *(const float4*)&part[(size_t)kb * SEQ * XDBL_LD + i];
        s.x += v.x; s.y += v.y; s.z += v.z; s.w += v.w;
    }
    *(float4*)&xdbl[i] = s;
}

// ---------------------------------------------------------------------------
// fp32 tiled GEMM (small delta GEMM, K=64)
// ---------------------------------------------------------------------------
__global__ __launch_bounds__(256) void gemm128(
    const float* __restrict__ A, const float* __restrict__ B,
    float* __restrict__ C, int M, int N, int K,
    int lda, int ldb, int ldc,
    const float* __restrict__ bias, int act)
{
    __shared__ float As[16][132];
    __shared__ float Bs[16][132];

    const int t   = threadIdx.x;
    const int bn0 = blockIdx.x * 128;
    const int bm0 = blockIdx.y * 128;
    const int tx  = t & 15;
    const int ty  = t >> 4;

    const int ar  = t >> 2;
    const int ak  = (t & 3) * 4;
    const int bk  = t >> 5;
    const int bn4 = (t & 31) * 4;

    float acc[8][8];
#pragma unroll
    for (int i = 0; i < 8; ++i)
#pragma unroll
        for (int j = 0; j < 8; ++j) acc[i][j] = 0.f;

    for (int k0 = 0; k0 < K; k0 += 16) {
        float4 a0 = *(const float4*)&A[(size_t)(bm0 + ar)      * lda + k0 + ak];
        float4 a1 = *(const float4*)&A[(size_t)(bm0 + ar + 64) * lda + k0 + ak];
        float4 b0 = *(const float4*)&B[(size_t)(k0 + bk)     * ldb + bn0 + bn4];
        float4 b1 = *(const float4*)&B[(size_t)(k0 + bk + 8) * ldb + bn0 + bn4];

        __syncthreads();
        As[ak + 0][ar] = a0.x; As[ak + 1][ar] = a0.y;
        As[ak + 2][ar] = a0.z; As[ak + 3][ar] = a0.w;
        As[ak + 0][ar + 64] = a1.x; As[ak + 1][ar + 64] = a1.y;
        As[ak + 2][ar + 64] = a1.z; As[ak + 3][ar + 64] = a1.w;
        *(float4*)&Bs[bk][bn4]     = b0;
        *(float4*)&Bs[bk + 8][bn4] = b1;
        __syncthreads();

#pragma unroll
        for (int kk = 0; kk < 16; ++kk) {
            float a[8], b[8];
            ((float4*)a)[0] = *(const float4*)&As[kk][ty * 8];
            ((float4*)a)[1] = *(const float4*)&As[kk][ty * 8 + 4];
            ((float4*)b)[0] = *(const float4*)&Bs[kk][tx * 8];
            ((float4*)b)[1] = *(const float4*)&Bs[kk][tx * 8 + 4];
#pragma unroll
            for (int i = 0; i < 8; ++i)
#pragma unroll
                for (int j = 0; j < 8; ++j)
                    acc[i][j] = fmaf(a[i], b[j], acc[i][j]);
        }
    }

    const int row = bm0 + ty * 8;
    const int col = bn0 + tx * 8;
#pragma unroll
    for (int i = 0; i < 8; ++i) {
        float vals[8];
#pragma unroll
        for (int j = 0; j < 8; ++j) {
            float v = acc[i][j];
            if (act == 1) {
                v += bias[col + j];
                v = (v > 20.f) ? v : log1pf(__expf(v));
            }
            vals[j] = v;
        }
        *(float4*)&C[(size_t)(row + i) * ldc + col]     = ((float4*)vals)[0];
        *(float4*)&C[(size_t)(row + i) * ldc + col + 4] = ((float4*)vals)[1];
    }
}

// ---------------------------------------------------------------------------
// Depthwise causal conv (K=3) + SiLU, fused with bf16 hi/lo split of u.
// ---------------------------------------------------------------------------
__global__ __launch_bounds__(256) void conv_silu_split(
    const float* __restrict__ xi, const float* __restrict__ cw,
    float* __restrict__ u, ushort* __restrict__ uhi, ushort* __restrict__ ulo)
{
    const int id = blockIdx.x * 256 + threadIdx.x;
    const int l = id >> 11;
    const int d = id & (D_IN - 1);
    const float w0 = cw[d * 3 + 0];
    const float w1 = cw[d * 3 + 1];
    const float w2 = cw[d * 3 + 2];
    const float x0  = xi[(size_t)l * D_IN + d];
    const float xm1 = (l >= 1) ? xi[(size_t)(l - 1) * D_IN + d] : 0.f;
    const float xm2 = (l >= 2) ? xi[(size_t)(l - 2) * D_IN + d] : 0.f;
    const float v = w0 * xm2 + w1 * xm1 + w2 * x0;
    const float s = fast_rcp(1.f + fast_exp2(-LOG2E * v));
    const float uu = v * s;
    u[id] = uu;
    const ushort h = f2bf(uu);
    uhi[id] = h;
    ulo[id] = f2bf(uu - bf2f(h));
}

// ---------------------------------------------------------------------------
// Per-chunk column sums of delta (double)
// ---------------------------------------------------------------------------
__global__ __launch_bounds__(256) void csum64(
    const float* __restrict__ delta, double* __restrict__ csum)
{
    const int d = blockIdx.x * 256 + threadIdx.x;
    const int c = blockIdx.y;
    double s = 0.0;
    for (int i = 0; i < LC; ++i)
        s += (double)delta[(size_t)(c * LC + i) * D_IN + d];
    csum[(size_t)c * D_IN + d] = s;
}

__global__ __launch_bounds__(256) void chunk_prefix(
    const double* __restrict__ csum, double* __restrict__ P0,
    double* __restrict__ Td)
{
    const int d = blockIdx.x * 256 + threadIdx.x;
    double P = 0.0;
    for (int c = 0; c < NCH; ++c) {
        P0[(size_t)c * D_IN + d] = P;
        P += csum[(size_t)c * D_IN + d];
    }
    Td[d] = P;
}

// ---------------------------------------------------------------------------
// sfx[l][d] = float(max(Td - P_inclusive(l), 0))
// ---------------------------------------------------------------------------
__global__ __launch_bounds__(256) void sfx_precompute(
    const float* __restrict__ delta, const double* __restrict__ P0,
    const double* __restrict__ Td, float* __restrict__ sfx)
{
    const int d = blockIdx.x * 256 + threadIdx.x;
    const int c = blockIdx.y;
    double P = P0[(size_t)c * D_IN + d];
    const double T = Td[d];
    for (int i = 0; i < LC; ++i) {
        P += (double)delta[(size_t)(c * LC + i) * D_IN + d];
        sfx[(size_t)(c * LC + i) * D_IN + d] = (float)fmax(T - P, 0.0);
    }
}

// ---------------------------------------------------------------------------
// Pass A: per-chunk local scan from h=0. Packed LDS: (dv, dv*u) float2 + B.
// ---------------------------------------------------------------------------
__global__ __launch_bounds__(512) void scan_partA(
    const float* __restrict__ delta, const float* __restrict__ u,
    const float* __restrict__ xdbl, const float* __restrict__ Alog,
    float* __restrict__ hfin)
{
    __shared__ float2 spA[LC][DT];     // (delta, delta*u)  16 KB
    __shared__ float  sBA[LC][16];     // B                  4 KB

    const int t  = threadIdx.x;
    const int c  = blockIdx.x;
    const int d0 = blockIdx.y * DT;

    {
        const int r = t >> 3, c4 = (t & 7) * 4;
        const float4 dv4 = *(const float4*)&delta[(size_t)(c * LC + r) * D_IN + d0 + c4];
        const float4 uv4 = *(const float4*)&u[(size_t)(c * LC + r) * D_IN + d0 + c4];
        spA[r][c4 + 0] = make_float2(dv4.x, dv4.x * uv4.x);
        spA[r][c4 + 1] = make_float2(dv4.y, dv4.y * uv4.y);
        spA[r][c4 + 2] = make_float2(dv4.z, dv4.z * uv4.z);
        spA[r][c4 + 3] = make_float2(dv4.w, dv4.w * uv4.w);
    }
    if (t < 256) {
        const int r = t >> 2, c4 = (t & 3) * 4;
        *(float4*)&sBA[r][c4] =
            *(const float4*)&xdbl[(size_t)(c * LC + r) * XDBL_LD + DT_RANK + c4];
    }
    __syncthreads();

    const int n  = t & 15;
    const int dq = t >> 4;
    const int d  = d0 + dq;
    const float An2 = -expf(Alog[d * N_STATE + n]) * LOG2E;

    float h = 0.f;
#pragma unroll
    for (int i = 0; i < LC; ++i) {
        const float2 p = spA[i][dq];
        h = fmaf(h, fast_exp2(An2 * p.x), p.y * sBA[i][n]);
    }
    hfin[((size_t)c * D_IN + d) * N_STATE + n] = h;
}

// ---------------------------------------------------------------------------
// Pass B: serial combine across chunks; hfin becomes incoming state H0.
// ---------------------------------------------------------------------------
__global__ __launch_bounds__(256) void scan_combine(
    float* __restrict__ hfin, const double* __restrict__ csum,
    const float* __restrict__ Alog)
{
    const int id = blockIdx.x * 256 + threadIdx.x;
    const int d = id >> 4;
    const int n = id & 15;
    const float An2 = -expf(Alog[d * N_STATE + n]) * LOG2E;
    float H = 0.f;
    for (int c = 0; c < NCH; ++c) {
        const size_t idx = ((size_t)c * D_IN + d) * N_STATE + n;
        const float hf = hfin[idx];
        hfin[idx] = H;
        const float Dec = fast_exp2(An2 * (float)csum[(size_t)c * D_IN + d]);
        H = fmaf(H, Dec, hf);
    }
}

// ---------------------------------------------------------------------------
// Pass C: scan + gate + n-reduce + res-SiLU. Packed LDS:
//   spack[i][dq] = (delta, u, sfx, res) -> one ds_read_b128 (broadcast x16)
//   sbc[i][n]    = (B, C)               -> one ds_read_b64
// n-reduce via 4x v_add_f32 DPP (quad_perm 0xB1/0x4E, row_ror:8/:4).
// ---------------------------------------------------------------------------
__global__ __launch_bounds__(512) void scan_partC(
    const float* __restrict__ delta, const float* __restrict__ u,
    const float* __restrict__ xdbl, const float* __restrict__ H0buf,
    const float* __restrict__ sfxbuf, const float* __restrict__ Alog,
    const float* __restrict__ Dvec, const float* __restrict__ res,
    float* __restrict__ yg)
{
    __shared__ float4 spack[LC][DT];   // 32 KB
    __shared__ float2 sbc[LC][16];     //  8 KB

    const int t  = threadIdx.x;
    const int c  = blockIdx.x;
    const int d0 = blockIdx.y * DT;

    {
        const int r = t >> 3, c4 = (t & 7) * 4;
        const size_t row = (size_t)(c * LC + r) * D_IN + d0 + c4;
        const float4 dv4 = *(const float4*)&delta[row];
        const float4 uv4 = *(const float4*)&u[row];
        const float4 sx4 = *(const float4*)&sfxbuf[row];
        const float4 rs4 = *(const float4*)&res[row];
        spack[r][c4 + 0] = make_float4(dv4.x, uv4.x, sx4.x, rs4.x);
        spack[r][c4 + 1] = make_float4(dv4.y, uv4.y, sx4.y, rs4.y);
        spack[r][c4 + 2] = make_float4(dv4.z, uv4.z, sx4.z, rs4.z);
        spack[r][c4 + 3] = make_float4(dv4.w, uv4.w, sx4.w, rs4.w);
    }
    if (t < 256) {
        const int r = t >> 2, n4 = (t & 3) * 4;
        const float4 b4 = *(const float4*)&xdbl[(size_t)(c * LC + r) * XDBL_LD + DT_RANK + n4];
        const float4 c4v = *(const float4*)&xdbl[(size_t)(c * LC + r) * XDBL_LD + DT_RANK + 16 + n4];
        sbc[r][n4 + 0] = make_float2(b4.x, c4v.x);
        sbc[r][n4 + 1] = make_float2(b4.y, c4v.y);
        sbc[r][n4 + 2] = make_float2(b4.z, c4v.z);
        sbc[r][n4 + 3] = make_float2(b4.w, c4v.w);
    }
    __syncthreads();

    const int n  = t & 15;
    const int dq = t >> 4;
    const int d  = d0 + dq;
    const float An2 = -expf(Alog[d * N_STATE + n]) * LOG2E;
    const float Dd = Dvec[d];

    float h = H0buf[((size_t)c * D_IN + d) * N_STATE + n];

#pragma unroll
    for (int i = 0; i < LC; ++i) {
        const float4 p = spack[i][dq];
        const float2 bc = sbc[i][n];
        const float E  = fast_exp2(An2 * p.z);
        const float g  = E * fast_rcp(E + 1e-12f);
        h = fmaf(h, fast_exp2(An2 * p.x), (p.x * p.y) * bc.x);
        float contrib = h * g * bc.y;
        contrib = dpp_add<0xB1>(contrib);    // quad_perm 1,0,3,2  (xor 1)
        contrib = dpp_add<0x4E>(contrib);    // quad_perm 2,3,0,1  (xor 2)
        contrib = dpp_add<0x128>(contrib);   // row_ror:8
        contrib = dpp_add<0x124>(contrib);   // row_ror:4
        if (n == 0) {
            const float rv = p.w;
            const float sg = fast_rcp(1.f + fast_exp2(-LOG2E * rv));
            yg[(size_t)(c * LC + i) * D_IN + d] = (contrib + p.y * Dd) * (rv * sg);
        }
    }
}

// ---------------------------------------------------------------------------
// Launch.  Workspace (74.5 MB peak, time-multiplexed; ws proven >= 84.9 MB):
//   [ 0    ,16.78M): xi -> wxp [16][2048][128] -> sfx -> yg_hi/yg_lo
//   [16.78 ,33.55 ): res
//   [33.55 ,50.33 ): x_hi/x_lo -> u (f32) -> wo_hi/wo_lo
//   [50.33 ,51.38 ): xdbl [2048][128] f32
//   [51.38 ,68.16 ): wi_hi/wi_lo -> u_hi/u_lo -> delta/yg
//   [68.16 ,73.42 ): hfin, csum, P0, Td
//   [73.42 ,74.47 ): wx_hi/wx_lo
// ---------------------------------------------------------------------------
extern "C" void kernel_launch(void* const* d_in, const int* in_sizes, int n_in,
                              void* d_out, int out_size, void* d_ws, size_t ws_size,
                              hipStream_t stream)
{
    const float* x      = (const float*)d_in[0];
    const float* W_in   = (const float*)d_in[1];
    const float* conv_w = (const float*)d_in[2];
    const float* W_x    = (const float*)d_in[3];
    const float* W_del  = (const float*)d_in[4];
    const float* b_del  = (const float*)d_in[5];
    const float* A_log  = (const float*)d_in[6];
    const float* Dv     = (const float*)d_in[7];
    const float* W_out  = (const float*)d_in[8];
    float* out = (float*)d_out;

    char* ws = (char*)d_ws;
    float*  xi    = (float*)(ws + 0);
    float*  wxp   = (float*)(ws + 0);          // partials (xi dead after conv)
    float*  sfx   = (float*)(ws + 0);          // after wx_reduce
    ushort* yg_hi = (ushort*)(ws + 0);         // after partC
    ushort* yg_lo = (ushort*)(ws + 8388608);
    float*  res   = (float*)(ws + 16777216);
    ushort* x_hi  = (ushort*)(ws + 33554432);
    ushort* x_lo  = (ushort*)(ws + 37748736);
    float*  u     = (float*)(ws + 33554432);
    ushort* wo_hi = (ushort*)(ws + 33554432);
    ushort* wo_lo = (ushort*)(ws + 37748736);
    float*  xdbl  = (float*)(ws + 50331648);
    ushort* wi_hi = (ushort*)(ws + 51380224);
    ushort* wi_lo = (ushort*)(ws + 59768832);
    ushort* u_hi  = (ushort*)(ws + 51380224);  // after gemm #1 (wi dead)
    ushort* u_lo  = (ushort*)(ws + 59768832);
    float*  delta = (float*)(ws + 51380224);   // after wx gemm (u_hi dead)
    float*  hfin  = (float*)(ws + 68157440);
    double* csum  = (double*)(ws + 72351744);
    double* P0    = (double*)(ws + 72876032);
    double* Td    = (double*)(ws + 73400320);
    ushort* wx_hi = (ushort*)(ws + 73416704);
    ushort* wx_lo = (ushort*)(ws + 73940992);
    float*  yg    = delta;   // pass C stages reads to LDS before writing

    // 1) W_in^T split
    split_transpose<<<dim3(4096 / 32, 1024 / 32), 256, 0, stream>>>(
        W_in, wi_hi, wi_lo, 1024, 4096);

    // 2) x split
    split_bf16<<<(SEQ * D_MODEL / 4) / 256, 256, 0, stream>>>(x, x_hi, x_lo);

    // 3) [xi | res] = x @ W_in
    gemm_mfma3<<<dim3(4096 / 128, 2048 / 128), 256, 0, stream>>>(
        x_hi, x_lo, wi_hi, wi_lo, xi, res, D_IN,
        SEQ, 2 * D_IN, D_MODEL, D_IN, D_IN);

    // 4) u = silu(conv(xi)) + u hi/lo split (fused)
    conv_silu_split<<<(SEQ * D_IN) / 256, 256, 0, stream>>>(
        xi, conv_w, u, u_hi, u_lo);

    // 5) W_x^T padded split
    split_transpose_pad<<<dim3(XDBL_LD / 32, D_IN / 32), 256, 0, stream>>>(
        W_x, wx_hi, wx_lo, D_IN, XDBL_W);

    // 6) x_dbl = u @ W_x  (split-K MFMA, fixed-order reduce)
    gemm_wx_mfma<<<dim3(WX_KSPLIT, SEQ / 128), 256, 0, stream>>>(
        u_hi, u_lo, wx_hi, wx_lo, wxp);
    wx_reduce<<<(SEQ * XDBL_LD / 4) / 256, 256, 0, stream>>>(wxp, xdbl);

    // 7) delta = softplus(delta_lr @ W_delta + b_delta)
    gemm128<<<dim3(2048 / 128, 2048 / 128), 256, 0, stream>>>(
        xdbl, W_del, delta, SEQ, D_IN, DT_RANK, XDBL_LD, D_IN, D_IN,
        b_del, 1);

    // 8) chunk sums + prefix + per-element suffix (double, deterministic)
    csum64<<<dim3(D_IN / 256, NCH), 256, 0, stream>>>(delta, csum);
    chunk_prefix<<<D_IN / 256, 256, 0, stream>>>(csum, P0, Td);
    sfx_precompute<<<dim3(D_IN / 256, NCH), 256, 0, stream>>>(delta, P0, Td, sfx);

    // 9) chunk-parallel selective scan
    scan_partA<<<dim3(NCH, D_IN / DT), 512, 0, stream>>>(delta, u, xdbl, A_log, hfin);
    scan_combine<<<(D_IN * N_STATE) / 256, 256, 0, stream>>>(hfin, csum, A_log);
    scan_partC<<<dim3(NCH, D_IN / DT), 512, 0, stream>>>(
        delta, u, xdbl, hfin, sfx, A_log, Dv, res, yg);

    // 10) yg split (sfx dead; region reused)
    split_bf16<<<(SEQ * D_IN / 4) / 256, 256, 0, stream>>>(yg, yg_hi, yg_lo);

    // 11) W_out^T split (u dead; region reused)
    split_transpose<<<dim3(1024 / 32, 2048 / 32), 256, 0, stream>>>(
        W_out, wo_hi, wo_lo, 2048, 1024);

    // 12) out = yg @ W_out
    gemm_mfma3<<<dim3(1024 / 128, 2048 / 128), 256, 0, stream>>>(
        yg_hi, yg_lo, wo_hi, wo_lo, out, out, D_MODEL,
        SEQ, D_MODEL, D_IN, D_MODEL, D_MODEL);
}

// Round 9
// 273.066 us; speedup vs baseline: 5.0953x; 1.1085x over previous
//
#include <hip/hip_runtime.h>
#include <hip/hip_bf16.h>
#include <math.h>

// ---------------------------------------------------------------------------
// Shapes (compile-time constants for this problem)
// ---------------------------------------------------------------------------
#define SEQ     2048
#define D_MODEL 1024
#define D_IN    2048
#define N_STATE 16
#define DT_RANK 64
#define XDBL_W  96          // DT_RANK + 2*N_STATE
#define XDBL_LD 128         // padded leading dim of x_dbl
#define LC      64          // scan chunk length
#define NCH     32          // SEQ / LC
#define DT      32          // d-channels per scan block
#define WX_KSPLIT 16
#define WX_KSEG   (D_IN / WX_KSPLIT)   // 128
#define OUT_KSPLIT 4
#define OUT_KSEG   (D_IN / OUT_KSPLIT) // 512

#define LOG2E   1.4426950408889634f

typedef __attribute__((ext_vector_type(8))) short bf16x8;
typedef __attribute__((ext_vector_type(4))) float f32x4;

__device__ __forceinline__ float fast_exp2(float x) { return __builtin_amdgcn_exp2f(x); }
__device__ __forceinline__ float fast_rcp(float x)  { return __builtin_amdgcn_rcpf(x); }

// async global->LDS, 16 bytes/lane; LDS dest = wave-uniform base + lane*16.
__device__ __forceinline__ void gload16(const ushort* g, ushort* l) {
    __builtin_amdgcn_global_load_lds(
        (const __attribute__((address_space(1))) void*)g,
        (__attribute__((address_space(3))) void*)l, 16, 0, 0);
}

// Pre-swizzled-source staging: LDS linear (slot idx = q*256 + wave*64 + lane),
// each lane fetches global col-block (lane&7)^(lane>>3) so LDS holds the
// XOR-swizzled layout ( [r][ (kc^(r&7))*8 ] ) the MFMA ds_read_b128 expects.
#define GL_DEFS                                                                \
    const int lane8 = lane >> 3;                                               \
    const int scol  = (lane & 7) ^ lane8;                                      \
    const int wq    = wave * 8;

#define STAGE_GL(SRC, DST, BASE, LDK, KOFF)                                    \
    _Pragma("unroll")                                                          \
    for (int q = 0; q < 4; ++q) {                                              \
        const int rr = q * 32 + wq + lane8;                                    \
        gload16(&SRC[(size_t)((BASE) + rr) * (LDK) + (KOFF) + scol * 8],       \
                ((ushort*)DST) + (q * 256 + wave * 64) * 8);                   \
    }

// v_add_f32 with DPP-moved operand: 16-lane butterfly without the DS pipe.
template <int CTRL>
__device__ __forceinline__ float dpp_add(float x) {
    int y = __builtin_amdgcn_update_dpp(0, __float_as_int(x), CTRL, 0xF, 0xF, true);
    return x + __int_as_float(y);
}

__device__ __forceinline__ ushort f2bf(float x) {
    unsigned u = __float_as_uint(x);
    u += 0x7FFFu + ((u >> 16) & 1u);      // RNE
    return (ushort)(u >> 16);
}
__device__ __forceinline__ float bf2f(ushort h) {
    return __uint_as_float(((unsigned)h) << 16);
}

// ---------------------------------------------------------------------------
// split fp32 -> bf16 hi/lo (elementwise). One float4 per thread.
// ---------------------------------------------------------------------------
__global__ __launch_bounds__(256) void split_bf16(
    const float* __restrict__ in, ushort* __restrict__ hi,
    ushort* __restrict__ lo)
{
    const int i = blockIdx.x * 256 + threadIdx.x;
    const float4 v = *(const float4*)&in[(size_t)i * 4];
    ushort4 h, l;
    h.x = f2bf(v.x); l.x = f2bf(v.x - bf2f(h.x));
    h.y = f2bf(v.y); l.y = f2bf(v.y - bf2f(h.y));
    h.z = f2bf(v.z); l.z = f2bf(v.z - bf2f(h.z));
    h.w = f2bf(v.w); l.w = f2bf(v.w - bf2f(h.w));
    *(ushort4*)&hi[(size_t)i * 4] = h;
    *(ushort4*)&lo[(size_t)i * 4] = l;
}

// ---------------------------------------------------------------------------
// split + transpose: in[R][C] fp32 -> hi/lo[C][R] bf16.
// ---------------------------------------------------------------------------
__global__ __launch_bounds__(256) void split_transpose(
    const float* __restrict__ in, ushort* __restrict__ hi,
    ushort* __restrict__ lo, int R, int C)
{
    __shared__ float tile[32][33];
    const int c0 = blockIdx.x * 32;
    const int r0 = blockIdx.y * 32;
    const int tc = threadIdx.x & 31;
    const int tr = threadIdx.x >> 5;
#pragma unroll
    for (int q = 0; q < 4; ++q)
        tile[tr + 8 * q][tc] = in[(size_t)(r0 + tr + 8 * q) * C + c0 + tc];
    __syncthreads();
#pragma unroll
    for (int q = 0; q < 4; ++q) {
        const float v = tile[tc][tr + 8 * q];
        const ushort h = f2bf(v);
        const ushort l = f2bf(v - bf2f(h));
        const size_t o = (size_t)(c0 + tr + 8 * q) * R + r0 + tc;
        hi[o] = h;
        lo[o] = l;
    }
}

// ---------------------------------------------------------------------------
// split + transpose with zero padding on the output-row axis.
// ---------------------------------------------------------------------------
__global__ __launch_bounds__(256) void split_transpose_pad(
    const float* __restrict__ in, ushort* __restrict__ hi,
    ushort* __restrict__ lo, int R, int Csrc)
{
    __shared__ float tile[32][33];
    const int c0 = blockIdx.x * 32;
    const int r0 = blockIdx.y * 32;
    const int tc = threadIdx.x & 31;
    const int tr = threadIdx.x >> 5;
#pragma unroll
    for (int q = 0; q < 4; ++q) {
        const int c = c0 + tc;
        tile[tr + 8 * q][tc] =
            (c < Csrc) ? in[(size_t)(r0 + tr + 8 * q) * Csrc + c] : 0.f;
    }
    __syncthreads();
#pragma unroll
    for (int q = 0; q < 4; ++q) {
        const float v = tile[tc][tr + 8 * q];
        const ushort h = f2bf(v);
        const ushort l = f2bf(v - bf2f(h));
        const size_t o = (size_t)(c0 + tr + 8 * q) * R + r0 + tc;
        hi[o] = h;
        lo[o] = l;
    }
}

// ---------------------------------------------------------------------------
// bf16x3-split MFMA GEMM (A row-major hi/lo, B transposed hi/lo).
// acc += Ahi*Bhi + Ahi*Blo + Alo*Bhi.  Tile 128x128, K-step 64, 4 waves.
// Staging via global_load_lds with pre-swizzled source.
// ---------------------------------------------------------------------------
__global__ __launch_bounds__(256) void gemm_mfma3(
    const ushort* __restrict__ Ahi, const ushort* __restrict__ Alo,
    const ushort* __restrict__ Bhi, const ushort* __restrict__ Blo,
    float* __restrict__ C0, float* __restrict__ C1, int nsplit,
    int M, int N, int K, int ldc0, int ldc1)
{
    __shared__ ushort lA[2][128][64];
    __shared__ ushort lB[2][128][64];

    const int t    = threadIdx.x;
    const int m0   = blockIdx.y * 128;
    const int n0   = blockIdx.x * 128;
    const int wave = t >> 6;
    const int lane = t & 63;
    const int mw   = (wave & 1) * 64;
    const int nw   = (wave >> 1) * 64;
    const int l15  = lane & 15;
    const int l4   = lane >> 4;
    const int sw   = l15 & 7;
    GL_DEFS

    f32x4 acc[4][4];
#pragma unroll
    for (int i = 0; i < 4; ++i)
#pragma unroll
        for (int j = 0; j < 4; ++j)
            acc[i][j] = (f32x4){0.f, 0.f, 0.f, 0.f};

    for (int k0 = 0; k0 < K; k0 += 64) {
        __syncthreads();                 // previous iteration done reading LDS
        STAGE_GL(Ahi, lA[0], m0, K, k0)
        STAGE_GL(Alo, lA[1], m0, K, k0)
        STAGE_GL(Bhi, lB[0], n0, K, k0)
        STAGE_GL(Blo, lB[1], n0, K, k0)
        __syncthreads();                 // drains vmcnt (loads landed in LDS)

#pragma unroll
        for (int ks = 0; ks < 2; ++ks) {
            const int slot = (((ks << 2) | l4) ^ sw) * 8;
            bf16x8 ah[4], al[4], bh[4], bl[4];
#pragma unroll
            for (int f = 0; f < 4; ++f) {
                const int ar = mw + f * 16 + l15;
                const int br = nw + f * 16 + l15;
                ah[f] = *(const bf16x8*)&lA[0][ar][slot];
                al[f] = *(const bf16x8*)&lA[1][ar][slot];
                bh[f] = *(const bf16x8*)&lB[0][br][slot];
                bl[f] = *(const bf16x8*)&lB[1][br][slot];
            }
#pragma unroll
            for (int i = 0; i < 4; ++i)
#pragma unroll
                for (int j = 0; j < 4; ++j) {
                    acc[i][j] = __builtin_amdgcn_mfma_f32_16x16x32_bf16(
                        ah[i], bh[j], acc[i][j], 0, 0, 0);
                    acc[i][j] = __builtin_amdgcn_mfma_f32_16x16x32_bf16(
                        ah[i], bl[j], acc[i][j], 0, 0, 0);
                    acc[i][j] = __builtin_amdgcn_mfma_f32_16x16x32_bf16(
                        al[i], bh[j], acc[i][j], 0, 0, 0);
                }
        }
    }

#pragma unroll
    for (int i = 0; i < 4; ++i) {
        const int rowg = m0 + mw + i * 16 + l4 * 4;
#pragma unroll
        for (int j = 0; j < 4; ++j) {
            const int colg = n0 + nw + j * 16 + l15;
            float* base;
            int cc, ldc;
            if (colg < nsplit) { base = C0; cc = colg;          ldc = ldc0; }
            else               { base = C1; cc = colg - nsplit; ldc = ldc1; }
#pragma unroll
            for (int v = 0; v < 4; ++v)
                base[(size_t)(rowg + v) * ldc + cc] = acc[i][j][v];
        }
    }
}

// ---------------------------------------------------------------------------
// split-K MFMA GEMM for x_dbl = u @ W_x (N padded 96->128).
// ---------------------------------------------------------------------------
__global__ __launch_bounds__(256) void gemm_wx_mfma(
    const ushort* __restrict__ Ahi, const ushort* __restrict__ Alo,
    const ushort* __restrict__ Bhi, const ushort* __restrict__ Blo,
    float* __restrict__ part)
{
    __shared__ ushort lA[2][128][64];
    __shared__ ushort lB[2][128][64];

    const int t    = threadIdx.x;
    const int kb   = blockIdx.x;
    const int m0   = blockIdx.y * 128;
    const int wave = t >> 6;
    const int lane = t & 63;
    const int mw   = (wave & 1) * 64;
    const int nw   = (wave >> 1) * 64;
    const int l15  = lane & 15;
    const int l4   = lane >> 4;
    const int sw   = l15 & 7;
    const int kbase = kb * WX_KSEG;
    GL_DEFS

    f32x4 acc[4][4];
#pragma unroll
    for (int i = 0; i < 4; ++i)
#pragma unroll
        for (int j = 0; j < 4; ++j)
            acc[i][j] = (f32x4){0.f, 0.f, 0.f, 0.f};

    for (int k0 = 0; k0 < WX_KSEG; k0 += 64) {
        __syncthreads();
        STAGE_GL(Ahi, lA[0], m0, D_IN, kbase + k0)
        STAGE_GL(Alo, lA[1], m0, D_IN, kbase + k0)
        STAGE_GL(Bhi, lB[0], 0,  D_IN, kbase + k0)
        STAGE_GL(Blo, lB[1], 0,  D_IN, kbase + k0)
        __syncthreads();

#pragma unroll
        for (int ks = 0; ks < 2; ++ks) {
            const int slot = (((ks << 2) | l4) ^ sw) * 8;
            bf16x8 ah[4], al[4], bh[4], bl[4];
#pragma unroll
            for (int f = 0; f < 4; ++f) {
                const int ar = mw + f * 16 + l15;
                const int br = nw + f * 16 + l15;
                ah[f] = *(const bf16x8*)&lA[0][ar][slot];
                al[f] = *(const bf16x8*)&lA[1][ar][slot];
                bh[f] = *(const bf16x8*)&lB[0][br][slot];
                bl[f] = *(const bf16x8*)&lB[1][br][slot];
            }
#pragma unroll
            for (int i = 0; i < 4; ++i)
#pragma unroll
                for (int j = 0; j < 4; ++j) {
                    acc[i][j] = __builtin_amdgcn_mfma_f32_16x16x32_bf16(
                        ah[i], bh[j], acc[i][j], 0, 0, 0);
                    acc[i][j] = __builtin_amdgcn_mfma_f32_16x16x32_bf16(
                        ah[i], bl[j], acc[i][j], 0, 0, 0);
                    acc[i][j] = __builtin_amdgcn_mfma_f32_16x16x32_bf16(
                        al[i], bh[j], acc[i][j], 0, 0, 0);
                }
        }
    }

#pragma unroll
    for (int i = 0; i < 4; ++i) {
        const int rowg = m0 + mw + i * 16 + l4 * 4;
#pragma unroll
        for (int j = 0; j < 4; ++j) {
            const int colg = nw + j * 16 + l15;
#pragma unroll
            for (int v = 0; v < 4; ++v)
                part[((size_t)kb * SEQ + rowg + v) * XDBL_LD + colg] =
                    acc[i][j][v];
        }
    }
}

// Fixed-order reduction of the WX_KSPLIT partials -> xdbl [SEQ][XDBL_LD].
__global__ __launch_bounds__(256) void wx_reduce(
    const float* __restrict__ part, float* __restrict__ xdbl)
{
    const size_t i = (size_t)(blockIdx.x * 256 + threadIdx.x) * 4;
    float4 s = *(const float4*)&part[i];
#pragma unroll
    for (int kb = 1; kb < WX_KSPLIT; ++kb) {
        const float4 v = *(const float4*)&part[(size_t)kb * SEQ * XDBL_LD + i];
        s.x += v.x; s.y += v.y; s.z += v.z; s.w += v.w;
    }
    *(float4*)&xdbl[i] = s;
}

// ---------------------------------------------------------------------------
// split-K=4 MFMA GEMM for out = yg @ W_out (M=SEQ, N=D_MODEL, K=D_IN).
// Grid (N/128, M/128, 4).  Partials: slice kb -> (kb&2 ? p23 : p01)
// + (kb&1)*SEQ*D_MODEL.  Fills 512 blocks (2/CU) vs 128 unsplit.
// ---------------------------------------------------------------------------
__global__ __launch_bounds__(256) void gemm_out_mfma(
    const ushort* __restrict__ Ahi, const ushort* __restrict__ Alo,
    const ushort* __restrict__ Bhi, const ushort* __restrict__ Blo,
    float* __restrict__ p01, float* __restrict__ p23)
{
    __shared__ ushort lA[2][128][64];
    __shared__ ushort lB[2][128][64];

    const int t    = threadIdx.x;
    const int n0   = blockIdx.x * 128;
    const int m0   = blockIdx.y * 128;
    const int kb   = blockIdx.z;
    const int wave = t >> 6;
    const int lane = t & 63;
    const int mw   = (wave & 1) * 64;
    const int nw   = (wave >> 1) * 64;
    const int l15  = lane & 15;
    const int l4   = lane >> 4;
    const int sw   = l15 & 7;
    const int kbase = kb * OUT_KSEG;
    GL_DEFS

    f32x4 acc[4][4];
#pragma unroll
    for (int i = 0; i < 4; ++i)
#pragma unroll
        for (int j = 0; j < 4; ++j)
            acc[i][j] = (f32x4){0.f, 0.f, 0.f, 0.f};

    for (int k0 = 0; k0 < OUT_KSEG; k0 += 64) {
        __syncthreads();
        STAGE_GL(Ahi, lA[0], m0, D_IN, kbase + k0)
        STAGE_GL(Alo, lA[1], m0, D_IN, kbase + k0)
        STAGE_GL(Bhi, lB[0], n0, D_IN, kbase + k0)
        STAGE_GL(Blo, lB[1], n0, D_IN, kbase + k0)
        __syncthreads();

#pragma unroll
        for (int ks = 0; ks < 2; ++ks) {
            const int slot = (((ks << 2) | l4) ^ sw) * 8;
            bf16x8 ah[4], al[4], bh[4], bl[4];
#pragma unroll
            for (int f = 0; f < 4; ++f) {
                const int ar = mw + f * 16 + l15;
                const int br = nw + f * 16 + l15;
                ah[f] = *(const bf16x8*)&lA[0][ar][slot];
                al[f] = *(const bf16x8*)&lA[1][ar][slot];
                bh[f] = *(const bf16x8*)&lB[0][br][slot];
                bl[f] = *(const bf16x8*)&lB[1][br][slot];
            }
#pragma unroll
            for (int i = 0; i < 4; ++i)
#pragma unroll
                for (int j = 0; j < 4; ++j) {
                    acc[i][j] = __builtin_amdgcn_mfma_f32_16x16x32_bf16(
                        ah[i], bh[j], acc[i][j], 0, 0, 0);
                    acc[i][j] = __builtin_amdgcn_mfma_f32_16x16x32_bf16(
                        ah[i], bl[j], acc[i][j], 0, 0, 0);
                    acc[i][j] = __builtin_amdgcn_mfma_f32_16x16x32_bf16(
                        al[i], bh[j], acc[i][j], 0, 0, 0);
                }
        }
    }

    float* base = (kb & 2) ? p23 : p01;
    base += (size_t)(kb & 1) * SEQ * D_MODEL;
#pragma unroll
    for (int i = 0; i < 4; ++i) {
        const int rowg = m0 + mw + i * 16 + l4 * 4;
#pragma unroll
        for (int j = 0; j < 4; ++j) {
            const int colg = n0 + nw + j * 16 + l15;
#pragma unroll
            for (int v = 0; v < 4; ++v)
                base[(size_t)(rowg + v) * D_MODEL + colg] = acc[i][j][v];
        }
    }
}

// Fixed-order reduce of the 4 output partials -> out [SEQ][D_MODEL].
__global__ __launch_bounds__(256) void out_reduce(
    const float* __restrict__ p01, const float* __restrict__ p23,
    float* __restrict__ out)
{
    const size_t i = (size_t)(blockIdx.x * 256 + threadIdx.x) * 4;
    const size_t MN = (size_t)SEQ * D_MODEL;
    const float4 a = *(const float4*)&p01[i];
    const float4 b = *(const float4*)&p01[i + MN];
    const float4 c = *(const float4*)&p23[i];
    const float4 d = *(const float4*)&p23[i + MN];
    float4 s;
    s.x = ((a.x + b.x) + c.x) + d.x;
    s.y = ((a.y + b.y) + c.y) + d.y;
    s.z = ((a.z + b.z) + c.z) + d.z;
    s.w = ((a.w + b.w) + c.w) + d.w;
    *(float4*)&out[i] = s;
}

// ---------------------------------------------------------------------------
// fp32 tiled GEMM (small delta GEMM, K=64)
// ---------------------------------------------------------------------------
__global__ __launch_bounds__(256) void gemm128(
    const float* __restrict__ A, const float* __restrict__ B,
    float* __restrict__ C, int M, int N, int K,
    int lda, int ldb, int ldc,
    const float* __restrict__ bias, int act)
{
    __shared__ float As[16][132];
    __shared__ float Bs[16][132];

    const int t   = threadIdx.x;
    const int bn0 = blockIdx.x * 128;
    const int bm0 = blockIdx.y * 128;
    const int tx  = t & 15;
    const int ty  = t >> 4;

    const int ar  = t >> 2;
    const int ak  = (t & 3) * 4;
    const int bk  = t >> 5;
    const int bn4 = (t & 31) * 4;

    float acc[8][8];
#pragma unroll
    for (int i = 0; i < 8; ++i)
#pragma unroll
        for (int j = 0; j < 8; ++j) acc[i][j] = 0.f;

    for (int k0 = 0; k0 < K; k0 += 16) {
        float4 a0 = *(const float4*)&A[(size_t)(bm0 + ar)      * lda + k0 + ak];
        float4 a1 = *(const float4*)&A[(size_t)(bm0 + ar + 64) * lda + k0 + ak];
        float4 b0 = *(const float4*)&B[(size_t)(k0 + bk)     * ldb + bn0 + bn4];
        float4 b1 = *(const float4*)&B[(size_t)(k0 + bk + 8) * ldb + bn0 + bn4];

        __syncthreads();
        As[ak + 0][ar] = a0.x; As[ak + 1][ar] = a0.y;
        As[ak + 2][ar] = a0.z; As[ak + 3][ar] = a0.w;
        As[ak + 0][ar + 64] = a1.x; As[ak + 1][ar + 64] = a1.y;
        As[ak + 2][ar + 64] = a1.z; As[ak + 3][ar + 64] = a1.w;
        *(float4*)&Bs[bk][bn4]     = b0;
        *(float4*)&Bs[bk + 8][bn4] = b1;
        __syncthreads();

#pragma unroll
        for (int kk = 0; kk < 16; ++kk) {
            float a[8], b[8];
            ((float4*)a)[0] = *(const float4*)&As[kk][ty * 8];
            ((float4*)a)[1] = *(const float4*)&As[kk][ty * 8 + 4];
            ((float4*)b)[0] = *(const float4*)&Bs[kk][tx * 8];
            ((float4*)b)[1] = *(const float4*)&Bs[kk][tx * 8 + 4];
#pragma unroll
            for (int i = 0; i < 8; ++i)
#pragma unroll
                for (int j = 0; j < 8; ++j)
                    acc[i][j] = fmaf(a[i], b[j], acc[i][j]);
        }
    }

    const int row = bm0 + ty * 8;
    const int col = bn0 + tx * 8;
#pragma unroll
    for (int i = 0; i < 8; ++i) {
        float vals[8];
#pragma unroll
        for (int j = 0; j < 8; ++j) {
            float v = acc[i][j];
            if (act == 1) {
                v += bias[col + j];
                v = (v > 20.f) ? v : log1pf(__expf(v));
            }
            vals[j] = v;
        }
        *(float4*)&C[(size_t)(row + i) * ldc + col]     = ((float4*)vals)[0];
        *(float4*)&C[(size_t)(row + i) * ldc + col + 4] = ((float4*)vals)[1];
    }
}

// ---------------------------------------------------------------------------
// Depthwise causal conv (K=3) + SiLU, fused with bf16 hi/lo split of u.
// ---------------------------------------------------------------------------
__global__ __launch_bounds__(256) void conv_silu_split(
    const float* __restrict__ xi, const float* __restrict__ cw,
    float* __restrict__ u, ushort* __restrict__ uhi, ushort* __restrict__ ulo)
{
    const int id = blockIdx.x * 256 + threadIdx.x;
    const int l = id >> 11;
    const int d = id & (D_IN - 1);
    const float w0 = cw[d * 3 + 0];
    const float w1 = cw[d * 3 + 1];
    const float w2 = cw[d * 3 + 2];
    const float x0  = xi[(size_t)l * D_IN + d];
    const float xm1 = (l >= 1) ? xi[(size_t)(l - 1) * D_IN + d] : 0.f;
    const float xm2 = (l >= 2) ? xi[(size_t)(l - 2) * D_IN + d] : 0.f;
    const float v = w0 * xm2 + w1 * xm1 + w2 * x0;
    const float s = fast_rcp(1.f + fast_exp2(-LOG2E * v));
    const float uu = v * s;
    u[id] = uu;
    const ushort h = f2bf(uu);
    uhi[id] = h;
    ulo[id] = f2bf(uu - bf2f(h));
}

// ---------------------------------------------------------------------------
// Per-chunk column sums of delta (double)
// ---------------------------------------------------------------------------
__global__ __launch_bounds__(256) void csum64(
    const float* __restrict__ delta, double* __restrict__ csum)
{
    const int d = blockIdx.x * 256 + threadIdx.x;
    const int c = blockIdx.y;
    double s = 0.0;
    for (int i = 0; i < LC; ++i)
        s += (double)delta[(size_t)(c * LC + i) * D_IN + d];
    csum[(size_t)c * D_IN + d] = s;
}

__global__ __launch_bounds__(256) void chunk_prefix(
    const double* __restrict__ csum, double* __restrict__ P0,
    double* __restrict__ Td)
{
    const int d = blockIdx.x * 256 + threadIdx.x;
    double P = 0.0;
    for (int c = 0; c < NCH; ++c) {
        P0[(size_t)c * D_IN + d] = P;
        P += csum[(size_t)c * D_IN + d];
    }
    Td[d] = P;
}

// ---------------------------------------------------------------------------
// sfx[l][d] = float(max(Td - P_inclusive(l), 0))
// ---------------------------------------------------------------------------
__global__ __launch_bounds__(256) void sfx_precompute(
    const float* __restrict__ delta, const double* __restrict__ P0,
    const double* __restrict__ Td, float* __restrict__ sfx)
{
    const int d = blockIdx.x * 256 + threadIdx.x;
    const int c = blockIdx.y;
    double P = P0[(size_t)c * D_IN + d];
    const double T = Td[d];
    for (int i = 0; i < LC; ++i) {
        P += (double)delta[(size_t)(c * LC + i) * D_IN + d];
        sfx[(size_t)(c * LC + i) * D_IN + d] = (float)fmax(T - P, 0.0);
    }
}

// ---------------------------------------------------------------------------
// Pass A: per-chunk local scan from h=0. Packed LDS: (dv, dv*u) float2 + B.
// ---------------------------------------------------------------------------
__global__ __launch_bounds__(512) void scan_partA(
    const float* __restrict__ delta, const float* __restrict__ u,
    const float* __restrict__ xdbl, const float* __restrict__ Alog,
    float* __restrict__ hfin)
{
    __shared__ float2 spA[LC][DT];     // (delta, delta*u)  16 KB
    __shared__ float  sBA[LC][16];     // B                  4 KB

    const int t  = threadIdx.x;
    const int c  = blockIdx.x;
    const int d0 = blockIdx.y * DT;

    {
        const int r = t >> 3, c4 = (t & 7) * 4;
        const float4 dv4 = *(const float4*)&delta[(size_t)(c * LC + r) * D_IN + d0 + c4];
        const float4 uv4 = *(const float4*)&u[(size_t)(c * LC + r) * D_IN + d0 + c4];
        spA[r][c4 + 0] = make_float2(dv4.x, dv4.x * uv4.x);
        spA[r][c4 + 1] = make_float2(dv4.y, dv4.y * uv4.y);
        spA[r][c4 + 2] = make_float2(dv4.z, dv4.z * uv4.z);
        spA[r][c4 + 3] = make_float2(dv4.w, dv4.w * uv4.w);
    }
    if (t < 256) {
        const int r = t >> 2, c4 = (t & 3) * 4;
        *(float4*)&sBA[r][c4] =
            *(const float4*)&xdbl[(size_t)(c * LC + r) * XDBL_LD + DT_RANK + c4];
    }
    __syncthreads();

    const int n  = t & 15;
    const int dq = t >> 4;
    const int d  = d0 + dq;
    const float An2 = -expf(Alog[d * N_STATE + n]) * LOG2E;

    float h = 0.f;
#pragma unroll
    for (int i = 0; i < LC; ++i) {
        const float2 p = spA[i][dq];
        h = fmaf(h, fast_exp2(An2 * p.x), p.y * sBA[i][n]);
    }
    hfin[((size_t)c * D_IN + d) * N_STATE + n] = h;
}

// ---------------------------------------------------------------------------
// Pass B: serial combine across chunks; hfin becomes incoming state H0.
// ---------------------------------------------------------------------------
__global__ __launch_bounds__(256) void scan_combine(
    float* __restrict__ hfin, const double* __restrict__ csum,
    const float* __restrict__ Alog)
{
    const int id = blockIdx.x * 256 + threadIdx.x;
    const int d = id >> 4;
    const int n = id & 15;
    const float An2 = -expf(Alog[d * N_STATE + n]) * LOG2E;
    float H = 0.f;
    for (int c = 0; c < NCH; ++c) {
        const size_t idx = ((size_t)c * D_IN + d) * N_STATE + n;
        const float hf = hfin[idx];
        hfin[idx] = H;
        const float Dec = fast_exp2(An2 * (float)csum[(size_t)c * D_IN + d]);
        H = fmaf(H, Dec, hf);
    }
}

// ---------------------------------------------------------------------------
// Pass C: scan + gate + n-reduce + res-SiLU. Packed LDS + DPP n-reduce.
// ---------------------------------------------------------------------------
__global__ __launch_bounds__(512) void scan_partC(
    const float* __restrict__ delta, const float* __restrict__ u,
    const float* __restrict__ xdbl, const float* __restrict__ H0buf,
    const float* __restrict__ sfxbuf, const float* __restrict__ Alog,
    const float* __restrict__ Dvec, const float* __restrict__ res,
    float* __restrict__ yg)
{
    __shared__ float4 spack[LC][DT];   // 32 KB
    __shared__ float2 sbc[LC][16];     //  8 KB

    const int t  = threadIdx.x;
    const int c  = blockIdx.x;
    const int d0 = blockIdx.y * DT;

    {
        const int r = t >> 3, c4 = (t & 7) * 4;
        const size_t row = (size_t)(c * LC + r) * D_IN + d0 + c4;
        const float4 dv4 = *(const float4*)&delta[row];
        const float4 uv4 = *(const float4*)&u[row];
        const float4 sx4 = *(const float4*)&sfxbuf[row];
        const float4 rs4 = *(const float4*)&res[row];
        spack[r][c4 + 0] = make_float4(dv4.x, uv4.x, sx4.x, rs4.x);
        spack[r][c4 + 1] = make_float4(dv4.y, uv4.y, sx4.y, rs4.y);
        spack[r][c4 + 2] = make_float4(dv4.z, uv4.z, sx4.z, rs4.z);
        spack[r][c4 + 3] = make_float4(dv4.w, uv4.w, sx4.w, rs4.w);
    }
    if (t < 256) {
        const int r = t >> 2, n4 = (t & 3) * 4;
        const float4 b4 = *(const float4*)&xdbl[(size_t)(c * LC + r) * XDBL_LD + DT_RANK + n4];
        const float4 c4v = *(const float4*)&xdbl[(size_t)(c * LC + r) * XDBL_LD + DT_RANK + 16 + n4];
        sbc[r][n4 + 0] = make_float2(b4.x, c4v.x);
        sbc[r][n4 + 1] = make_float2(b4.y, c4v.y);
        sbc[r][n4 + 2] = make_float2(b4.z, c4v.z);
        sbc[r][n4 + 3] = make_float2(b4.w, c4v.w);
    }
    __syncthreads();

    const int n  = t & 15;
    const int dq = t >> 4;
    const int d  = d0 + dq;
    const float An2 = -expf(Alog[d * N_STATE + n]) * LOG2E;
    const float Dd = Dvec[d];

    float h = H0buf[((size_t)c * D_IN + d) * N_STATE + n];

#pragma unroll
    for (int i = 0; i < LC; ++i) {
        const float4 p = spack[i][dq];
        const float2 bc = sbc[i][n];
        const float E  = fast_exp2(An2 * p.z);
        const float g  = E * fast_rcp(E + 1e-12f);
        h = fmaf(h, fast_exp2(An2 * p.x), (p.x * p.y) * bc.x);
        float contrib = h * g * bc.y;
        contrib = dpp_add<0xB1>(contrib);    // quad_perm 1,0,3,2  (xor 1)
        contrib = dpp_add<0x4E>(contrib);    // quad_perm 2,3,0,1  (xor 2)
        contrib = dpp_add<0x128>(contrib);   // row_ror:8
        contrib = dpp_add<0x124>(contrib);   // row_ror:4
        if (n == 0) {
            const float rv = p.w;
            const float sg = fast_rcp(1.f + fast_exp2(-LOG2E * rv));
            yg[(size_t)(c * LC + i) * D_IN + d] = (contrib + p.y * Dd) * (rv * sg);
        }
    }
}

// ---------------------------------------------------------------------------
// Launch.  Workspace (74.5 MB peak, time-multiplexed; ws proven >= 84.9 MB):
//   [ 0    ,16.78M): xi -> wxp -> sfx -> yg_hi/yg_lo
//   [16.78 ,33.55 ): res -> out partials p01 (after scan_partC)
//   [33.55 ,50.33 ): x_hi/x_lo -> u (f32) -> wo_hi/wo_lo
//   [50.33 ,51.38 ): xdbl [2048][128] f32
//   [51.38 ,68.16 ): wi_hi/wi_lo -> u_hi/u_lo -> delta/yg -> p23 (after split)
//   [68.16 ,73.42 ): hfin, csum, P0, Td
//   [73.42 ,74.47 ): wx_hi/wx_lo
// ---------------------------------------------------------------------------
extern "C" void kernel_launch(void* const* d_in, const int* in_sizes, int n_in,
                              void* d_out, int out_size, void* d_ws, size_t ws_size,
                              hipStream_t stream)
{
    const float* x      = (const float*)d_in[0];
    const float* W_in   = (const float*)d_in[1];
    const float* conv_w = (const float*)d_in[2];
    const float* W_x    = (const float*)d_in[3];
    const float* W_del  = (const float*)d_in[4];
    const float* b_del  = (const float*)d_in[5];
    const float* A_log  = (const float*)d_in[6];
    const float* Dv     = (const float*)d_in[7];
    const float* W_out  = (const float*)d_in[8];
    float* out = (float*)d_out;

    char* ws = (char*)d_ws;
    float*  xi    = (float*)(ws + 0);
    float*  wxp   = (float*)(ws + 0);          // partials (xi dead after conv)
    float*  sfx   = (float*)(ws + 0);          // after wx_reduce
    ushort* yg_hi = (ushort*)(ws + 0);         // after partC
    ushort* yg_lo = (ushort*)(ws + 8388608);
    float*  res   = (float*)(ws + 16777216);
    float*  p01   = (float*)(ws + 16777216);   // out partials (res dead)
    ushort* x_hi  = (ushort*)(ws + 33554432);
    ushort* x_lo  = (ushort*)(ws + 37748736);
    float*  u     = (float*)(ws + 33554432);
    ushort* wo_hi = (ushort*)(ws + 33554432);
    ushort* wo_lo = (ushort*)(ws + 37748736);
    float*  xdbl  = (float*)(ws + 50331648);
    ushort* wi_hi = (ushort*)(ws + 51380224);
    ushort* wi_lo = (ushort*)(ws + 59768832);
    ushort* u_hi  = (ushort*)(ws + 51380224);  // after gemm #1 (wi dead)
    ushort* u_lo  = (ushort*)(ws + 59768832);
    float*  delta = (float*)(ws + 51380224);   // after wx gemm (u_hi dead)
    float*  p23   = (float*)(ws + 51380224);   // out partials (yg dead)
    float*  hfin  = (float*)(ws + 68157440);
    double* csum  = (double*)(ws + 72351744);
    double* P0    = (double*)(ws + 72876032);
    double* Td    = (double*)(ws + 73400320);
    ushort* wx_hi = (ushort*)(ws + 73416704);
    ushort* wx_lo = (ushort*)(ws + 73940992);
    float*  yg    = delta;   // pass C stages reads to LDS before writing

    // 1) W_in^T split
    split_transpose<<<dim3(4096 / 32, 1024 / 32), 256, 0, stream>>>(
        W_in, wi_hi, wi_lo, 1024, 4096);

    // 2) x split
    split_bf16<<<(SEQ * D_MODEL / 4) / 256, 256, 0, stream>>>(x, x_hi, x_lo);

    // 3) [xi | res] = x @ W_in
    gemm_mfma3<<<dim3(4096 / 128, 2048 / 128), 256, 0, stream>>>(
        x_hi, x_lo, wi_hi, wi_lo, xi, res, D_IN,
        SEQ, 2 * D_IN, D_MODEL, D_IN, D_IN);

    // 4) u = silu(conv(xi)) + u hi/lo split (fused)
    conv_silu_split<<<(SEQ * D_IN) / 256, 256, 0, stream>>>(
        xi, conv_w, u, u_hi, u_lo);

    // 5) W_x^T padded split
    split_transpose_pad<<<dim3(XDBL_LD / 32, D_IN / 32), 256, 0, stream>>>(
        W_x, wx_hi, wx_lo, D_IN, XDBL_W);

    // 6) x_dbl = u @ W_x  (split-K MFMA, fixed-order reduce)
    gemm_wx_mfma<<<dim3(WX_KSPLIT, SEQ / 128), 256, 0, stream>>>(
        u_hi, u_lo, wx_hi, wx_lo, wxp);
    wx_reduce<<<(SEQ * XDBL_LD / 4) / 256, 256, 0, stream>>>(wxp, xdbl);

    // 7) delta = softplus(delta_lr @ W_delta + b_delta)
    gemm128<<<dim3(2048 / 128, 2048 / 128), 256, 0, stream>>>(
        xdbl, W_del, delta, SEQ, D_IN, DT_RANK, XDBL_LD, D_IN, D_IN,
        b_del, 1);

    // 8) chunk sums + prefix + per-element suffix (double, deterministic)
    csum64<<<dim3(D_IN / 256, NCH), 256, 0, stream>>>(delta, csum);
    chunk_prefix<<<D_IN / 256, 256, 0, stream>>>(csum, P0, Td);
    sfx_precompute<<<dim3(D_IN / 256, NCH), 256, 0, stream>>>(delta, P0, Td, sfx);

    // 9) chunk-parallel selective scan
    scan_partA<<<dim3(NCH, D_IN / DT), 512, 0, stream>>>(delta, u, xdbl, A_log, hfin);
    scan_combine<<<(D_IN * N_STATE) / 256, 256, 0, stream>>>(hfin, csum, A_log);
    scan_partC<<<dim3(NCH, D_IN / DT), 512, 0, stream>>>(
        delta, u, xdbl, hfin, sfx, A_log, Dv, res, yg);

    // 10) yg split (sfx dead; region reused)
    split_bf16<<<(SEQ * D_IN / 4) / 256, 256, 0, stream>>>(yg, yg_hi, yg_lo);

    // 11) W_out^T split (u dead; region reused)
    split_transpose<<<dim3(1024 / 32, 2048 / 32), 256, 0, stream>>>(
        W_out, wo_hi, wo_lo, 2048, 1024);

    // 12) out = yg @ W_out  (split-K=4, 512 blocks; partials in dead regions)
    gemm_out_mfma<<<dim3(D_MODEL / 128, SEQ / 128, OUT_KSPLIT), 256, 0, stream>>>(
        yg_hi, yg_lo, wo_hi, wo_lo, p01, p23);
    out_reduce<<<(SEQ * D_MODEL / 4) / 256, 256, 0, stream>>>(p01, p23, out);
}

// Round 10
// 263.005 us; speedup vs baseline: 5.2902x; 1.0383x over previous
//
#include <hip/hip_runtime.h>
#include <hip/hip_bf16.h>
#include <math.h>

// ---------------------------------------------------------------------------
// Shapes (compile-time constants for this problem)
// ---------------------------------------------------------------------------
#define SEQ     2048
#define D_MODEL 1024
#define D_IN    2048
#define N_STATE 16
#define DT_RANK 64
#define XDBL_W  96          // DT_RANK + 2*N_STATE
#define XDBL_LD 128         // padded leading dim of x_dbl
#define LC      64          // scan chunk length
#define NCH     32          // SEQ / LC
#define DT      32          // d-channels per scan block
#define WX_KSPLIT 16
#define WX_KSEG   (D_IN / WX_KSPLIT)   // 128
#define OUT_KSPLIT 4
#define OUT_KSEG   (D_IN / OUT_KSPLIT) // 512

#define LOG2E   1.4426950408889634f

typedef __attribute__((ext_vector_type(8))) short bf16x8;
typedef __attribute__((ext_vector_type(4))) float f32x4;

__device__ __forceinline__ float fast_exp2(float x) { return __builtin_amdgcn_exp2f(x); }
__device__ __forceinline__ float fast_rcp(float x)  { return __builtin_amdgcn_rcpf(x); }

// async global->LDS, 16 bytes/lane; LDS dest = wave-uniform base + lane*16.
__device__ __forceinline__ void gload16(const ushort* g, ushort* l) {
    __builtin_amdgcn_global_load_lds(
        (const __attribute__((address_space(1))) void*)g,
        (__attribute__((address_space(3))) void*)l, 16, 0, 0);
}

// Pre-swizzled-source staging: LDS linear (slot idx = q*256 + wave*64 + lane),
// each lane fetches global col-block (lane&7)^(lane>>3) so LDS holds the
// XOR-swizzled layout ( [r][ (kc^(r&7))*8 ] ) the MFMA ds_read_b128 expects.
#define GL_DEFS                                                                \
    const int lane8 = lane >> 3;                                               \
    const int scol  = (lane & 7) ^ lane8;                                      \
    const int wq    = wave * 8;

#define STAGE_GL(SRC, DST, BASE, LDK, KOFF)                                    \
    _Pragma("unroll")                                                          \
    for (int q = 0; q < 4; ++q) {                                              \
        const int rr = q * 32 + wq + lane8;                                    \
        gload16(&SRC[(size_t)((BASE) + rr) * (LDK) + (KOFF) + scol * 8],       \
                ((ushort*)DST) + (q * 256 + wave * 64) * 8);                   \
    }

// v_add_f32 with DPP-moved operand: 16-lane butterfly without the DS pipe.
template <int CTRL>
__device__ __forceinline__ float dpp_add(float x) {
    int y = __builtin_amdgcn_update_dpp(0, __float_as_int(x), CTRL, 0xF, 0xF, true);
    return x + __int_as_float(y);
}

__device__ __forceinline__ ushort f2bf(float x) {
    unsigned u = __float_as_uint(x);
    u += 0x7FFFu + ((u >> 16) & 1u);      // RNE
    return (ushort)(u >> 16);
}
__device__ __forceinline__ float bf2f(ushort h) {
    return __uint_as_float(((unsigned)h) << 16);
}

// ---------------------------------------------------------------------------
// split fp32 -> bf16 hi/lo (elementwise). One float4 per thread.
// ---------------------------------------------------------------------------
__global__ __launch_bounds__(256) void split_bf16(
    const float* __restrict__ in, ushort* __restrict__ hi,
    ushort* __restrict__ lo)
{
    const int i = blockIdx.x * 256 + threadIdx.x;
    const float4 v = *(const float4*)&in[(size_t)i * 4];
    ushort4 h, l;
    h.x = f2bf(v.x); l.x = f2bf(v.x - bf2f(h.x));
    h.y = f2bf(v.y); l.y = f2bf(v.y - bf2f(h.y));
    h.z = f2bf(v.z); l.z = f2bf(v.z - bf2f(h.z));
    h.w = f2bf(v.w); l.w = f2bf(v.w - bf2f(h.w));
    *(ushort4*)&hi[(size_t)i * 4] = h;
    *(ushort4*)&lo[(size_t)i * 4] = l;
}

// ---------------------------------------------------------------------------
// split + transpose: in[R][C] fp32 -> hi/lo[C][R] bf16.
// ---------------------------------------------------------------------------
__global__ __launch_bounds__(256) void split_transpose(
    const float* __restrict__ in, ushort* __restrict__ hi,
    ushort* __restrict__ lo, int R, int C)
{
    __shared__ float tile[32][33];
    const int c0 = blockIdx.x * 32;
    const int r0 = blockIdx.y * 32;
    const int tc = threadIdx.x & 31;
    const int tr = threadIdx.x >> 5;
#pragma unroll
    for (int q = 0; q < 4; ++q)
        tile[tr + 8 * q][tc] = in[(size_t)(r0 + tr + 8 * q) * C + c0 + tc];
    __syncthreads();
#pragma unroll
    for (int q = 0; q < 4; ++q) {
        const float v = tile[tc][tr + 8 * q];
        const ushort h = f2bf(v);
        const ushort l = f2bf(v - bf2f(h));
        const size_t o = (size_t)(c0 + tr + 8 * q) * R + r0 + tc;
        hi[o] = h;
        lo[o] = l;
    }
}

// ---------------------------------------------------------------------------
// split + transpose with zero padding on the output-row axis.
// ---------------------------------------------------------------------------
__global__ __launch_bounds__(256) void split_transpose_pad(
    const float* __restrict__ in, ushort* __restrict__ hi,
    ushort* __restrict__ lo, int R, int Csrc)
{
    __shared__ float tile[32][33];
    const int c0 = blockIdx.x * 32;
    const int r0 = blockIdx.y * 32;
    const int tc = threadIdx.x & 31;
    const int tr = threadIdx.x >> 5;
#pragma unroll
    for (int q = 0; q < 4; ++q) {
        const int c = c0 + tc;
        tile[tr + 8 * q][tc] =
            (c < Csrc) ? in[(size_t)(r0 + tr + 8 * q) * Csrc + c] : 0.f;
    }
    __syncthreads();
#pragma unroll
    for (int q = 0; q < 4; ++q) {
        const float v = tile[tc][tr + 8 * q];
        const ushort h = f2bf(v);
        const ushort l = f2bf(v - bf2f(h));
        const size_t o = (size_t)(c0 + tr + 8 * q) * R + r0 + tc;
        hi[o] = h;
        lo[o] = l;
    }
}

// ---------------------------------------------------------------------------
// bf16x3-split MFMA GEMM (A row-major hi/lo, B transposed hi/lo).
// ---------------------------------------------------------------------------
__global__ __launch_bounds__(256) void gemm_mfma3(
    const ushort* __restrict__ Ahi, const ushort* __restrict__ Alo,
    const ushort* __restrict__ Bhi, const ushort* __restrict__ Blo,
    float* __restrict__ C0, float* __restrict__ C1, int nsplit,
    int M, int N, int K, int ldc0, int ldc1)
{
    __shared__ ushort lA[2][128][64];
    __shared__ ushort lB[2][128][64];

    const int t    = threadIdx.x;
    const int m0   = blockIdx.y * 128;
    const int n0   = blockIdx.x * 128;
    const int wave = t >> 6;
    const int lane = t & 63;
    const int mw   = (wave & 1) * 64;
    const int nw   = (wave >> 1) * 64;
    const int l15  = lane & 15;
    const int l4   = lane >> 4;
    const int sw   = l15 & 7;
    GL_DEFS

    f32x4 acc[4][4];
#pragma unroll
    for (int i = 0; i < 4; ++i)
#pragma unroll
        for (int j = 0; j < 4; ++j)
            acc[i][j] = (f32x4){0.f, 0.f, 0.f, 0.f};

    for (int k0 = 0; k0 < K; k0 += 64) {
        __syncthreads();
        STAGE_GL(Ahi, lA[0], m0, K, k0)
        STAGE_GL(Alo, lA[1], m0, K, k0)
        STAGE_GL(Bhi, lB[0], n0, K, k0)
        STAGE_GL(Blo, lB[1], n0, K, k0)
        __syncthreads();

#pragma unroll
        for (int ks = 0; ks < 2; ++ks) {
            const int slot = (((ks << 2) | l4) ^ sw) * 8;
            bf16x8 ah[4], al[4], bh[4], bl[4];
#pragma unroll
            for (int f = 0; f < 4; ++f) {
                const int ar = mw + f * 16 + l15;
                const int br = nw + f * 16 + l15;
                ah[f] = *(const bf16x8*)&lA[0][ar][slot];
                al[f] = *(const bf16x8*)&lA[1][ar][slot];
                bh[f] = *(const bf16x8*)&lB[0][br][slot];
                bl[f] = *(const bf16x8*)&lB[1][br][slot];
            }
#pragma unroll
            for (int i = 0; i < 4; ++i)
#pragma unroll
                for (int j = 0; j < 4; ++j) {
                    acc[i][j] = __builtin_amdgcn_mfma_f32_16x16x32_bf16(
                        ah[i], bh[j], acc[i][j], 0, 0, 0);
                    acc[i][j] = __builtin_amdgcn_mfma_f32_16x16x32_bf16(
                        ah[i], bl[j], acc[i][j], 0, 0, 0);
                    acc[i][j] = __builtin_amdgcn_mfma_f32_16x16x32_bf16(
                        al[i], bh[j], acc[i][j], 0, 0, 0);
                }
        }
    }

#pragma unroll
    for (int i = 0; i < 4; ++i) {
        const int rowg = m0 + mw + i * 16 + l4 * 4;
#pragma unroll
        for (int j = 0; j < 4; ++j) {
            const int colg = n0 + nw + j * 16 + l15;
            float* base;
            int cc, ldc;
            if (colg < nsplit) { base = C0; cc = colg;          ldc = ldc0; }
            else               { base = C1; cc = colg - nsplit; ldc = ldc1; }
#pragma unroll
            for (int v = 0; v < 4; ++v)
                base[(size_t)(rowg + v) * ldc + cc] = acc[i][j][v];
        }
    }
}

// ---------------------------------------------------------------------------
// split-K MFMA GEMM for x_dbl = u @ W_x (N padded 96->128).
// ---------------------------------------------------------------------------
__global__ __launch_bounds__(256) void gemm_wx_mfma(
    const ushort* __restrict__ Ahi, const ushort* __restrict__ Alo,
    const ushort* __restrict__ Bhi, const ushort* __restrict__ Blo,
    float* __restrict__ part)
{
    __shared__ ushort lA[2][128][64];
    __shared__ ushort lB[2][128][64];

    const int t    = threadIdx.x;
    const int kb   = blockIdx.x;
    const int m0   = blockIdx.y * 128;
    const int wave = t >> 6;
    const int lane = t & 63;
    const int mw   = (wave & 1) * 64;
    const int nw   = (wave >> 1) * 64;
    const int l15  = lane & 15;
    const int l4   = lane >> 4;
    const int sw   = l15 & 7;
    const int kbase = kb * WX_KSEG;
    GL_DEFS

    f32x4 acc[4][4];
#pragma unroll
    for (int i = 0; i < 4; ++i)
#pragma unroll
        for (int j = 0; j < 4; ++j)
            acc[i][j] = (f32x4){0.f, 0.f, 0.f, 0.f};

    for (int k0 = 0; k0 < WX_KSEG; k0 += 64) {
        __syncthreads();
        STAGE_GL(Ahi, lA[0], m0, D_IN, kbase + k0)
        STAGE_GL(Alo, lA[1], m0, D_IN, kbase + k0)
        STAGE_GL(Bhi, lB[0], 0,  D_IN, kbase + k0)
        STAGE_GL(Blo, lB[1], 0,  D_IN, kbase + k0)
        __syncthreads();

#pragma unroll
        for (int ks = 0; ks < 2; ++ks) {
            const int slot = (((ks << 2) | l4) ^ sw) * 8;
            bf16x8 ah[4], al[4], bh[4], bl[4];
#pragma unroll
            for (int f = 0; f < 4; ++f) {
                const int ar = mw + f * 16 + l15;
                const int br = nw + f * 16 + l15;
                ah[f] = *(const bf16x8*)&lA[0][ar][slot];
                al[f] = *(const bf16x8*)&lA[1][ar][slot];
                bh[f] = *(const bf16x8*)&lB[0][br][slot];
                bl[f] = *(const bf16x8*)&lB[1][br][slot];
            }
#pragma unroll
            for (int i = 0; i < 4; ++i)
#pragma unroll
                for (int j = 0; j < 4; ++j) {
                    acc[i][j] = __builtin_amdgcn_mfma_f32_16x16x32_bf16(
                        ah[i], bh[j], acc[i][j], 0, 0, 0);
                    acc[i][j] = __builtin_amdgcn_mfma_f32_16x16x32_bf16(
                        ah[i], bl[j], acc[i][j], 0, 0, 0);
                    acc[i][j] = __builtin_amdgcn_mfma_f32_16x16x32_bf16(
                        al[i], bh[j], acc[i][j], 0, 0, 0);
                }
        }
    }

#pragma unroll
    for (int i = 0; i < 4; ++i) {
        const int rowg = m0 + mw + i * 16 + l4 * 4;
#pragma unroll
        for (int j = 0; j < 4; ++j) {
            const int colg = nw + j * 16 + l15;
#pragma unroll
            for (int v = 0; v < 4; ++v)
                part[((size_t)kb * SEQ + rowg + v) * XDBL_LD + colg] =
                    acc[i][j][v];
        }
    }
}

// Fixed-order reduction of the WX_KSPLIT partials -> xdbl [SEQ][XDBL_LD].
__global__ __launch_bounds__(256) void wx_reduce(
    const float* __restrict__ part, float* __restrict__ xdbl)
{
    const size_t i = (size_t)(blockIdx.x * 256 + threadIdx.x) * 4;
    float4 s = *(const float4*)&part[i];
#pragma unroll
    for (int kb = 1; kb < WX_KSPLIT; ++kb) {
        const float4 v = *(const float4*)&part[(size_t)kb * SEQ * XDBL_LD + i];
        s.x += v.x; s.y += v.y; s.z += v.z; s.w += v.w;
    }
    *(float4*)&xdbl[i] = s;
}

// ---------------------------------------------------------------------------
// split-K=4 MFMA GEMM for out = yg @ W_out.
// ---------------------------------------------------------------------------
__global__ __launch_bounds__(256) void gemm_out_mfma(
    const ushort* __restrict__ Ahi, const ushort* __restrict__ Alo,
    const ushort* __restrict__ Bhi, const ushort* __restrict__ Blo,
    float* __restrict__ p01, float* __restrict__ p23)
{
    __shared__ ushort lA[2][128][64];
    __shared__ ushort lB[2][128][64];

    const int t    = threadIdx.x;
    const int n0   = blockIdx.x * 128;
    const int m0   = blockIdx.y * 128;
    const int kb   = blockIdx.z;
    const int wave = t >> 6;
    const int lane = t & 63;
    const int mw   = (wave & 1) * 64;
    const int nw   = (wave >> 1) * 64;
    const int l15  = lane & 15;
    const int l4   = lane >> 4;
    const int sw   = l15 & 7;
    const int kbase = kb * OUT_KSEG;
    GL_DEFS

    f32x4 acc[4][4];
#pragma unroll
    for (int i = 0; i < 4; ++i)
#pragma unroll
        for (int j = 0; j < 4; ++j)
            acc[i][j] = (f32x4){0.f, 0.f, 0.f, 0.f};

    for (int k0 = 0; k0 < OUT_KSEG; k0 += 64) {
        __syncthreads();
        STAGE_GL(Ahi, lA[0], m0, D_IN, kbase + k0)
        STAGE_GL(Alo, lA[1], m0, D_IN, kbase + k0)
        STAGE_GL(Bhi, lB[0], n0, D_IN, kbase + k0)
        STAGE_GL(Blo, lB[1], n0, D_IN, kbase + k0)
        __syncthreads();

#pragma unroll
        for (int ks = 0; ks < 2; ++ks) {
            const int slot = (((ks << 2) | l4) ^ sw) * 8;
            bf16x8 ah[4], al[4], bh[4], bl[4];
#pragma unroll
            for (int f = 0; f < 4; ++f) {
                const int ar = mw + f * 16 + l15;
                const int br = nw + f * 16 + l15;
                ah[f] = *(const bf16x8*)&lA[0][ar][slot];
                al[f] = *(const bf16x8*)&lA[1][ar][slot];
                bh[f] = *(const bf16x8*)&lB[0][br][slot];
                bl[f] = *(const bf16x8*)&lB[1][br][slot];
            }
#pragma unroll
            for (int i = 0; i < 4; ++i)
#pragma unroll
                for (int j = 0; j < 4; ++j) {
                    acc[i][j] = __builtin_amdgcn_mfma_f32_16x16x32_bf16(
                        ah[i], bh[j], acc[i][j], 0, 0, 0);
                    acc[i][j] = __builtin_amdgcn_mfma_f32_16x16x32_bf16(
                        ah[i], bl[j], acc[i][j], 0, 0, 0);
                    acc[i][j] = __builtin_amdgcn_mfma_f32_16x16x32_bf16(
                        al[i], bh[j], acc[i][j], 0, 0, 0);
                }
        }
    }

    float* base = (kb & 2) ? p23 : p01;
    base += (size_t)(kb & 1) * SEQ * D_MODEL;
#pragma unroll
    for (int i = 0; i < 4; ++i) {
        const int rowg = m0 + mw + i * 16 + l4 * 4;
#pragma unroll
        for (int j = 0; j < 4; ++j) {
            const int colg = n0 + nw + j * 16 + l15;
#pragma unroll
            for (int v = 0; v < 4; ++v)
                base[(size_t)(rowg + v) * D_MODEL + colg] = acc[i][j][v];
        }
    }
}

// Fixed-order reduce of the 4 output partials -> out [SEQ][D_MODEL].
__global__ __launch_bounds__(256) void out_reduce(
    const float* __restrict__ p01, const float* __restrict__ p23,
    float* __restrict__ out)
{
    const size_t i = (size_t)(blockIdx.x * 256 + threadIdx.x) * 4;
    const size_t MN = (size_t)SEQ * D_MODEL;
    const float4 a = *(const float4*)&p01[i];
    const float4 b = *(const float4*)&p01[i + MN];
    const float4 c = *(const float4*)&p23[i];
    const float4 d = *(const float4*)&p23[i + MN];
    float4 s;
    s.x = ((a.x + b.x) + c.x) + d.x;
    s.y = ((a.y + b.y) + c.y) + d.y;
    s.z = ((a.z + b.z) + c.z) + d.z;
    s.w = ((a.w + b.w) + c.w) + d.w;
    *(float4*)&out[i] = s;
}

// ---------------------------------------------------------------------------
// fp32 tiled GEMM (small delta GEMM, K=64)
// ---------------------------------------------------------------------------
__global__ __launch_bounds__(256) void gemm128(
    const float* __restrict__ A, const float* __restrict__ B,
    float* __restrict__ C, int M, int N, int K,
    int lda, int ldb, int ldc,
    const float* __restrict__ bias, int act)
{
    __shared__ float As[16][132];
    __shared__ float Bs[16][132];

    const int t   = threadIdx.x;
    const int bn0 = blockIdx.x * 128;
    const int bm0 = blockIdx.y * 128;
    const int tx  = t & 15;
    const int ty  = t >> 4;

    const int ar  = t >> 2;
    const int ak  = (t & 3) * 4;
    const int bk  = t >> 5;
    const int bn4 = (t & 31) * 4;

    float acc[8][8];
#pragma unroll
    for (int i = 0; i < 8; ++i)
#pragma unroll
        for (int j = 0; j < 8; ++j) acc[i][j] = 0.f;

    for (int k0 = 0; k0 < K; k0 += 16) {
        float4 a0 = *(const float4*)&A[(size_t)(bm0 + ar)      * lda + k0 + ak];
        float4 a1 = *(const float4*)&A[(size_t)(bm0 + ar + 64) * lda + k0 + ak];
        float4 b0 = *(const float4*)&B[(size_t)(k0 + bk)     * ldb + bn0 + bn4];
        float4 b1 = *(const float4*)&B[(size_t)(k0 + bk + 8) * ldb + bn0 + bn4];

        __syncthreads();
        As[ak + 0][ar] = a0.x; As[ak + 1][ar] = a0.y;
        As[ak + 2][ar] = a0.z; As[ak + 3][ar] = a0.w;
        As[ak + 0][ar + 64] = a1.x; As[ak + 1][ar + 64] = a1.y;
        As[ak + 2][ar + 64] = a1.z; As[ak + 3][ar + 64] = a1.w;
        *(float4*)&Bs[bk][bn4]     = b0;
        *(float4*)&Bs[bk + 8][bn4] = b1;
        __syncthreads();

#pragma unroll
        for (int kk = 0; kk < 16; ++kk) {
            float a[8], b[8];
            ((float4*)a)[0] = *(const float4*)&As[kk][ty * 8];
            ((float4*)a)[1] = *(const float4*)&As[kk][ty * 8 + 4];
            ((float4*)b)[0] = *(const float4*)&Bs[kk][tx * 8];
            ((float4*)b)[1] = *(const float4*)&Bs[kk][tx * 8 + 4];
#pragma unroll
            for (int i = 0; i < 8; ++i)
#pragma unroll
                for (int j = 0; j < 8; ++j)
                    acc[i][j] = fmaf(a[i], b[j], acc[i][j]);
        }
    }

    const int row = bm0 + ty * 8;
    const int col = bn0 + tx * 8;
#pragma unroll
    for (int i = 0; i < 8; ++i) {
        float vals[8];
#pragma unroll
        for (int j = 0; j < 8; ++j) {
            float v = acc[i][j];
            if (act == 1) {
                v += bias[col + j];
                v = (v > 20.f) ? v : log1pf(__expf(v));
            }
            vals[j] = v;
        }
        *(float4*)&C[(size_t)(row + i) * ldc + col]     = ((float4*)vals)[0];
        *(float4*)&C[(size_t)(row + i) * ldc + col + 4] = ((float4*)vals)[1];
    }
}

// ---------------------------------------------------------------------------
// Depthwise causal conv (K=3) + SiLU, fused with bf16 hi/lo split of u.
// ---------------------------------------------------------------------------
__global__ __launch_bounds__(256) void conv_silu_split(
    const float* __restrict__ xi, const float* __restrict__ cw,
    float* __restrict__ u, ushort* __restrict__ uhi, ushort* __restrict__ ulo)
{
    const int id = blockIdx.x * 256 + threadIdx.x;
    const int l = id >> 11;
    const int d = id & (D_IN - 1);
    const float w0 = cw[d * 3 + 0];
    const float w1 = cw[d * 3 + 1];
    const float w2 = cw[d * 3 + 2];
    const float x0  = xi[(size_t)l * D_IN + d];
    const float xm1 = (l >= 1) ? xi[(size_t)(l - 1) * D_IN + d] : 0.f;
    const float xm2 = (l >= 2) ? xi[(size_t)(l - 2) * D_IN + d] : 0.f;
    const float v = w0 * xm2 + w1 * xm1 + w2 * x0;
    const float s = fast_rcp(1.f + fast_exp2(-LOG2E * v));
    const float uu = v * s;
    u[id] = uu;
    const ushort h = f2bf(uu);
    uhi[id] = h;
    ulo[id] = f2bf(uu - bf2f(h));
}

// ---------------------------------------------------------------------------
// Per-chunk column sums of delta (double)
// ---------------------------------------------------------------------------
__global__ __launch_bounds__(256) void csum64(
    const float* __restrict__ delta, double* __restrict__ csum)
{
    const int d = blockIdx.x * 256 + threadIdx.x;
    const int c = blockIdx.y;
    double s = 0.0;
    for (int i = 0; i < LC; ++i)
        s += (double)delta[(size_t)(c * LC + i) * D_IN + d];
    csum[(size_t)c * D_IN + d] = s;
}

__global__ __launch_bounds__(256) void chunk_prefix(
    const double* __restrict__ csum, double* __restrict__ P0,
    double* __restrict__ Td)
{
    const int d = blockIdx.x * 256 + threadIdx.x;
    double P = 0.0;
    for (int c = 0; c < NCH; ++c) {
        P0[(size_t)c * D_IN + d] = P;
        P += csum[(size_t)c * D_IN + d];
    }
    Td[d] = P;
}

// ---------------------------------------------------------------------------
// sfx[l][d] = float(max(Td - P_inclusive(l), 0)); ALSO converts res -> rg =
// res*sigmoid(res) IN PLACE (res is regenerated by gemm1 every call, so this
// is replay-safe).
// ---------------------------------------------------------------------------
__global__ __launch_bounds__(256) void sfx_precompute(
    const float* __restrict__ delta, const double* __restrict__ P0,
    const double* __restrict__ Td, float* __restrict__ sfx,
    float* __restrict__ res)
{
    const int d = blockIdx.x * 256 + threadIdx.x;
    const int c = blockIdx.y;
    double P = P0[(size_t)c * D_IN + d];
    const double T = Td[d];
    for (int i = 0; i < LC; ++i) {
        const size_t row = (size_t)(c * LC + i) * D_IN + d;
        P += (double)delta[row];
        sfx[row] = (float)fmax(T - P, 0.0);
        const float r = res[row];
        res[row] = r * fast_rcp(1.f + fast_exp2(-LOG2E * r));
    }
}

// ---------------------------------------------------------------------------
// Pass A (cumsum form): per-chunk sum Wc[c,d,n] = sum_j du[j]*B[j,n]*E[j],
// E[j] = exp2(An2*sfx[j]).  No recurrence, no per-step decay exp.
// ---------------------------------------------------------------------------
__global__ __launch_bounds__(512) void scan_partA(
    const float* __restrict__ delta, const float* __restrict__ u,
    const float* __restrict__ sfxbuf, const float* __restrict__ xdbl,
    const float* __restrict__ Alog, float* __restrict__ Wc)
{
    __shared__ float2 spA[LC][DT];     // (delta*u, sfx)  16 KB
    __shared__ float  sBA[LC][16];     // B                4 KB

    const int t  = threadIdx.x;
    const int c  = blockIdx.x;
    const int d0 = blockIdx.y * DT;

    {
        const int r = t >> 3, c4 = (t & 7) * 4;
        const size_t row = (size_t)(c * LC + r) * D_IN + d0 + c4;
        const float4 dv4 = *(const float4*)&delta[row];
        const float4 uv4 = *(const float4*)&u[row];
        const float4 sx4 = *(const float4*)&sfxbuf[row];
        spA[r][c4 + 0] = make_float2(dv4.x * uv4.x, sx4.x);
        spA[r][c4 + 1] = make_float2(dv4.y * uv4.y, sx4.y);
        spA[r][c4 + 2] = make_float2(dv4.z * uv4.z, sx4.z);
        spA[r][c4 + 3] = make_float2(dv4.w * uv4.w, sx4.w);
    }
    if (t < 256) {
        const int r = t >> 2, c4 = (t & 3) * 4;
        *(float4*)&sBA[r][c4] =
            *(const float4*)&xdbl[(size_t)(c * LC + r) * XDBL_LD + DT_RANK + c4];
    }
    __syncthreads();

    const int n  = t & 15;
    const int dq = t >> 4;
    const int d  = d0 + dq;
    const float An2 = -expf(Alog[d * N_STATE + n]) * LOG2E;

    float W = 0.f;
#pragma unroll
    for (int i = 0; i < LC; ++i) {
        const float2 p = spA[i][dq];
        W = fmaf(p.x * sBA[i][n], fast_exp2(An2 * p.y), W);
    }
    Wc[((size_t)c * D_IN + d) * N_STATE + n] = W;
}

// ---------------------------------------------------------------------------
// Pass B: exclusive prefix over chunks (plain adds; no decay needed in the
// cumsum form).  Wc becomes the incoming prefix W0 for each chunk (in place).
// ---------------------------------------------------------------------------
__global__ __launch_bounds__(256) void scan_combine(float* __restrict__ Wc)
{
    const int id = blockIdx.x * 256 + threadIdx.x;   // (d,n)
    float W = 0.f;
    for (int c = 0; c < NCH; ++c) {
        const size_t idx = (size_t)c * (D_IN * N_STATE) + id;
        const float w = Wc[idx];
        Wc[idx] = W;
        W += w;
    }
}

// ---------------------------------------------------------------------------
// Pass C (cumsum form):
//   W += du*B*E;  xs = W / (E + 1e-12);  y_l = sum_n xs*C;  out *= rg
// spack[i][dq] = (du, sfx, u, rg) -> one ds_read_b128 (broadcast x16)
// sbc[i][n]    = (B, C)           -> one ds_read_b64
// Per iter: 1 exp + 1 rcp + ~7 VALU + 4 DPP (was 3-4 trans + ~20 VALU).
// ---------------------------------------------------------------------------
__global__ __launch_bounds__(512) void scan_partC(
    const float* __restrict__ delta, const float* __restrict__ u,
    const float* __restrict__ xdbl, const float* __restrict__ W0buf,
    const float* __restrict__ sfxbuf, const float* __restrict__ Alog,
    const float* __restrict__ Dvec, const float* __restrict__ rgbuf,
    float* __restrict__ yg)
{
    __shared__ float4 spack[LC][DT];   // 32 KB
    __shared__ float2 sbc[LC][16];     //  8 KB

    const int t  = threadIdx.x;
    const int c  = blockIdx.x;
    const int d0 = blockIdx.y * DT;

    {
        const int r = t >> 3, c4 = (t & 7) * 4;
        const size_t row = (size_t)(c * LC + r) * D_IN + d0 + c4;
        const float4 dv4 = *(const float4*)&delta[row];
        const float4 uv4 = *(const float4*)&u[row];
        const float4 sx4 = *(const float4*)&sfxbuf[row];
        const float4 rg4 = *(const float4*)&rgbuf[row];
        spack[r][c4 + 0] = make_float4(dv4.x * uv4.x, sx4.x, uv4.x, rg4.x);
        spack[r][c4 + 1] = make_float4(dv4.y * uv4.y, sx4.y, uv4.y, rg4.y);
        spack[r][c4 + 2] = make_float4(dv4.z * uv4.z, sx4.z, uv4.z, rg4.z);
        spack[r][c4 + 3] = make_float4(dv4.w * uv4.w, sx4.w, uv4.w, rg4.w);
    }
    if (t < 256) {
        const int r = t >> 2, n4 = (t & 3) * 4;
        const float4 b4 = *(const float4*)&xdbl[(size_t)(c * LC + r) * XDBL_LD + DT_RANK + n4];
        const float4 c4v = *(const float4*)&xdbl[(size_t)(c * LC + r) * XDBL_LD + DT_RANK + 16 + n4];
        sbc[r][n4 + 0] = make_float2(b4.x, c4v.x);
        sbc[r][n4 + 1] = make_float2(b4.y, c4v.y);
        sbc[r][n4 + 2] = make_float2(b4.z, c4v.z);
        sbc[r][n4 + 3] = make_float2(b4.w, c4v.w);
    }
    __syncthreads();

    const int n  = t & 15;
    const int dq = t >> 4;
    const int d  = d0 + dq;
    const float An2 = -expf(Alog[d * N_STATE + n]) * LOG2E;
    const float Dd = Dvec[d];

    float W = W0buf[((size_t)c * D_IN + d) * N_STATE + n];

#pragma unroll
    for (int i = 0; i < LC; ++i) {
        const float4 p = spack[i][dq];
        const float2 bc = sbc[i][n];
        const float E = fast_exp2(An2 * p.y);
        W = fmaf(p.x * bc.x, E, W);
        const float xs = W * fast_rcp(E + 1e-12f);
        float contrib = xs * bc.y;
        contrib = dpp_add<0xB1>(contrib);    // quad_perm 1,0,3,2  (xor 1)
        contrib = dpp_add<0x4E>(contrib);    // quad_perm 2,3,0,1  (xor 2)
        contrib = dpp_add<0x128>(contrib);   // row_ror:8
        contrib = dpp_add<0x124>(contrib);   // row_ror:4
        if (n == 0) {
            yg[(size_t)(c * LC + i) * D_IN + d] =
                fmaf(p.z, Dd, contrib) * p.w;
        }
    }
}

// ---------------------------------------------------------------------------
// Launch.  Workspace (74.5 MB peak, time-multiplexed; ws proven >= 84.9 MB):
//   [ 0    ,16.78M): xi -> wxp -> sfx -> yg_hi/yg_lo
//   [16.78 ,33.55 ): res (becomes rg in-place) -> out partials p01
//   [33.55 ,50.33 ): x_hi/x_lo -> u (f32) -> wo_hi/wo_lo
//   [50.33 ,51.38 ): xdbl [2048][128] f32
//   [51.38 ,68.16 ): wi_hi/wi_lo -> u_hi/u_lo -> delta/yg -> p23
//   [68.16 ,73.42 ): Wc/W0, csum, P0, Td
//   [73.42 ,74.47 ): wx_hi/wx_lo
// ---------------------------------------------------------------------------
extern "C" void kernel_launch(void* const* d_in, const int* in_sizes, int n_in,
                              void* d_out, int out_size, void* d_ws, size_t ws_size,
                              hipStream_t stream)
{
    const float* x      = (const float*)d_in[0];
    const float* W_in   = (const float*)d_in[1];
    const float* conv_w = (const float*)d_in[2];
    const float* W_x    = (const float*)d_in[3];
    const float* W_del  = (const float*)d_in[4];
    const float* b_del  = (const float*)d_in[5];
    const float* A_log  = (const float*)d_in[6];
    const float* Dv     = (const float*)d_in[7];
    const float* W_out  = (const float*)d_in[8];
    float* out = (float*)d_out;

    char* ws = (char*)d_ws;
    float*  xi    = (float*)(ws + 0);
    float*  wxp   = (float*)(ws + 0);
    float*  sfx   = (float*)(ws + 0);
    ushort* yg_hi = (ushort*)(ws + 0);
    ushort* yg_lo = (ushort*)(ws + 8388608);
    float*  res   = (float*)(ws + 16777216);   // becomes rg in sfx_precompute
    float*  p01   = (float*)(ws + 16777216);
    ushort* x_hi  = (ushort*)(ws + 33554432);
    ushort* x_lo  = (ushort*)(ws + 37748736);
    float*  u     = (float*)(ws + 33554432);
    ushort* wo_hi = (ushort*)(ws + 33554432);
    ushort* wo_lo = (ushort*)(ws + 37748736);
    float*  xdbl  = (float*)(ws + 50331648);
    ushort* wi_hi = (ushort*)(ws + 51380224);
    ushort* wi_lo = (ushort*)(ws + 59768832);
    ushort* u_hi  = (ushort*)(ws + 51380224);
    ushort* u_lo  = (ushort*)(ws + 59768832);
    float*  delta = (float*)(ws + 51380224);
    float*  p23   = (float*)(ws + 51380224);
    float*  Wc    = (float*)(ws + 68157440);   // 4.19 MB
    double* csum  = (double*)(ws + 72351744);
    double* P0    = (double*)(ws + 72876032);
    double* Td    = (double*)(ws + 73400320);
    ushort* wx_hi = (ushort*)(ws + 73416704);
    ushort* wx_lo = (ushort*)(ws + 73940992);
    float*  yg    = delta;

    // 1) W_in^T split
    split_transpose<<<dim3(4096 / 32, 1024 / 32), 256, 0, stream>>>(
        W_in, wi_hi, wi_lo, 1024, 4096);

    // 2) x split
    split_bf16<<<(SEQ * D_MODEL / 4) / 256, 256, 0, stream>>>(x, x_hi, x_lo);

    // 3) [xi | res] = x @ W_in
    gemm_mfma3<<<dim3(4096 / 128, 2048 / 128), 256, 0, stream>>>(
        x_hi, x_lo, wi_hi, wi_lo, xi, res, D_IN,
        SEQ, 2 * D_IN, D_MODEL, D_IN, D_IN);

    // 4) u = silu(conv(xi)) + u hi/lo split (fused)
    conv_silu_split<<<(SEQ * D_IN) / 256, 256, 0, stream>>>(
        xi, conv_w, u, u_hi, u_lo);

    // 5) W_x^T padded split
    split_transpose_pad<<<dim3(XDBL_LD / 32, D_IN / 32), 256, 0, stream>>>(
        W_x, wx_hi, wx_lo, D_IN, XDBL_W);

    // 6) x_dbl = u @ W_x  (split-K MFMA, fixed-order reduce)
    gemm_wx_mfma<<<dim3(WX_KSPLIT, SEQ / 128), 256, 0, stream>>>(
        u_hi, u_lo, wx_hi, wx_lo, wxp);
    wx_reduce<<<(SEQ * XDBL_LD / 4) / 256, 256, 0, stream>>>(wxp, xdbl);

    // 7) delta = softplus(delta_lr @ W_delta + b_delta)
    gemm128<<<dim3(2048 / 128, 2048 / 128), 256, 0, stream>>>(
        xdbl, W_del, delta, SEQ, D_IN, DT_RANK, XDBL_LD, D_IN, D_IN,
        b_del, 1);

    // 8) chunk sums + prefix + suffix/rg precompute (double, deterministic)
    csum64<<<dim3(D_IN / 256, NCH), 256, 0, stream>>>(delta, csum);
    chunk_prefix<<<D_IN / 256, 256, 0, stream>>>(csum, P0, Td);
    sfx_precompute<<<dim3(D_IN / 256, NCH), 256, 0, stream>>>(
        delta, P0, Td, sfx, res);

    // 9) chunk-parallel scan (cumsum form)
    scan_partA<<<dim3(NCH, D_IN / DT), 512, 0, stream>>>(
        delta, u, sfx, xdbl, A_log, Wc);
    scan_combine<<<(D_IN * N_STATE) / 256, 256, 0, stream>>>(Wc);
    scan_partC<<<dim3(NCH, D_IN / DT), 512, 0, stream>>>(
        delta, u, xdbl, Wc, sfx, A_log, Dv, res, yg);

    // 10) yg split (sfx dead; region reused)
    split_bf16<<<(SEQ * D_IN / 4) / 256, 256, 0, stream>>>(yg, yg_hi, yg_lo);

    // 11) W_out^T split (u dead; region reused)
    split_transpose<<<dim3(1024 / 32, 2048 / 32), 256, 0, stream>>>(
        W_out, wo_hi, wo_lo, 2048, 1024);

    // 12) out = yg @ W_out  (split-K=4; partials in dead regions)
    gemm_out_mfma<<<dim3(D_MODEL / 128, SEQ / 128, OUT_KSPLIT), 256, 0, stream>>>(
        yg_hi, yg_lo, wo_hi, wo_lo, p01, p23);
    out_reduce<<<(SEQ * D_MODEL / 4) / 256, 256, 0, stream>>>(p01, p23, out);
}